// Round 1
// baseline (6715.652 us; speedup 1.0000x reference)
//
#include <hip/hip_runtime.h>
#include <hip/hip_bf16.h>

// CapsNet forward, fp32 baseline with fused conv+relu+pool, bf16 u_hat.
// B=256, R=1152, C=10, O=16, I=8

#define NB 256

// ---------------- conv1(3->64,3x3,s1,p0) + relu + maxpool(2,2,p1) ----------------
// out: P1 [256,64,38,38]
__global__ __launch_bounds__(256) void k_conv1_pool(
    const float* __restrict__ data, const float* __restrict__ w1,
    const float* __restrict__ b1, float* __restrict__ P1)
{
    int t = blockIdx.x * 256 + threadIdx.x;              // 256*64*38*38 threads
    int px = t % 38, py = (t / 38) % 38, oc = (t / 1444) % 64, b = t / 92416;

    float w[27];
    const float* wp = w1 + oc * 27;
    #pragma unroll
    for (int i = 0; i < 27; i++) w[i] = wp[i];
    float bias = b1[oc];

    int y0 = 2 * py - 1, x0 = 2 * px - 1;
    float tile[3][4][4];
    #pragma unroll
    for (int ic = 0; ic < 3; ic++) {
        const float* dp = data + (b * 3 + ic) * 5776;
        #pragma unroll
        for (int i = 0; i < 4; i++) {
            int y = y0 + i;
            #pragma unroll
            for (int j = 0; j < 4; j++) {
                int x = x0 + j;
                bool ok = ((unsigned)y < 76u) && ((unsigned)x < 76u);
                tile[ic][i][j] = ok ? dp[y * 76 + x] : 0.f;
            }
        }
    }
    float m = 0.f;   // relu >= 0 so 0 is a safe identity for the max
    #pragma unroll
    for (int dy = 0; dy < 2; dy++) {
        int y = y0 + dy;
        if ((unsigned)y >= 74u) continue;
        #pragma unroll
        for (int dx = 0; dx < 2; dx++) {
            int x = x0 + dx;
            if ((unsigned)x >= 74u) continue;
            float v = bias;
            #pragma unroll
            for (int ic = 0; ic < 3; ic++)
                #pragma unroll
                for (int ky = 0; ky < 3; ky++)
                    #pragma unroll
                    for (int kx = 0; kx < 3; kx++)
                        v += tile[ic][dy + ky][dx + kx] * w[ic * 9 + ky * 3 + kx];
            m = fmaxf(m, fmaxf(v, 0.f));
        }
    }
    P1[t] = m;  // t == ((b*64+oc)*38+py)*38+px
}

// ---------------- conv2(64->128,3x3,s1,p1) + relu + maxpool(2,2,p1) ----------------
// in: P1 [256,64,38,38] -> out: P2 [256,128,20,20]; 4 oc per thread
__global__ __launch_bounds__(256) void k_conv2_pool(
    const float* __restrict__ P1, const float* __restrict__ w2,
    const float* __restrict__ cb, float* __restrict__ P2)
{
    int t = blockIdx.x * 256 + threadIdx.x;              // 256*32*400 threads
    int px = t % 20, py = (t / 20) % 20, g = (t / 400) % 32, b = t / 12800;
    int oc0 = g * 4;
    float acc[4][2][2] = {};
    int y0 = 2 * py - 2, x0 = 2 * px - 2;                // input-tile origin

    for (int ic = 0; ic < 64; ic++) {
        const float* ip = P1 + (b * 64 + ic) * 1444;
        float tile[4][4];
        #pragma unroll
        for (int i = 0; i < 4; i++) {
            int y = y0 + i;
            #pragma unroll
            for (int j = 0; j < 4; j++) {
                int x = x0 + j;
                bool ok = ((unsigned)y < 38u) && ((unsigned)x < 38u);
                tile[i][j] = ok ? ip[y * 38 + x] : 0.f;   // conv2 pad=1 zero-pad
            }
        }
        #pragma unroll
        for (int o = 0; o < 4; o++) {
            const float* wp = w2 + ((oc0 + o) * 64 + ic) * 9;
            #pragma unroll
            for (int ky = 0; ky < 3; ky++)
                #pragma unroll
                for (int kx = 0; kx < 3; kx++) {
                    float wv = wp[ky * 3 + kx];
                    #pragma unroll
                    for (int dy = 0; dy < 2; dy++)
                        #pragma unroll
                        for (int dx = 0; dx < 2; dx++)
                            acc[o][dy][dx] += tile[dy + ky][dx + kx] * wv;
                }
        }
    }
    #pragma unroll
    for (int o = 0; o < 4; o++) {
        float bias = cb[oc0 + o];
        float m = 0.f;
        #pragma unroll
        for (int dy = 0; dy < 2; dy++) {
            int y = 2 * py - 1 + dy;
            if ((unsigned)y >= 38u) continue;
            #pragma unroll
            for (int dx = 0; dx < 2; dx++) {
                int x = 2 * px - 1 + dx;
                if ((unsigned)x >= 38u) continue;
                m = fmaxf(m, fmaxf(acc[o][dy][dx] + bias, 0.f));
            }
        }
        P2[((b * 128 + oc0 + o) * 20 + py) * 20 + px] = m;
    }
}

// ---------------- prim_w [256,128,81] -> pwT [128*81, 256] ----------------
__global__ __launch_bounds__(256) void k_transpose_pw(
    const float* __restrict__ pw, float* __restrict__ pwT)
{
    int t = blockIdx.x * 256 + threadIdx.x;              // 256*128*81
    int oc = t & 255, rest = t >> 8;                     // rest = ic*81+k
    pwT[t] = pw[oc * 10368 + rest];
}

// ---------------- primcaps conv(128->256,9x9,s2,p0) ----------------
// in: P2 [256,128,20,20] -> P3 [256, 9216] (flat [oc][y][x]); 8 oc per thread
__global__ __launch_bounds__(256) void k_primcaps(
    const float* __restrict__ P2, const float* __restrict__ pwT,
    const float* __restrict__ pb, float* __restrict__ P3)
{
    int t = blockIdx.x * 256 + threadIdx.x;              // 256*36*32 threads
    int g = t & 31, s = (t >> 5) % 36, b = t / 1152;
    int y = s / 6, x = s % 6;
    int oc0 = g * 8;
    float acc[8] = {};
    const float* ip = P2 + b * 51200 + (2 * y) * 20 + 2 * x;
    const float* wp = pwT + oc0;

    for (int ic = 0; ic < 128; ic++) {
        for (int ky = 0; ky < 9; ky++) {
            #pragma unroll
            for (int kx = 0; kx < 9; kx++) {
                float v = ip[ic * 400 + ky * 20 + kx];   // rows 2y+ky <= 18 < 20: no guard
                const float4* w4 = (const float4*)(wp + (ic * 81 + ky * 9 + kx) * 256);
                float4 a4 = w4[0], b4 = w4[1];
                acc[0] += v * a4.x; acc[1] += v * a4.y;
                acc[2] += v * a4.z; acc[3] += v * a4.w;
                acc[4] += v * b4.x; acc[5] += v * b4.y;
                acc[6] += v * b4.z; acc[7] += v * b4.w;
            }
        }
    }
    #pragma unroll
    for (int o = 0; o < 8; o++)
        P3[b * 9216 + (oc0 + o) * 36 + s] = acc[o] + pb[oc0 + o];
}

// ---------------- squash u (groups of 8 flat elements), in place ----------------
__global__ __launch_bounds__(256) void k_squash(float* __restrict__ u)
{
    int t = blockIdx.x * 256 + threadIdx.x;              // 256*1152 threads
    float4 a = *(const float4*)(u + t * 8);
    float4 b = *(const float4*)(u + t * 8 + 4);
    float sn = a.x*a.x + a.y*a.y + a.z*a.z + a.w*a.w
             + b.x*b.x + b.y*b.y + b.z*b.z + b.w*b.w;
    float sc = sqrtf(sn) / (1.f + sn);                   // == sn/((1+sn)*sqrt(sn))
    a.x*=sc; a.y*=sc; a.z*=sc; a.w*=sc; b.x*=sc; b.y*=sc; b.z*=sc; b.w*=sc;
    *(float4*)(u + t * 8) = a;
    *(float4*)(u + t * 8 + 4) = b;
}

// ---------------- u_hat[r][b][co] = sum_i W[r,co,i]*u[b,r,i]  (bf16 out) -------
__global__ __launch_bounds__(256) void k_uhat(
    const float* __restrict__ u, const float* __restrict__ W,
    __hip_bfloat16* __restrict__ uhat)
{
    int t = blockIdx.x * 256 + threadIdx.x;              // 1152*256*160 threads
    int co = t % 160, b = (t / 160) & 255, r = t / 40960;
    const float4* up = (const float4*)(u + (b * 1152 + r) * 8);
    float4 u0 = up[0], u1 = up[1];
    const float4* wp = (const float4*)(W + (r * 160 + co) * 8);
    float4 w0 = wp[0], w1 = wp[1];
    float s = u0.x*w0.x + u0.y*w0.y + u0.z*w0.z + u0.w*w0.w
            + u1.x*w1.x + u1.y*w1.y + u1.z*w1.z + u1.w*w1.w;
    uhat[t] = __float2bfloat16(s);
}

// ---------------- softmax over r per class: cij[c][r] ----------------
__global__ __launch_bounds__(256) void k_softmax(
    const float* __restrict__ bij, float* __restrict__ cij)
{
    int c = blockIdx.x, tid = threadIdx.x;
    __shared__ float red[256];
    const float* bp = bij + c * 1152;
    float mx = -1e30f;
    for (int r = tid; r < 1152; r += 256) mx = fmaxf(mx, bp[r]);
    red[tid] = mx; __syncthreads();
    for (int s = 128; s > 0; s >>= 1) { if (tid < s) red[tid] = fmaxf(red[tid], red[tid + s]); __syncthreads(); }
    mx = red[0]; __syncthreads();
    float sum = 0.f;
    for (int r = tid; r < 1152; r += 256) sum += expf(bp[r] - mx);
    red[tid] = sum; __syncthreads();
    for (int s = 128; s > 0; s >>= 1) { if (tid < s) red[tid] += red[tid + s]; __syncthreads(); }
    float inv = 1.f / red[0];
    for (int r = tid; r < 1152; r += 256) cij[c * 1152 + r] = expf(bp[r] - mx) * inv;
}

// ---------------- s_j + elementwise squash -> v[b][c][o] (+ final output) -------
__global__ __launch_bounds__(256) void k_sj_vj(
    const __hip_bfloat16* __restrict__ uhat, const float* __restrict__ cij,
    float* __restrict__ v, float* __restrict__ out, int write_out)
{
    int bc = blockIdx.x;                                  // 2560 blocks
    int c = bc % 10, b = bc / 10;
    int tid = threadIdx.x, o = tid & 15, rs = tid >> 4;
    float acc = 0.f;
    for (int r = rs; r < 1152; r += 16) {
        float cc = cij[c * 1152 + r];
        float uh = __bfloat162float(uhat[(r * 256 + b) * 160 + c * 16 + o]);
        acc += cc * uh;
    }
    __shared__ float red[16][17];
    red[rs][o] = acc; __syncthreads();
    if (tid < 16) {
        float s = 0.f;
        #pragma unroll
        for (int k = 0; k < 16; k++) s += red[k][tid];
        float vv = s * fabsf(s) / (1.f + s * s);          // elementwise squash
        v[(b * 10 + c) * 16 + tid] = vv;
        if (write_out) out[(b * 10 + c) * 16 + tid] = vv;
    }
}

// ---------------- a_ij = mean_b <u_hat, v>; b_ij += a ----------------
__global__ __launch_bounds__(256) void k_aij(
    const __hip_bfloat16* __restrict__ uhat, const float* __restrict__ v,
    float* __restrict__ bij)
{
    int r = blockIdx.x, tid = threadIdx.x;
    __shared__ float red[160];
    if (tid < 160) {
        float acc = 0.f;
        for (int b = 0; b < 256; b++)
            acc += __bfloat162float(uhat[(r * 256 + b) * 160 + tid]) * v[b * 160 + tid];
        red[tid] = acc;
    }
    __syncthreads();
    if (tid < 10) {
        float s = 0.f;
        #pragma unroll
        for (int k = 0; k < 16; k++) s += red[tid * 16 + k];
        bij[tid * 1152 + r] += s * (1.f / 256.f);
    }
}

// ---------------- classifiers: sigmoid(w2 . relu(w1 . feat + b1) + b2) ----------
__global__ __launch_bounds__(128) void k_cls(
    const float* __restrict__ v, const float* __restrict__ w1,
    const float* __restrict__ b1, const float* __restrict__ w2,
    const float* __restrict__ b2, float* __restrict__ out)
{
    int bk = blockIdx.x;                                  // 2560 blocks
    int k = bk % 10, b = bk / 10;
    int tid = threadIdx.x;
    __shared__ float feat[160];
    __shared__ float red[128];
    for (int f = tid; f < 160; f += 128) feat[f] = v[b * 160 + f];
    __syncthreads();
    float h = 0.f;
    if (tid < 100) {
        float a = b1[k * 100 + tid];
        for (int f = 0; f < 160; f++) a += feat[f] * w1[(k * 160 + f) * 100 + tid];
        h = fmaxf(a, 0.f) * w2[k * 100 + tid];
    }
    red[tid] = h; __syncthreads();
    for (int s = 64; s > 0; s >>= 1) { if (tid < s) red[tid] += red[tid + s]; __syncthreads(); }
    if (tid == 0) {
        float logit = red[0] + b2[k];
        out[40960 + b * 10 + k] = 1.f / (1.f + expf(-logit));
    }
}

extern "C" void kernel_launch(void* const* d_in, const int* in_sizes, int n_in,
                              void* d_out, int out_size, void* d_ws, size_t ws_size,
                              hipStream_t stream) {
    const float* data    = (const float*)d_in[0];
    const float* conv1_w = (const float*)d_in[1];
    const float* conv1_b = (const float*)d_in[2];
    const float* conv2_w = (const float*)d_in[3];
    const float* conv2_b = (const float*)d_in[4];
    const float* prim_w  = (const float*)d_in[5];
    const float* prim_b  = (const float*)d_in[6];
    const float* W       = (const float*)d_in[7];
    const float* cls_w1  = (const float*)d_in[8];
    const float* cls_b1  = (const float*)d_in[9];
    const float* cls_w2  = (const float*)d_in[10];
    const float* cls_b2  = (const float*)d_in[11];
    float* out = (float*)d_out;

    char* ws = (char*)d_ws;
    // P1 region later reused for bf16 u_hat (94,371,840 B <= 94,633,984 B)
    float*          P1   = (float*)(ws + 0);
    __hip_bfloat16* uhat = (__hip_bfloat16*)(ws + 0);
    float*          P2   = (float*)(ws + 94633984);
    float*          u    = (float*)(ws + 147062784);
    float*          pwT  = (float*)(ws + 156499968);
    float*          v    = (float*)(ws + 167116800);
    float*          bij  = (float*)(ws + 167280640);
    float*          cij  = (float*)(ws + 167326720);
    // total: 167,372,800 bytes

    hipMemsetAsync(bij, 0, 11520 * sizeof(float), stream);

    k_conv1_pool<<<92416, 256, 0, stream>>>(data, conv1_w, conv1_b, P1);
    k_transpose_pw<<<10368, 256, 0, stream>>>(prim_w, pwT);
    k_conv2_pool<<<12800, 256, 0, stream>>>(P1, conv2_w, conv2_b, P2);
    k_primcaps<<<1152, 256, 0, stream>>>(P2, pwT, prim_b, u);
    k_squash<<<1152, 256, 0, stream>>>(u);
    k_uhat<<<184320, 256, 0, stream>>>(u, W, uhat);

    for (int it = 0; it < 3; it++) {
        k_softmax<<<10, 256, 0, stream>>>(bij, cij);
        k_sj_vj<<<2560, 256, 0, stream>>>(uhat, cij, v, out, it == 2 ? 1 : 0);
        if (it < 2) k_aij<<<1152, 256, 0, stream>>>(uhat, v, bij);
    }
    k_cls<<<2560, 128, 0, stream>>>(v, cls_w1, cls_b1, cls_w2, cls_b2, out);
}

// Round 2
// 3654.058 us; speedup vs baseline: 1.8379x; 1.8379x over previous
//
#include <hip/hip_runtime.h>
#include <hip/hip_bf16.h>

// CapsNet forward. Round 2: primcaps conv -> bf16 MFMA implicit GEMM.
// B=256, R=1152, C=10, O=16, I=8

typedef __bf16 bf16x8 __attribute__((ext_vector_type(8)));
typedef float  f32x4  __attribute__((ext_vector_type(4)));

// ---------------- conv1(3->64,3x3,s1,p0) + relu + maxpool(2,2,p1) ----------------
// out: P1 [256,64,38,38] fp32
__global__ __launch_bounds__(256) void k_conv1_pool(
    const float* __restrict__ data, const float* __restrict__ w1,
    const float* __restrict__ b1, float* __restrict__ P1)
{
    int t = blockIdx.x * 256 + threadIdx.x;              // 256*64*38*38 threads
    int px = t % 38, py = (t / 38) % 38, oc = (t / 1444) % 64, b = t / 92416;

    float w[27];
    const float* wp = w1 + oc * 27;
    #pragma unroll
    for (int i = 0; i < 27; i++) w[i] = wp[i];
    float bias = b1[oc];

    int y0 = 2 * py - 1, x0 = 2 * px - 1;
    float tile[3][4][4];
    #pragma unroll
    for (int ic = 0; ic < 3; ic++) {
        const float* dp = data + (b * 3 + ic) * 5776;
        #pragma unroll
        for (int i = 0; i < 4; i++) {
            int y = y0 + i;
            #pragma unroll
            for (int j = 0; j < 4; j++) {
                int x = x0 + j;
                bool ok = ((unsigned)y < 76u) && ((unsigned)x < 76u);
                tile[ic][i][j] = ok ? dp[y * 76 + x] : 0.f;
            }
        }
    }
    float m = 0.f;   // relu >= 0 so 0 is a safe identity for the max
    #pragma unroll
    for (int dy = 0; dy < 2; dy++) {
        int y = y0 + dy;
        if ((unsigned)y >= 74u) continue;
        #pragma unroll
        for (int dx = 0; dx < 2; dx++) {
            int x = x0 + dx;
            if ((unsigned)x >= 74u) continue;
            float v = bias;
            #pragma unroll
            for (int ic = 0; ic < 3; ic++)
                #pragma unroll
                for (int ky = 0; ky < 3; ky++)
                    #pragma unroll
                    for (int kx = 0; kx < 3; kx++)
                        v += tile[ic][dy + ky][dx + kx] * w[ic * 9 + ky * 3 + kx];
            m = fmaxf(m, fmaxf(v, 0.f));
        }
    }
    P1[t] = m;
}

// ---------------- conv2(64->128,3x3,s1,p1) + relu + maxpool(2,2,p1) ----------------
// in: P1 [256,64,38,38] fp32 -> out: P2 [256,128,20,20] bf16; 4 oc per thread
__global__ __launch_bounds__(256) void k_conv2_pool(
    const float* __restrict__ P1, const float* __restrict__ w2,
    const float* __restrict__ cb, __hip_bfloat16* __restrict__ P2)
{
    int t = blockIdx.x * 256 + threadIdx.x;              // 256*32*400 threads
    int px = t % 20, py = (t / 20) % 20, g = (t / 400) % 32, b = t / 12800;
    int oc0 = g * 4;
    float acc[4][2][2] = {};
    int y0 = 2 * py - 2, x0 = 2 * px - 2;

    for (int ic = 0; ic < 64; ic++) {
        const float* ip = P1 + (b * 64 + ic) * 1444;
        float tile[4][4];
        #pragma unroll
        for (int i = 0; i < 4; i++) {
            int y = y0 + i;
            #pragma unroll
            for (int j = 0; j < 4; j++) {
                int x = x0 + j;
                bool ok = ((unsigned)y < 38u) && ((unsigned)x < 38u);
                tile[i][j] = ok ? ip[y * 38 + x] : 0.f;
            }
        }
        #pragma unroll
        for (int o = 0; o < 4; o++) {
            const float* wp = w2 + ((oc0 + o) * 64 + ic) * 9;
            #pragma unroll
            for (int ky = 0; ky < 3; ky++)
                #pragma unroll
                for (int kx = 0; kx < 3; kx++) {
                    float wv = wp[ky * 3 + kx];
                    #pragma unroll
                    for (int dy = 0; dy < 2; dy++)
                        #pragma unroll
                        for (int dx = 0; dx < 2; dx++)
                            acc[o][dy][dx] += tile[dy + ky][dx + kx] * wv;
                }
        }
    }
    #pragma unroll
    for (int o = 0; o < 4; o++) {
        float bias = cb[oc0 + o];
        float m = 0.f;
        #pragma unroll
        for (int dy = 0; dy < 2; dy++) {
            int y = 2 * py - 1 + dy;
            if ((unsigned)y >= 38u) continue;
            #pragma unroll
            for (int dx = 0; dx < 2; dx++) {
                int x = 2 * px - 1 + dx;
                if ((unsigned)x >= 38u) continue;
                m = fmaxf(m, fmaxf(acc[o][dy][dx] + bias, 0.f));
            }
        }
        P2[((b * 128 + oc0 + o) * 20 + py) * 20 + px] = __float2bfloat16(m);
    }
}

// ---------------- P2 [b][ic][y][x] bf16 -> P2t [b][y][x][ic] bf16 ----------------
__global__ __launch_bounds__(256) void k_transpose_p2(
    const __hip_bfloat16* __restrict__ P2, __hip_bfloat16* __restrict__ P2t)
{
    int t = blockIdx.x * 256 + threadIdx.x;              // 256*400*128 threads
    int ic = t & 127, rest = t >> 7;
    int yx = rest % 400, b = rest / 400;
    P2t[t] = P2[(b * 128 + ic) * 400 + yx];
}

// ---------------- prim_w (256,128,81) fp32 -> Awt [oc][(ky*9+kx)*128+ic] bf16 ----
__global__ __launch_bounds__(256) void k_prep_awt(
    const float* __restrict__ pw, __hip_bfloat16* __restrict__ Awt)
{
    int t = blockIdx.x * 256 + threadIdx.x;              // 256*10368 threads
    int oc = t / 10368, rem = t % 10368;
    int k81 = rem >> 7, ic = rem & 127;
    Awt[t] = __float2bfloat16(pw[(oc * 128 + ic) * 81 + k81]);
}

// ---------------- primcaps as MFMA GEMM: u[oc][n] = Awt[oc][:] . patch[:][n] ------
// M=256 (2 blocks of 128), N=9216 (72 blocks of 128), K=10368 (162 iters of 64)
// u flat out: u[b*9216 + oc*36 + s] fp32 (+bias)
__global__ __launch_bounds__(256) void k_primcaps_mfma(
    const __hip_bfloat16* __restrict__ P2t,   // [256][20][20][128]
    const __hip_bfloat16* __restrict__ Awt,   // [256][10368]
    const float* __restrict__ pb,             // [256]
    float* __restrict__ u)
{
    __shared__ ushort lA[128 * 72];   // row stride 72 elems = 144 B (16B-aligned)
    __shared__ ushort lB[128 * 72];
    const int tid  = threadIdx.x;
    const int bm   = blockIdx.x & 1;          // 2 M-blocks
    const int bn   = blockIdx.x >> 1;         // 72 N-blocks
    const int wave = tid >> 6, lane = tid & 63;
    const int wm   = wave & 1, wn = wave >> 1;      // 2x2 waves of 64x64
    const int lane15 = lane & 15, quad = lane >> 4;

    // staging: thread covers (row srow, k-half shalf) -> 64 contiguous bytes
    const int srow = tid & 127, shalf = tid >> 7;

    // B column decode (column n -> patch base in P2t)
    int n  = bn * 128 + srow;
    int cb = n / 36, cs = n % 36;
    int cy = cs / 6, cx = cs % 6;
    const __hip_bfloat16* Bbase = P2t + ((cb * 20 + 2 * cy) * 20 + 2 * cx) * 128;
    const __hip_bfloat16* Abase = Awt + (bm * 128 + srow) * 10368;
    ushort* lAw = &lA[srow * 72 + shalf * 32];
    ushort* lBw = &lB[srow * 72 + shalf * 32];

    const ushort* aRd = &lA[(wm * 64 + lane15) * 72 + quad * 8];
    const ushort* bRd = &lB[(wn * 64 + lane15) * 72 + quad * 8];

    f32x4 zero = {0.f, 0.f, 0.f, 0.f};
    f32x4 acc[4][4];
    #pragma unroll
    for (int i = 0; i < 4; i++)
        #pragma unroll
        for (int j = 0; j < 4; j++) acc[i][j] = zero;

    for (int kb = 0; kb < 162; kb++) {
        int k81 = kb >> 1;
        int ky = k81 / 9, kx = k81 - ky * 9;
        int goffA = kb * 64 + shalf * 32;
        int goffB = (ky * 20 + kx) * 128 + (kb & 1) * 64 + shalf * 32;

        const uint4* ga = (const uint4*)(Abase + goffA);
        const uint4* gb = (const uint4*)(Bbase + goffB);
        uint4 av0 = ga[0], av1 = ga[1], av2 = ga[2], av3 = ga[3];
        uint4 bv0 = gb[0], bv1 = gb[1], bv2 = gb[2], bv3 = gb[3];

        __syncthreads();               // previous iter's LDS reads complete
        ((uint4*)lAw)[0] = av0; ((uint4*)lAw)[1] = av1;
        ((uint4*)lAw)[2] = av2; ((uint4*)lAw)[3] = av3;
        ((uint4*)lBw)[0] = bv0; ((uint4*)lBw)[1] = bv1;
        ((uint4*)lBw)[2] = bv2; ((uint4*)lBw)[3] = bv3;
        __syncthreads();

        #pragma unroll
        for (int kk = 0; kk < 2; kk++) {
            bf16x8 af[4], bf[4];
            #pragma unroll
            for (int tm = 0; tm < 4; tm++)
                af[tm] = *(const bf16x8*)(aRd + tm * 16 * 72 + kk * 32);
            #pragma unroll
            for (int tn = 0; tn < 4; tn++)
                bf[tn] = *(const bf16x8*)(bRd + tn * 16 * 72 + kk * 32);
            #pragma unroll
            for (int tm = 0; tm < 4; tm++)
                #pragma unroll
                for (int tn = 0; tn < 4; tn++)
                    acc[tm][tn] = __builtin_amdgcn_mfma_f32_16x16x32_bf16(
                        af[tm], bf[tn], acc[tm][tn], 0, 0, 0);
        }
    }

    // epilogue: D[m][n], n = lane15, m = quad*4 + reg
    #pragma unroll
    for (int tm = 0; tm < 4; tm++) {
        int m0 = bm * 128 + wm * 64 + tm * 16 + quad * 4;
        #pragma unroll
        for (int tn = 0; tn < 4; tn++) {
            int nn = bn * 128 + wn * 64 + tn * 16 + lane15;
            int ob = nn / 36, os = nn % 36;
            float* up = u + ob * 9216 + os;
            f32x4 a = acc[tm][tn];
            #pragma unroll
            for (int r = 0; r < 4; r++)
                up[(m0 + r) * 36] = a[r] + pb[m0 + r];
        }
    }
}

// ---------------- squash u (groups of 8 flat elements), in place ----------------
__global__ __launch_bounds__(256) void k_squash(float* __restrict__ u)
{
    int t = blockIdx.x * 256 + threadIdx.x;              // 256*1152 threads
    float4 a = *(const float4*)(u + t * 8);
    float4 b = *(const float4*)(u + t * 8 + 4);
    float sn = a.x*a.x + a.y*a.y + a.z*a.z + a.w*a.w
             + b.x*b.x + b.y*b.y + b.z*b.z + b.w*b.w;
    float sc = sqrtf(sn) / (1.f + sn);
    a.x*=sc; a.y*=sc; a.z*=sc; a.w*=sc; b.x*=sc; b.y*=sc; b.z*=sc; b.w*=sc;
    *(float4*)(u + t * 8) = a;
    *(float4*)(u + t * 8 + 4) = b;
}

// ---------------- u_hat[r][b][co] = sum_i W[r,co,i]*u[b,r,i]  (bf16 out) -------
// 2 co per thread -> 4B stores
__global__ __launch_bounds__(256) void k_uhat(
    const float* __restrict__ u, const float* __restrict__ W,
    __hip_bfloat16* __restrict__ uhat)
{
    int t = blockIdx.x * 256 + threadIdx.x;              // 1152*256*80 threads
    int co2 = t % 80, b = (t / 80) & 255, r = t / 20480;
    const float4* up = (const float4*)(u + (b * 1152 + r) * 8);
    float4 u0 = up[0], u1 = up[1];
    const float4* wp = (const float4*)(W + (r * 160 + co2 * 2) * 8);
    float4 w0 = wp[0], w1 = wp[1], w2 = wp[2], w3 = wp[3];
    float s0 = u0.x*w0.x + u0.y*w0.y + u0.z*w0.z + u0.w*w0.w
             + u1.x*w1.x + u1.y*w1.y + u1.z*w1.z + u1.w*w1.w;
    float s1 = u0.x*w2.x + u0.y*w2.y + u0.z*w2.z + u0.w*w2.w
             + u1.x*w3.x + u1.y*w3.y + u1.z*w3.z + u1.w*w3.w;
    __hip_bfloat162 h;
    h.x = __float2bfloat16(s0);
    h.y = __float2bfloat16(s1);
    *(__hip_bfloat162*)(uhat + (size_t)t * 2) = h;
}

// ---------------- softmax over r per class: cij[c][r] ----------------
__global__ __launch_bounds__(256) void k_softmax(
    const float* __restrict__ bij, float* __restrict__ cij)
{
    int c = blockIdx.x, tid = threadIdx.x;
    __shared__ float red[256];
    const float* bp = bij + c * 1152;
    float mx = -1e30f;
    for (int r = tid; r < 1152; r += 256) mx = fmaxf(mx, bp[r]);
    red[tid] = mx; __syncthreads();
    for (int s = 128; s > 0; s >>= 1) { if (tid < s) red[tid] = fmaxf(red[tid], red[tid + s]); __syncthreads(); }
    mx = red[0]; __syncthreads();
    float sum = 0.f;
    for (int r = tid; r < 1152; r += 256) sum += expf(bp[r] - mx);
    red[tid] = sum; __syncthreads();
    for (int s = 128; s > 0; s >>= 1) { if (tid < s) red[tid] += red[tid + s]; __syncthreads(); }
    float inv = 1.f / red[0];
    for (int r = tid; r < 1152; r += 256) cij[c * 1152 + r] = expf(bp[r] - mx) * inv;
}

// ---------------- s_j + elementwise squash -> v[b][c][o] (+ final output) -------
__global__ __launch_bounds__(256) void k_sj_vj(
    const __hip_bfloat16* __restrict__ uhat, const float* __restrict__ cij,
    float* __restrict__ v, float* __restrict__ out, int write_out)
{
    int bc = blockIdx.x;                                  // 2560 blocks
    int c = bc % 10, b = bc / 10;
    int tid = threadIdx.x, o = tid & 15, rs = tid >> 4;
    float acc = 0.f;
    for (int r = rs; r < 1152; r += 16) {
        float cc = cij[c * 1152 + r];
        float uh = __bfloat162float(uhat[(r * 256 + b) * 160 + c * 16 + o]);
        acc += cc * uh;
    }
    __shared__ float red[16][17];
    red[rs][o] = acc; __syncthreads();
    if (tid < 16) {
        float s = 0.f;
        #pragma unroll
        for (int k = 0; k < 16; k++) s += red[k][tid];
        float vv = s * fabsf(s) / (1.f + s * s);
        v[(b * 10 + c) * 16 + tid] = vv;
        if (write_out) out[(b * 10 + c) * 16 + tid] = vv;
    }
}

// ---------------- a_ij = mean_b <u_hat, v>; b_ij += a ----------------
__global__ __launch_bounds__(256) void k_aij(
    const __hip_bfloat16* __restrict__ uhat, const float* __restrict__ v,
    float* __restrict__ bij)
{
    int r = blockIdx.x, tid = threadIdx.x;
    __shared__ float red[160];
    if (tid < 160) {
        float acc = 0.f;
        for (int b = 0; b < 256; b++)
            acc += __bfloat162float(uhat[(r * 256 + b) * 160 + tid]) * v[b * 160 + tid];
        red[tid] = acc;
    }
    __syncthreads();
    if (tid < 10) {
        float s = 0.f;
        #pragma unroll
        for (int k = 0; k < 16; k++) s += red[tid * 16 + k];
        bij[tid * 1152 + r] += s * (1.f / 256.f);
    }
}

// ---------------- classifiers: sigmoid(w2 . relu(w1 . feat + b1) + b2) ----------
__global__ __launch_bounds__(128) void k_cls(
    const float* __restrict__ v, const float* __restrict__ w1,
    const float* __restrict__ b1, const float* __restrict__ w2,
    const float* __restrict__ b2, float* __restrict__ out)
{
    int bk = blockIdx.x;                                  // 2560 blocks
    int k = bk % 10, b = bk / 10;
    int tid = threadIdx.x;
    __shared__ float feat[160];
    __shared__ float red[128];
    for (int f = tid; f < 160; f += 128) feat[f] = v[b * 160 + f];
    __syncthreads();
    float h = 0.f;
    if (tid < 100) {
        float a = b1[k * 100 + tid];
        for (int f = 0; f < 160; f++) a += feat[f] * w1[(k * 160 + f) * 100 + tid];
        h = fmaxf(a, 0.f) * w2[k * 100 + tid];
    }
    red[tid] = h; __syncthreads();
    for (int s = 64; s > 0; s >>= 1) { if (tid < s) red[tid] += red[tid + s]; __syncthreads(); }
    if (tid == 0) {
        float logit = red[0] + b2[k];
        out[40960 + b * 10 + k] = 1.f / (1.f + expf(-logit));
    }
}

extern "C" void kernel_launch(void* const* d_in, const int* in_sizes, int n_in,
                              void* d_out, int out_size, void* d_ws, size_t ws_size,
                              hipStream_t stream) {
    const float* data    = (const float*)d_in[0];
    const float* conv1_w = (const float*)d_in[1];
    const float* conv1_b = (const float*)d_in[2];
    const float* conv2_w = (const float*)d_in[3];
    const float* conv2_b = (const float*)d_in[4];
    const float* prim_w  = (const float*)d_in[5];
    const float* prim_b  = (const float*)d_in[6];
    const float* W       = (const float*)d_in[7];
    const float* cls_w1  = (const float*)d_in[8];
    const float* cls_b1  = (const float*)d_in[9];
    const float* cls_w2  = (const float*)d_in[10];
    const float* cls_b2  = (const float*)d_in[11];
    float* out = (float*)d_out;

    char* ws = (char*)d_ws;
    // P1 region (94,633,984 B) later reused for bf16 u_hat (94,371,840 B)
    float*          P1   = (float*)(ws + 0);
    __hip_bfloat16* uhat = (__hip_bfloat16*)(ws + 0);
    __hip_bfloat16* P2   = (__hip_bfloat16*)(ws + 94633984);   // 26,214,400
    __hip_bfloat16* P2t  = (__hip_bfloat16*)(ws + 120848384);  // 26,214,400
    float*          u    = (float*)(ws + 147062784);           //  9,437,184
    __hip_bfloat16* Awt  = (__hip_bfloat16*)(ws + 156499968);  //  5,308,416
    float*          v    = (float*)(ws + 161808384);           //    163,840
    float*          bij  = (float*)(ws + 161972224);           //     46,080
    float*          cij  = (float*)(ws + 162018304);           //     46,080
    // total: 162,064,384 bytes (<= round-1 footprint of 167,372,800)

    hipMemsetAsync(bij, 0, 11520 * sizeof(float), stream);

    k_conv1_pool<<<92416, 256, 0, stream>>>(data, conv1_w, conv1_b, P1);
    k_prep_awt<<<10368, 256, 0, stream>>>(prim_w, Awt);
    k_conv2_pool<<<12800, 256, 0, stream>>>(P1, conv2_w, conv2_b, P2);
    k_transpose_p2<<<51200, 256, 0, stream>>>(P2, P2t);
    k_primcaps_mfma<<<144, 256, 0, stream>>>(P2t, Awt, prim_b, u);
    k_squash<<<1152, 256, 0, stream>>>(u);
    k_uhat<<<92160, 256, 0, stream>>>(u, W, uhat);

    for (int it = 0; it < 3; it++) {
        k_softmax<<<10, 256, 0, stream>>>(bij, cij);
        k_sj_vj<<<2560, 256, 0, stream>>>(uhat, cij, v, out, it == 2 ? 1 : 0);
        if (it < 2) k_aij<<<1152, 256, 0, stream>>>(uhat, v, bij);
    }
    k_cls<<<2560, 128, 0, stream>>>(v, cls_w1, cls_b1, cls_w2, cls_b2, out);
}

// Round 3
// 1177.394 us; speedup vs baseline: 5.7038x; 3.1035x over previous
//
#include <hip/hip_runtime.h>
#include <hip/hip_bf16.h>

// CapsNet forward. Round 3: conv2 -> bf16 MFMA implicit GEMM (like primcaps).
// B=256, R=1152, C=10, O=16, I=8

typedef __bf16 bf16x8 __attribute__((ext_vector_type(8)));
typedef float  f32x4  __attribute__((ext_vector_type(4)));

static __device__ __forceinline__ ushort f2bf(float f) {
    __hip_bfloat16 h = __float2bfloat16(f);
    return *(ushort*)&h;
}

// ---------------- conv1(3->64,3x3,s1,p0) + relu + maxpool(2,2,p1) ----------------
// out: P1t [256,38,38,64] bf16 (ic innermost). Lane covers oc -> coalesced writes;
// all 64 lanes of a wave share one (b,py,px) -> data tile loads are wave-uniform.
__global__ __launch_bounds__(256) void k_conv1_pool_t(
    const float* __restrict__ data, const float* __restrict__ w1,
    const float* __restrict__ b1, __hip_bfloat16* __restrict__ P1t)
{
    int t = blockIdx.x * 256 + threadIdx.x;              // 256*1444*64 threads
    int oc = t & 63, p = t >> 6;
    int px = p % 38, py = (p / 38) % 38, b = p / 1444;

    float w[27];
    const float* wp = w1 + oc * 27;
    #pragma unroll
    for (int i = 0; i < 27; i++) w[i] = wp[i];
    float bias = b1[oc];

    int y0 = 2 * py - 1, x0 = 2 * px - 1;
    float tile[3][4][4];
    #pragma unroll
    for (int ic = 0; ic < 3; ic++) {
        const float* dp = data + (b * 3 + ic) * 5776;
        #pragma unroll
        for (int i = 0; i < 4; i++) {
            int y = y0 + i;
            #pragma unroll
            for (int j = 0; j < 4; j++) {
                int x = x0 + j;
                bool ok = ((unsigned)y < 76u) && ((unsigned)x < 76u);
                tile[ic][i][j] = ok ? dp[y * 76 + x] : 0.f;
            }
        }
    }
    float m = 0.f;   // relu >= 0 so 0 is a safe identity for the max
    #pragma unroll
    for (int dy = 0; dy < 2; dy++) {
        int y = y0 + dy;
        if ((unsigned)y >= 74u) continue;
        #pragma unroll
        for (int dx = 0; dx < 2; dx++) {
            int x = x0 + dx;
            if ((unsigned)x >= 74u) continue;
            float v = bias;
            #pragma unroll
            for (int ic = 0; ic < 3; ic++)
                #pragma unroll
                for (int ky = 0; ky < 3; ky++)
                    #pragma unroll
                    for (int kx = 0; kx < 3; kx++)
                        v += tile[ic][dy + ky][dx + kx] * w[ic * 9 + ky * 3 + kx];
            m = fmaxf(m, fmaxf(v, 0.f));
        }
    }
    P1t[t] = __float2bfloat16(m);                        // [b][py][px][oc]
}

// ---------------- conv2_w (128,64,3,3) fp32 -> Aw2 [oc][(ky*3+kx)*64+ic] bf16 ----
__global__ __launch_bounds__(256) void k_prep_aw2(
    const float* __restrict__ w2, __hip_bfloat16* __restrict__ Aw2)
{
    int t = blockIdx.x * 256 + threadIdx.x;              // 128*576 threads
    int oc = t / 576, rem = t % 576;
    int k9 = rem >> 6, ic = rem & 63;
    Aw2[t] = __float2bfloat16(w2[(oc * 64 + ic) * 9 + k9]);
}

// ---------------- conv2 as MFMA GEMM + bias + relu ------------------------------
// M=128 (oc, single tile), N=369664 (2888 tiles of 128: b*1444+y*38+x), K=576
// out: Q [256][38][38][128] bf16 (oc innermost)
__global__ __launch_bounds__(256) void k_conv2_mfma(
    const __hip_bfloat16* __restrict__ P1t,   // [256][38][38][64]
    const __hip_bfloat16* __restrict__ Aw2,   // [128][576]
    const float* __restrict__ cb,             // [128]
    __hip_bfloat16* __restrict__ Q)
{
    __shared__ ushort lA[128 * 72];   // row stride 72 elems = 144 B
    __shared__ ushort lB[128 * 72];
    const int tid  = threadIdx.x;
    const int bn   = blockIdx.x;              // 2888 N-blocks
    const int wave = tid >> 6, lane = tid & 63;
    const int wm   = wave & 1, wn = wave >> 1;
    const int lane15 = lane & 15, quad = lane >> 4;
    const int srow = tid & 127, shalf = tid >> 7;

    // B column decode: n -> (b, y, x) pre-pool conv2 output position
    int n = bn * 128 + srow;
    int b = n / 1444, yx = n % 1444;
    int y = yx / 38, x = yx % 38;

    const __hip_bfloat16* Abase = Aw2 + srow * 576;
    ushort* lAw = &lA[srow * 72 + shalf * 32];
    ushort* lBw = &lB[srow * 72 + shalf * 32];
    const ushort* aRd = &lA[(wm * 64 + lane15) * 72 + quad * 8];
    const ushort* bRd = &lB[(wn * 64 + lane15) * 72 + quad * 8];

    f32x4 zero = {0.f, 0.f, 0.f, 0.f};
    f32x4 acc[4][4];
    #pragma unroll
    for (int i = 0; i < 4; i++)
        #pragma unroll
        for (int j = 0; j < 4; j++) acc[i][j] = zero;

    for (int kb = 0; kb < 9; kb++) {                      // tap (ky,kx), 64 ic each
        int ky = kb / 3, kx = kb - ky * 3;
        int iy = y + ky - 1, ix = x + kx - 1;
        bool ok = ((unsigned)iy < 38u) && ((unsigned)ix < 38u);

        const uint4* ga = (const uint4*)(Abase + kb * 64 + shalf * 32);
        uint4 av0 = ga[0], av1 = ga[1], av2 = ga[2], av3 = ga[3];
        uint4 z4 = {0u, 0u, 0u, 0u};
        uint4 bv0 = z4, bv1 = z4, bv2 = z4, bv3 = z4;
        if (ok) {
            const uint4* gb = (const uint4*)(P1t + (((b * 38 + iy) * 38 + ix) << 6) + shalf * 32);
            bv0 = gb[0]; bv1 = gb[1]; bv2 = gb[2]; bv3 = gb[3];
        }

        __syncthreads();
        ((uint4*)lAw)[0] = av0; ((uint4*)lAw)[1] = av1;
        ((uint4*)lAw)[2] = av2; ((uint4*)lAw)[3] = av3;
        ((uint4*)lBw)[0] = bv0; ((uint4*)lBw)[1] = bv1;
        ((uint4*)lBw)[2] = bv2; ((uint4*)lBw)[3] = bv3;
        __syncthreads();

        #pragma unroll
        for (int kk = 0; kk < 2; kk++) {
            bf16x8 af[4], bf[4];
            #pragma unroll
            for (int tm = 0; tm < 4; tm++)
                af[tm] = *(const bf16x8*)(aRd + tm * 16 * 72 + kk * 32);
            #pragma unroll
            for (int tn = 0; tn < 4; tn++)
                bf[tn] = *(const bf16x8*)(bRd + tn * 16 * 72 + kk * 32);
            #pragma unroll
            for (int tm = 0; tm < 4; tm++)
                #pragma unroll
                for (int tn = 0; tn < 4; tn++)
                    acc[tm][tn] = __builtin_amdgcn_mfma_f32_16x16x32_bf16(
                        af[tm], bf[tn], acc[tm][tn], 0, 0, 0);
        }
    }

    // epilogue: D[m][n] -> Q[n*128 + m], relu(val+bias), 4 bf16 packed per store
    #pragma unroll
    for (int tm = 0; tm < 4; tm++) {
        int m0 = wm * 64 + tm * 16 + quad * 4;
        float b0 = cb[m0], b1 = cb[m0 + 1], b2 = cb[m0 + 2], b3 = cb[m0 + 3];
        #pragma unroll
        for (int tn = 0; tn < 4; tn++) {
            int nn = bn * 128 + wn * 64 + tn * 16 + lane15;
            f32x4 a = acc[tm][tn];
            ushort4 pk;
            pk.x = f2bf(fmaxf(a[0] + b0, 0.f));
            pk.y = f2bf(fmaxf(a[1] + b1, 0.f));
            pk.z = f2bf(fmaxf(a[2] + b2, 0.f));
            pk.w = f2bf(fmaxf(a[3] + b3, 0.f));
            *(ushort4*)((ushort*)Q + (size_t)nn * 128 + m0) = pk;
        }
    }
}

// ---------------- maxpool(2,2,p1) over Q -> P2t [256][20][20][128] ----------------
__global__ __launch_bounds__(256) void k_pool2t(
    const __hip_bfloat16* __restrict__ Q, __hip_bfloat16* __restrict__ P2t)
{
    int t = blockIdx.x * 256 + threadIdx.x;              // 256*400*128 threads
    int ic = t & 127, rest = t >> 7;
    int px = rest % 20, py = (rest / 20) % 20, b = rest / 400;
    float m = 0.f;                                       // Q >= 0 (relu'd)
    #pragma unroll
    for (int dy = 0; dy < 2; dy++) {
        int y = 2 * py - 1 + dy;
        if ((unsigned)y >= 38u) continue;
        #pragma unroll
        for (int dx = 0; dx < 2; dx++) {
            int x = 2 * px - 1 + dx;
            if ((unsigned)x >= 38u) continue;
            m = fmaxf(m, __bfloat162float(Q[(((b * 38 + y) * 38 + x) << 7) + ic]));
        }
    }
    P2t[t] = __float2bfloat16(m);
}

// ---------------- prim_w (256,128,81) fp32 -> Awt [oc][(ky*9+kx)*128+ic] bf16 ----
__global__ __launch_bounds__(256) void k_prep_awt(
    const float* __restrict__ pw, __hip_bfloat16* __restrict__ Awt)
{
    int t = blockIdx.x * 256 + threadIdx.x;              // 256*10368 threads
    int oc = t / 10368, rem = t % 10368;
    int k81 = rem >> 7, ic = rem & 127;
    Awt[t] = __float2bfloat16(pw[(oc * 128 + ic) * 81 + k81]);
}

// ---------------- primcaps as MFMA GEMM: u[oc][n] = Awt[oc][:] . patch[:][n] ------
// M=256 (2 blocks of 128), N=9216 (72 blocks of 128), K=10368 (162 iters of 64)
__global__ __launch_bounds__(256) void k_primcaps_mfma(
    const __hip_bfloat16* __restrict__ P2t,   // [256][20][20][128]
    const __hip_bfloat16* __restrict__ Awt,   // [256][10368]
    const float* __restrict__ pb,             // [256]
    float* __restrict__ u)
{
    __shared__ ushort lA[128 * 72];
    __shared__ ushort lB[128 * 72];
    const int tid  = threadIdx.x;
    const int bm   = blockIdx.x & 1;
    const int bn   = blockIdx.x >> 1;
    const int wave = tid >> 6, lane = tid & 63;
    const int wm   = wave & 1, wn = wave >> 1;
    const int lane15 = lane & 15, quad = lane >> 4;
    const int srow = tid & 127, shalf = tid >> 7;

    int n  = bn * 128 + srow;
    int cb = n / 36, cs = n % 36;
    int cy = cs / 6, cx = cs % 6;
    const __hip_bfloat16* Bbase = P2t + ((cb * 20 + 2 * cy) * 20 + 2 * cx) * 128;
    const __hip_bfloat16* Abase = Awt + (bm * 128 + srow) * 10368;
    ushort* lAw = &lA[srow * 72 + shalf * 32];
    ushort* lBw = &lB[srow * 72 + shalf * 32];
    const ushort* aRd = &lA[(wm * 64 + lane15) * 72 + quad * 8];
    const ushort* bRd = &lB[(wn * 64 + lane15) * 72 + quad * 8];

    f32x4 zero = {0.f, 0.f, 0.f, 0.f};
    f32x4 acc[4][4];
    #pragma unroll
    for (int i = 0; i < 4; i++)
        #pragma unroll
        for (int j = 0; j < 4; j++) acc[i][j] = zero;

    for (int kb = 0; kb < 162; kb++) {
        int k81 = kb >> 1;
        int ky = k81 / 9, kx = k81 - ky * 9;
        int goffA = kb * 64 + shalf * 32;
        int goffB = (ky * 20 + kx) * 128 + (kb & 1) * 64 + shalf * 32;

        const uint4* ga = (const uint4*)(Abase + goffA);
        const uint4* gb = (const uint4*)(Bbase + goffB);
        uint4 av0 = ga[0], av1 = ga[1], av2 = ga[2], av3 = ga[3];
        uint4 bv0 = gb[0], bv1 = gb[1], bv2 = gb[2], bv3 = gb[3];

        __syncthreads();
        ((uint4*)lAw)[0] = av0; ((uint4*)lAw)[1] = av1;
        ((uint4*)lAw)[2] = av2; ((uint4*)lAw)[3] = av3;
        ((uint4*)lBw)[0] = bv0; ((uint4*)lBw)[1] = bv1;
        ((uint4*)lBw)[2] = bv2; ((uint4*)lBw)[3] = bv3;
        __syncthreads();

        #pragma unroll
        for (int kk = 0; kk < 2; kk++) {
            bf16x8 af[4], bf[4];
            #pragma unroll
            for (int tm = 0; tm < 4; tm++)
                af[tm] = *(const bf16x8*)(aRd + tm * 16 * 72 + kk * 32);
            #pragma unroll
            for (int tn = 0; tn < 4; tn++)
                bf[tn] = *(const bf16x8*)(bRd + tn * 16 * 72 + kk * 32);
            #pragma unroll
            for (int tm = 0; tm < 4; tm++)
                #pragma unroll
                for (int tn = 0; tn < 4; tn++)
                    acc[tm][tn] = __builtin_amdgcn_mfma_f32_16x16x32_bf16(
                        af[tm], bf[tn], acc[tm][tn], 0, 0, 0);
        }
    }

    #pragma unroll
    for (int tm = 0; tm < 4; tm++) {
        int m0 = bm * 128 + wm * 64 + tm * 16 + quad * 4;
        #pragma unroll
        for (int tn = 0; tn < 4; tn++) {
            int nn = bn * 128 + wn * 64 + tn * 16 + lane15;
            int ob = nn / 36, os = nn % 36;
            float* up = u + ob * 9216 + os;
            f32x4 a = acc[tm][tn];
            #pragma unroll
            for (int r = 0; r < 4; r++)
                up[(m0 + r) * 36] = a[r] + pb[m0 + r];
        }
    }
}

// ---------------- squash u (groups of 8 flat elements), in place ----------------
__global__ __launch_bounds__(256) void k_squash(float* __restrict__ u)
{
    int t = blockIdx.x * 256 + threadIdx.x;              // 256*1152 threads
    float4 a = *(const float4*)(u + t * 8);
    float4 b = *(const float4*)(u + t * 8 + 4);
    float sn = a.x*a.x + a.y*a.y + a.z*a.z + a.w*a.w
             + b.x*b.x + b.y*b.y + b.z*b.z + b.w*b.w;
    float sc = sqrtf(sn) / (1.f + sn);
    a.x*=sc; a.y*=sc; a.z*=sc; a.w*=sc; b.x*=sc; b.y*=sc; b.z*=sc; b.w*=sc;
    *(float4*)(u + t * 8) = a;
    *(float4*)(u + t * 8 + 4) = b;
}

// ---------------- u_hat[r][b][co] = sum_i W[r,co,i]*u[b,r,i]  (bf16 out) -------
__global__ __launch_bounds__(256) void k_uhat(
    const float* __restrict__ u, const float* __restrict__ W,
    __hip_bfloat16* __restrict__ uhat)
{
    int t = blockIdx.x * 256 + threadIdx.x;              // 1152*256*80 threads
    int co2 = t % 80, b = (t / 80) & 255, r = t / 20480;
    const float4* up = (const float4*)(u + (b * 1152 + r) * 8);
    float4 u0 = up[0], u1 = up[1];
    const float4* wp = (const float4*)(W + (r * 160 + co2 * 2) * 8);
    float4 w0 = wp[0], w1 = wp[1], w2 = wp[2], w3 = wp[3];
    float s0 = u0.x*w0.x + u0.y*w0.y + u0.z*w0.z + u0.w*w0.w
             + u1.x*w1.x + u1.y*w1.y + u1.z*w1.z + u1.w*w1.w;
    float s1 = u0.x*w2.x + u0.y*w2.y + u0.z*w2.z + u0.w*w2.w
             + u1.x*w3.x + u1.y*w3.y + u1.z*w3.z + u1.w*w3.w;
    __hip_bfloat162 h;
    h.x = __float2bfloat16(s0);
    h.y = __float2bfloat16(s1);
    *(__hip_bfloat162*)(uhat + (size_t)t * 2) = h;
}

// ---------------- softmax over r per class: cij[c][r] ----------------
__global__ __launch_bounds__(256) void k_softmax(
    const float* __restrict__ bij, float* __restrict__ cij)
{
    int c = blockIdx.x, tid = threadIdx.x;
    __shared__ float red[256];
    const float* bp = bij + c * 1152;
    float mx = -1e30f;
    for (int r = tid; r < 1152; r += 256) mx = fmaxf(mx, bp[r]);
    red[tid] = mx; __syncthreads();
    for (int s = 128; s > 0; s >>= 1) { if (tid < s) red[tid] = fmaxf(red[tid], red[tid + s]); __syncthreads(); }
    mx = red[0]; __syncthreads();
    float sum = 0.f;
    for (int r = tid; r < 1152; r += 256) sum += expf(bp[r] - mx);
    red[tid] = sum; __syncthreads();
    for (int s = 128; s > 0; s >>= 1) { if (tid < s) red[tid] += red[tid + s]; __syncthreads(); }
    float inv = 1.f / red[0];
    for (int r = tid; r < 1152; r += 256) cij[c * 1152 + r] = expf(bp[r] - mx) * inv;
}

// ---------------- s_j + elementwise squash -> v[b][c][o] (+ final output) -------
__global__ __launch_bounds__(256) void k_sj_vj(
    const __hip_bfloat16* __restrict__ uhat, const float* __restrict__ cij,
    float* __restrict__ v, float* __restrict__ out, int write_out)
{
    int bc = blockIdx.x;                                  // 2560 blocks
    int c = bc % 10, b = bc / 10;
    int tid = threadIdx.x, o = tid & 15, rs = tid >> 4;
    float acc = 0.f;
    for (int r = rs; r < 1152; r += 16) {
        float cc = cij[c * 1152 + r];
        float uh = __bfloat162float(uhat[(r * 256 + b) * 160 + c * 16 + o]);
        acc += cc * uh;
    }
    __shared__ float red[16][17];
    red[rs][o] = acc; __syncthreads();
    if (tid < 16) {
        float s = 0.f;
        #pragma unroll
        for (int k = 0; k < 16; k++) s += red[k][tid];
        float vv = s * fabsf(s) / (1.f + s * s);
        v[(b * 10 + c) * 16 + tid] = vv;
        if (write_out) out[(b * 10 + c) * 16 + tid] = vv;
    }
}

// ---------------- a_ij = mean_b <u_hat, v>; b_ij += a ----------------
__global__ __launch_bounds__(256) void k_aij(
    const __hip_bfloat16* __restrict__ uhat, const float* __restrict__ v,
    float* __restrict__ bij)
{
    int r = blockIdx.x, tid = threadIdx.x;
    __shared__ float red[160];
    if (tid < 160) {
        float acc = 0.f;
        for (int b = 0; b < 256; b++)
            acc += __bfloat162float(uhat[(r * 256 + b) * 160 + tid]) * v[b * 160 + tid];
        red[tid] = acc;
    }
    __syncthreads();
    if (tid < 10) {
        float s = 0.f;
        #pragma unroll
        for (int k = 0; k < 16; k++) s += red[tid * 16 + k];
        bij[tid * 1152 + r] += s * (1.f / 256.f);
    }
}

// ---------------- classifiers: sigmoid(w2 . relu(w1 . feat + b1) + b2) ----------
__global__ __launch_bounds__(128) void k_cls(
    const float* __restrict__ v, const float* __restrict__ w1,
    const float* __restrict__ b1, const float* __restrict__ w2,
    const float* __restrict__ b2, float* __restrict__ out)
{
    int bk = blockIdx.x;                                  // 2560 blocks
    int k = bk % 10, b = bk / 10;
    int tid = threadIdx.x;
    __shared__ float feat[160];
    __shared__ float red[128];
    for (int f = tid; f < 160; f += 128) feat[f] = v[b * 160 + f];
    __syncthreads();
    float h = 0.f;
    if (tid < 100) {
        float a = b1[k * 100 + tid];
        for (int f = 0; f < 160; f++) a += feat[f] * w1[(k * 160 + f) * 100 + tid];
        h = fmaxf(a, 0.f) * w2[k * 100 + tid];
    }
    red[tid] = h; __syncthreads();
    for (int s = 64; s > 0; s >>= 1) { if (tid < s) red[tid] += red[tid + s]; __syncthreads(); }
    if (tid == 0) {
        float logit = red[0] + b2[k];
        out[40960 + b * 10 + k] = 1.f / (1.f + expf(-logit));
    }
}

extern "C" void kernel_launch(void* const* d_in, const int* in_sizes, int n_in,
                              void* d_out, int out_size, void* d_ws, size_t ws_size,
                              hipStream_t stream) {
    const float* data    = (const float*)d_in[0];
    const float* conv1_w = (const float*)d_in[1];
    const float* conv1_b = (const float*)d_in[2];
    const float* conv2_w = (const float*)d_in[3];
    const float* conv2_b = (const float*)d_in[4];
    const float* prim_w  = (const float*)d_in[5];
    const float* prim_b  = (const float*)d_in[6];
    const float* W       = (const float*)d_in[7];
    const float* cls_w1  = (const float*)d_in[8];
    const float* cls_b1  = (const float*)d_in[9];
    const float* cls_w2  = (const float*)d_in[10];
    const float* cls_b2  = (const float*)d_in[11];
    float* out = (float*)d_out;

    char* ws = (char*)d_ws;
    // Q (94,633,984 B) reused for bf16 uhat (94,371,840 B) after k_pool2t.
    // P1t (47,316,992 B) reused for P2t (13,107,200 B) after k_conv2_mfma.
    __hip_bfloat16* Q    = (__hip_bfloat16*)(ws + 0);
    __hip_bfloat16* uhat = (__hip_bfloat16*)(ws + 0);
    __hip_bfloat16* P1t  = (__hip_bfloat16*)(ws + 94633984);
    __hip_bfloat16* P2t  = (__hip_bfloat16*)(ws + 94633984);
    float*          u    = (float*)(ws + 141950976);           // 9,437,184
    __hip_bfloat16* Awt  = (__hip_bfloat16*)(ws + 151388160);  // 5,308,416
    __hip_bfloat16* Aw2  = (__hip_bfloat16*)(ws + 156696576);  //   147,456
    float*          v    = (float*)(ws + 156844032);           //   163,840
    float*          bij  = (float*)(ws + 157007872);           //    46,080
    float*          cij  = (float*)(ws + 157053952);           //    46,080
    // total: 157,100,032 bytes

    hipMemsetAsync(bij, 0, 11520 * sizeof(float), stream);

    k_conv1_pool_t<<<92416, 256, 0, stream>>>(data, conv1_w, conv1_b, P1t);
    k_prep_aw2<<<288, 256, 0, stream>>>(conv2_w, Aw2);
    k_prep_awt<<<10368, 256, 0, stream>>>(prim_w, Awt);
    k_conv2_mfma<<<2888, 256, 0, stream>>>(P1t, Aw2, conv2_b, Q);
    k_pool2t<<<51200, 256, 0, stream>>>(Q, P2t);
    k_primcaps_mfma<<<144, 256, 0, stream>>>(P2t, Awt, prim_b, u);
    k_squash<<<1152, 256, 0, stream>>>(u);
    k_uhat<<<92160, 256, 0, stream>>>(u, W, uhat);

    for (int it = 0; it < 3; it++) {
        k_softmax<<<10, 256, 0, stream>>>(bij, cij);
        k_sj_vj<<<2560, 256, 0, stream>>>(uhat, cij, v, out, it == 2 ? 1 : 0);
        if (it < 2) k_aij<<<1152, 256, 0, stream>>>(uhat, v, bij);
    }
    k_cls<<<2560, 128, 0, stream>>>(v, cls_w1, cls_b1, cls_w2, cls_b2, out);
}

// Round 4
// 957.489 us; speedup vs baseline: 7.0138x; 1.2297x over previous
//
#include <hip/hip_runtime.h>
#include <hip/hip_bf16.h>

// CapsNet forward. Round 4: conv1 -> single-K-step MFMA with fused relu+pool.
// B=256, R=1152, C=10, O=16, I=8

typedef __bf16 bf16x8 __attribute__((ext_vector_type(8)));
typedef float  f32x4  __attribute__((ext_vector_type(4)));

static __device__ __forceinline__ ushort f2bf(float f) {
    __hip_bfloat16 h = __float2bfloat16(f);
    return *(ushort*)&h;
}

// ---------------- conv1_w (64,3,3,3) fp32 -> Aw1 [oc][k=ic*9+ky*3+kx] bf16, K pad 32
__global__ __launch_bounds__(256) void k_prep_aw1(
    const float* __restrict__ w1, __hip_bfloat16* __restrict__ Aw1)
{
    int t = blockIdx.x * 256 + threadIdx.x;              // 2048 threads
    int oc = t >> 5, k = t & 31;
    Aw1[t] = __float2bfloat16(k < 27 ? w1[oc * 27 + k] : 0.f);
}

// ---------------- conv1(3->64,3x3,s1,p0) + relu + maxpool(2,2,p1) via MFMA -------
// One block per (b, pooled row py). LDS tile: 3ic x 4 rows x 78 cols fp32.
// Wave wm owns oc tile [wm*16, wm*16+16); 5 n-tile pairs cover 80 n_x positions
// (n_x = conv x + 1) for conv rows 2py-1 (dy=0) and 2py (dy=1).
// out: P1t [256][38][38][64] bf16 (oc innermost).
__global__ __launch_bounds__(256) void k_conv1_mfma(
    const float* __restrict__ data, const __hip_bfloat16* __restrict__ Aw1,
    const float* __restrict__ b1, __hip_bfloat16* __restrict__ P1t)
{
    __shared__ float tile[960];          // [ic]*312 + [rloc]*78 + [lc]; lc = x_in+1
    const int tid = threadIdx.x;
    const int py = blockIdx.x % 38, b = blockIdx.x / 38;

    // stage input tile (zero-padded outside image)
    #pragma unroll
    for (int c = 0; c < 4; c++) {
        int idx = tid + c * 256;
        if (idx < 960) {
            float val = 0.f;
            if (idx < 936) {
                int ic = idx / 312, rem = idx % 312;
                int rl = rem / 78, lc = rem % 78;
                int ri = 2 * py - 1 + rl, xi = lc - 1;
                if ((unsigned)ri < 76u && (unsigned)xi < 76u)
                    val = data[(b * 3 + ic) * 5776 + ri * 76 + xi];
            }
            tile[idx] = val;
        }
    }

    const int wave = tid >> 6, lane = tid & 63;
    const int l15 = lane & 15, quad = lane >> 4;

    // A fragment: weights, m = l15 (oc within tile), k = quad*8+j
    bf16x8 af = *(const bf16x8*)((const ushort*)Aw1 + (wave * 16 + l15) * 32 + quad * 8);

    // per-lane k -> LDS offset table (k = quad*8+j)
    int koff[8]; bool kok[8];
    #pragma unroll
    for (int j = 0; j < 8; j++) {
        int kk = quad * 8 + j;
        kok[j] = kk < 27;
        int ic = kk / 9, rem = kk - ic * 9, ky = rem / 3, kx = rem - ky * 3;
        koff[j] = kok[j] ? (ic * 312 + ky * 78 + kx) : 0;
    }

    // bias for m = wave*16 + quad*4 + r
    float bias[4];
    #pragma unroll
    for (int r = 0; r < 4; r++) bias[r] = b1[wave * 16 + quad * 4 + r];

    const bool valid0 = (py > 0);        // conv row 2py-1 in [0,74)
    const bool valid1 = (py < 37);       // conv row 2py   in [0,74)

    __syncthreads();

    #pragma unroll
    for (int t5 = 0; t5 < 5; t5++) {
        int n_x = t5 * 16 + l15;                         // conv x = n_x - 1
        bool col_ok = (unsigned)(n_x - 1) < 74u;

        bf16x8 bf0, bf1;
        #pragma unroll
        for (int j = 0; j < 8; j++) {
            float v0 = tile[koff[j] + n_x];              // dy=0 patch value
            float v1 = tile[koff[j] + 78 + n_x];         // dy=1 patch value
            bool ok = col_ok && kok[j];
            bf0[j] = (__bf16)(ok ? v0 : 0.f);
            bf1[j] = (__bf16)(ok ? v1 : 0.f);
        }
        f32x4 z = {0.f, 0.f, 0.f, 0.f};
        f32x4 c0 = __builtin_amdgcn_mfma_f32_16x16x32_bf16(af, bf0, z, 0, 0, 0);
        f32x4 c1 = __builtin_amdgcn_mfma_f32_16x16x32_bf16(af, bf1, z, 0, 0, 0);

        // relu(conv+bias), excluded positions contribute 0 (safe: relu >= 0)
        f32x4 p;
        #pragma unroll
        for (int r = 0; r < 4; r++) {
            float r0 = (valid0 && col_ok) ? fmaxf(c0[r] + bias[r], 0.f) : 0.f;
            float r1 = (valid1 && col_ok) ? fmaxf(c1[r] + bias[r], 0.f) : 0.f;
            p[r] = fmaxf(r0, r1);
        }
        // x-pair pooling: lanes (n_x even, n_x odd)
        #pragma unroll
        for (int r = 0; r < 4; r++)
            p[r] = fmaxf(p[r], __shfl_xor(p[r], 1));

        if (!(l15 & 1)) {
            int px = t5 * 8 + (l15 >> 1);
            if (px < 38) {
                ushort4 pk;
                pk.x = f2bf(p[0]); pk.y = f2bf(p[1]);
                pk.z = f2bf(p[2]); pk.w = f2bf(p[3]);
                *(ushort4*)((ushort*)P1t + ((size_t)(b * 38 + py) * 38 + px) * 64
                            + wave * 16 + quad * 4) = pk;
            }
        }
    }
}

// ---------------- conv2_w (128,64,3,3) fp32 -> Aw2 [oc][(ky*3+kx)*64+ic] bf16 ----
__global__ __launch_bounds__(256) void k_prep_aw2(
    const float* __restrict__ w2, __hip_bfloat16* __restrict__ Aw2)
{
    int t = blockIdx.x * 256 + threadIdx.x;              // 128*576 threads
    int oc = t / 576, rem = t % 576;
    int k9 = rem >> 6, ic = rem & 63;
    Aw2[t] = __float2bfloat16(w2[(oc * 64 + ic) * 9 + k9]);
}

// ---------------- conv2 as MFMA GEMM + bias + relu ------------------------------
// M=128 (oc, single tile), N=369664 (2888 tiles of 128: b*1444+y*38+x), K=576
// out: Q [256][38][38][128] bf16 (oc innermost)
__global__ __launch_bounds__(256) void k_conv2_mfma(
    const __hip_bfloat16* __restrict__ P1t,   // [256][38][38][64]
    const __hip_bfloat16* __restrict__ Aw2,   // [128][576]
    const float* __restrict__ cb,             // [128]
    __hip_bfloat16* __restrict__ Q)
{
    __shared__ ushort lA[128 * 72];   // row stride 72 elems = 144 B
    __shared__ ushort lB[128 * 72];
    const int tid  = threadIdx.x;
    const int bn   = blockIdx.x;              // 2888 N-blocks
    const int wave = tid >> 6, lane = tid & 63;
    const int wm   = wave & 1, wn = wave >> 1;
    const int lane15 = lane & 15, quad = lane >> 4;
    const int srow = tid & 127, shalf = tid >> 7;

    int n = bn * 128 + srow;
    int b = n / 1444, yx = n % 1444;
    int y = yx / 38, x = yx % 38;

    const __hip_bfloat16* Abase = Aw2 + srow * 576;
    ushort* lAw = &lA[srow * 72 + shalf * 32];
    ushort* lBw = &lB[srow * 72 + shalf * 32];
    const ushort* aRd = &lA[(wm * 64 + lane15) * 72 + quad * 8];
    const ushort* bRd = &lB[(wn * 64 + lane15) * 72 + quad * 8];

    f32x4 zero = {0.f, 0.f, 0.f, 0.f};
    f32x4 acc[4][4];
    #pragma unroll
    for (int i = 0; i < 4; i++)
        #pragma unroll
        for (int j = 0; j < 4; j++) acc[i][j] = zero;

    for (int kb = 0; kb < 9; kb++) {                      // tap (ky,kx), 64 ic each
        int ky = kb / 3, kx = kb - ky * 3;
        int iy = y + ky - 1, ix = x + kx - 1;
        bool ok = ((unsigned)iy < 38u) && ((unsigned)ix < 38u);

        const uint4* ga = (const uint4*)(Abase + kb * 64 + shalf * 32);
        uint4 av0 = ga[0], av1 = ga[1], av2 = ga[2], av3 = ga[3];
        uint4 z4 = {0u, 0u, 0u, 0u};
        uint4 bv0 = z4, bv1 = z4, bv2 = z4, bv3 = z4;
        if (ok) {
            const uint4* gb = (const uint4*)(P1t + (((b * 38 + iy) * 38 + ix) << 6) + shalf * 32);
            bv0 = gb[0]; bv1 = gb[1]; bv2 = gb[2]; bv3 = gb[3];
        }

        __syncthreads();
        ((uint4*)lAw)[0] = av0; ((uint4*)lAw)[1] = av1;
        ((uint4*)lAw)[2] = av2; ((uint4*)lAw)[3] = av3;
        ((uint4*)lBw)[0] = bv0; ((uint4*)lBw)[1] = bv1;
        ((uint4*)lBw)[2] = bv2; ((uint4*)lBw)[3] = bv3;
        __syncthreads();

        #pragma unroll
        for (int kk = 0; kk < 2; kk++) {
            bf16x8 af[4], bf[4];
            #pragma unroll
            for (int tm = 0; tm < 4; tm++)
                af[tm] = *(const bf16x8*)(aRd + tm * 16 * 72 + kk * 32);
            #pragma unroll
            for (int tn = 0; tn < 4; tn++)
                bf[tn] = *(const bf16x8*)(bRd + tn * 16 * 72 + kk * 32);
            #pragma unroll
            for (int tm = 0; tm < 4; tm++)
                #pragma unroll
                for (int tn = 0; tn < 4; tn++)
                    acc[tm][tn] = __builtin_amdgcn_mfma_f32_16x16x32_bf16(
                        af[tm], bf[tn], acc[tm][tn], 0, 0, 0);
        }
    }

    #pragma unroll
    for (int tm = 0; tm < 4; tm++) {
        int m0 = wm * 64 + tm * 16 + quad * 4;
        float b0 = cb[m0], b1 = cb[m0 + 1], b2 = cb[m0 + 2], b3 = cb[m0 + 3];
        #pragma unroll
        for (int tn = 0; tn < 4; tn++) {
            int nn = bn * 128 + wn * 64 + tn * 16 + lane15;
            f32x4 a = acc[tm][tn];
            ushort4 pk;
            pk.x = f2bf(fmaxf(a[0] + b0, 0.f));
            pk.y = f2bf(fmaxf(a[1] + b1, 0.f));
            pk.z = f2bf(fmaxf(a[2] + b2, 0.f));
            pk.w = f2bf(fmaxf(a[3] + b3, 0.f));
            *(ushort4*)((ushort*)Q + (size_t)nn * 128 + m0) = pk;
        }
    }
}

// ---------------- maxpool(2,2,p1) over Q -> P2t [256][20][20][128] ----------------
__global__ __launch_bounds__(256) void k_pool2t(
    const __hip_bfloat16* __restrict__ Q, __hip_bfloat16* __restrict__ P2t)
{
    int t = blockIdx.x * 256 + threadIdx.x;              // 256*400*128 threads
    int ic = t & 127, rest = t >> 7;
    int px = rest % 20, py = (rest / 20) % 20, b = rest / 400;
    float m = 0.f;                                       // Q >= 0 (relu'd)
    #pragma unroll
    for (int dy = 0; dy < 2; dy++) {
        int y = 2 * py - 1 + dy;
        if ((unsigned)y >= 38u) continue;
        #pragma unroll
        for (int dx = 0; dx < 2; dx++) {
            int x = 2 * px - 1 + dx;
            if ((unsigned)x >= 38u) continue;
            m = fmaxf(m, __bfloat162float(Q[(((b * 38 + y) * 38 + x) << 7) + ic]));
        }
    }
    P2t[t] = __float2bfloat16(m);
}

// ---------------- prim_w (256,128,81) fp32 -> Awt [oc][(ky*9+kx)*128+ic] bf16 ----
__global__ __launch_bounds__(256) void k_prep_awt(
    const float* __restrict__ pw, __hip_bfloat16* __restrict__ Awt)
{
    int t = blockIdx.x * 256 + threadIdx.x;              // 256*10368 threads
    int oc = t / 10368, rem = t % 10368;
    int k81 = rem >> 7, ic = rem & 127;
    Awt[t] = __float2bfloat16(pw[(oc * 128 + ic) * 81 + k81]);
}

// ---------------- primcaps as MFMA GEMM: u[oc][n] = Awt[oc][:] . patch[:][n] ------
// M=256 (2 blocks of 128), N=9216 (72 blocks of 128), K=10368 (162 iters of 64)
__global__ __launch_bounds__(256) void k_primcaps_mfma(
    const __hip_bfloat16* __restrict__ P2t,   // [256][20][20][128]
    const __hip_bfloat16* __restrict__ Awt,   // [256][10368]
    const float* __restrict__ pb,             // [256]
    float* __restrict__ u)
{
    __shared__ ushort lA[128 * 72];
    __shared__ ushort lB[128 * 72];
    const int tid  = threadIdx.x;
    const int bm   = blockIdx.x & 1;
    const int bn   = blockIdx.x >> 1;
    const int wave = tid >> 6, lane = tid & 63;
    const int wm   = wave & 1, wn = wave >> 1;
    const int lane15 = lane & 15, quad = lane >> 4;
    const int srow = tid & 127, shalf = tid >> 7;

    int n  = bn * 128 + srow;
    int cb = n / 36, cs = n % 36;
    int cy = cs / 6, cx = cs % 6;
    const __hip_bfloat16* Bbase = P2t + ((cb * 20 + 2 * cy) * 20 + 2 * cx) * 128;
    const __hip_bfloat16* Abase = Awt + (bm * 128 + srow) * 10368;
    ushort* lAw = &lA[srow * 72 + shalf * 32];
    ushort* lBw = &lB[srow * 72 + shalf * 32];
    const ushort* aRd = &lA[(wm * 64 + lane15) * 72 + quad * 8];
    const ushort* bRd = &lB[(wn * 64 + lane15) * 72 + quad * 8];

    f32x4 zero = {0.f, 0.f, 0.f, 0.f};
    f32x4 acc[4][4];
    #pragma unroll
    for (int i = 0; i < 4; i++)
        #pragma unroll
        for (int j = 0; j < 4; j++) acc[i][j] = zero;

    for (int kb = 0; kb < 162; kb++) {
        int k81 = kb >> 1;
        int ky = k81 / 9, kx = k81 - ky * 9;
        int goffA = kb * 64 + shalf * 32;
        int goffB = (ky * 20 + kx) * 128 + (kb & 1) * 64 + shalf * 32;

        const uint4* ga = (const uint4*)(Abase + goffA);
        const uint4* gb = (const uint4*)(Bbase + goffB);
        uint4 av0 = ga[0], av1 = ga[1], av2 = ga[2], av3 = ga[3];
        uint4 bv0 = gb[0], bv1 = gb[1], bv2 = gb[2], bv3 = gb[3];

        __syncthreads();
        ((uint4*)lAw)[0] = av0; ((uint4*)lAw)[1] = av1;
        ((uint4*)lAw)[2] = av2; ((uint4*)lAw)[3] = av3;
        ((uint4*)lBw)[0] = bv0; ((uint4*)lBw)[1] = bv1;
        ((uint4*)lBw)[2] = bv2; ((uint4*)lBw)[3] = bv3;
        __syncthreads();

        #pragma unroll
        for (int kk = 0; kk < 2; kk++) {
            bf16x8 af[4], bf[4];
            #pragma unroll
            for (int tm = 0; tm < 4; tm++)
                af[tm] = *(const bf16x8*)(aRd + tm * 16 * 72 + kk * 32);
            #pragma unroll
            for (int tn = 0; tn < 4; tn++)
                bf[tn] = *(const bf16x8*)(bRd + tn * 16 * 72 + kk * 32);
            #pragma unroll
            for (int tm = 0; tm < 4; tm++)
                #pragma unroll
                for (int tn = 0; tn < 4; tn++)
                    acc[tm][tn] = __builtin_amdgcn_mfma_f32_16x16x32_bf16(
                        af[tm], bf[tn], acc[tm][tn], 0, 0, 0);
        }
    }

    #pragma unroll
    for (int tm = 0; tm < 4; tm++) {
        int m0 = bm * 128 + wm * 64 + tm * 16 + quad * 4;
        #pragma unroll
        for (int tn = 0; tn < 4; tn++) {
            int nn = bn * 128 + wn * 64 + tn * 16 + lane15;
            int ob = nn / 36, os = nn % 36;
            float* up = u + ob * 9216 + os;
            f32x4 a = acc[tm][tn];
            #pragma unroll
            for (int r = 0; r < 4; r++)
                up[(m0 + r) * 36] = a[r] + pb[m0 + r];
        }
    }
}

// ---------------- squash u (groups of 8 flat elements), in place ----------------
__global__ __launch_bounds__(256) void k_squash(float* __restrict__ u)
{
    int t = blockIdx.x * 256 + threadIdx.x;              // 256*1152 threads
    float4 a = *(const float4*)(u + t * 8);
    float4 b = *(const float4*)(u + t * 8 + 4);
    float sn = a.x*a.x + a.y*a.y + a.z*a.z + a.w*a.w
             + b.x*b.x + b.y*b.y + b.z*b.z + b.w*b.w;
    float sc = sqrtf(sn) / (1.f + sn);
    a.x*=sc; a.y*=sc; a.z*=sc; a.w*=sc; b.x*=sc; b.y*=sc; b.z*=sc; b.w*=sc;
    *(float4*)(u + t * 8) = a;
    *(float4*)(u + t * 8 + 4) = b;
}

// ---------------- u_hat[r][b][co] = sum_i W[r,co,i]*u[b,r,i]  (bf16 out) -------
__global__ __launch_bounds__(256) void k_uhat(
    const float* __restrict__ u, const float* __restrict__ W,
    __hip_bfloat16* __restrict__ uhat)
{
    int t = blockIdx.x * 256 + threadIdx.x;              // 1152*256*80 threads
    int co2 = t % 80, b = (t / 80) & 255, r = t / 20480;
    const float4* up = (const float4*)(u + (b * 1152 + r) * 8);
    float4 u0 = up[0], u1 = up[1];
    const float4* wp = (const float4*)(W + (r * 160 + co2 * 2) * 8);
    float4 w0 = wp[0], w1 = wp[1], w2 = wp[2], w3 = wp[3];
    float s0 = u0.x*w0.x + u0.y*w0.y + u0.z*w0.z + u0.w*w0.w
             + u1.x*w1.x + u1.y*w1.y + u1.z*w1.z + u1.w*w1.w;
    float s1 = u0.x*w2.x + u0.y*w2.y + u0.z*w2.z + u0.w*w2.w
             + u1.x*w3.x + u1.y*w3.y + u1.z*w3.z + u1.w*w3.w;
    __hip_bfloat162 h;
    h.x = __float2bfloat16(s0);
    h.y = __float2bfloat16(s1);
    *(__hip_bfloat162*)(uhat + (size_t)t * 2) = h;
}

// ---------------- softmax over r per class: cij[c][r] ----------------
__global__ __launch_bounds__(256) void k_softmax(
    const float* __restrict__ bij, float* __restrict__ cij)
{
    int c = blockIdx.x, tid = threadIdx.x;
    __shared__ float red[256];
    const float* bp = bij + c * 1152;
    float mx = -1e30f;
    for (int r = tid; r < 1152; r += 256) mx = fmaxf(mx, bp[r]);
    red[tid] = mx; __syncthreads();
    for (int s = 128; s > 0; s >>= 1) { if (tid < s) red[tid] = fmaxf(red[tid], red[tid + s]); __syncthreads(); }
    mx = red[0]; __syncthreads();
    float sum = 0.f;
    for (int r = tid; r < 1152; r += 256) sum += expf(bp[r] - mx);
    red[tid] = sum; __syncthreads();
    for (int s = 128; s > 0; s >>= 1) { if (tid < s) red[tid] += red[tid + s]; __syncthreads(); }
    float inv = 1.f / red[0];
    for (int r = tid; r < 1152; r += 256) cij[c * 1152 + r] = expf(bp[r] - mx) * inv;
}

// ---------------- s_j + elementwise squash -> v[b][c][o] (+ final output) -------
__global__ __launch_bounds__(256) void k_sj_vj(
    const __hip_bfloat16* __restrict__ uhat, const float* __restrict__ cij,
    float* __restrict__ v, float* __restrict__ out, int write_out)
{
    int bc = blockIdx.x;                                  // 2560 blocks
    int c = bc % 10, b = bc / 10;
    int tid = threadIdx.x, o = tid & 15, rs = tid >> 4;
    float acc = 0.f;
    for (int r = rs; r < 1152; r += 16) {
        float cc = cij[c * 1152 + r];
        float uh = __bfloat162float(uhat[(r * 256 + b) * 160 + c * 16 + o]);
        acc += cc * uh;
    }
    __shared__ float red[16][17];
    red[rs][o] = acc; __syncthreads();
    if (tid < 16) {
        float s = 0.f;
        #pragma unroll
        for (int k = 0; k < 16; k++) s += red[k][tid];
        float vv = s * fabsf(s) / (1.f + s * s);
        v[(b * 10 + c) * 16 + tid] = vv;
        if (write_out) out[(b * 10 + c) * 16 + tid] = vv;
    }
}

// ---------------- a_ij = mean_b <u_hat, v>; b_ij += a ----------------
__global__ __launch_bounds__(256) void k_aij(
    const __hip_bfloat16* __restrict__ uhat, const float* __restrict__ v,
    float* __restrict__ bij)
{
    int r = blockIdx.x, tid = threadIdx.x;
    __shared__ float red[160];
    if (tid < 160) {
        float acc = 0.f;
        for (int b = 0; b < 256; b++)
            acc += __bfloat162float(uhat[(r * 256 + b) * 160 + tid]) * v[b * 160 + tid];
        red[tid] = acc;
    }
    __syncthreads();
    if (tid < 10) {
        float s = 0.f;
        #pragma unroll
        for (int k = 0; k < 16; k++) s += red[tid * 16 + k];
        bij[tid * 1152 + r] += s * (1.f / 256.f);
    }
}

// ---------------- classifiers: sigmoid(w2 . relu(w1 . feat + b1) + b2) ----------
__global__ __launch_bounds__(128) void k_cls(
    const float* __restrict__ v, const float* __restrict__ w1,
    const float* __restrict__ b1, const float* __restrict__ w2,
    const float* __restrict__ b2, float* __restrict__ out)
{
    int bk = blockIdx.x;                                  // 2560 blocks
    int k = bk % 10, b = bk / 10;
    int tid = threadIdx.x;
    __shared__ float feat[160];
    __shared__ float red[128];
    for (int f = tid; f < 160; f += 128) feat[f] = v[b * 160 + f];
    __syncthreads();
    float h = 0.f;
    if (tid < 100) {
        float a = b1[k * 100 + tid];
        for (int f = 0; f < 160; f++) a += feat[f] * w1[(k * 160 + f) * 100 + tid];
        h = fmaxf(a, 0.f) * w2[k * 100 + tid];
    }
    red[tid] = h; __syncthreads();
    for (int s = 64; s > 0; s >>= 1) { if (tid < s) red[tid] += red[tid + s]; __syncthreads(); }
    if (tid == 0) {
        float logit = red[0] + b2[k];
        out[40960 + b * 10 + k] = 1.f / (1.f + expf(-logit));
    }
}

extern "C" void kernel_launch(void* const* d_in, const int* in_sizes, int n_in,
                              void* d_out, int out_size, void* d_ws, size_t ws_size,
                              hipStream_t stream) {
    const float* data    = (const float*)d_in[0];
    const float* conv1_w = (const float*)d_in[1];
    const float* conv1_b = (const float*)d_in[2];
    const float* conv2_w = (const float*)d_in[3];
    const float* conv2_b = (const float*)d_in[4];
    const float* prim_w  = (const float*)d_in[5];
    const float* prim_b  = (const float*)d_in[6];
    const float* W       = (const float*)d_in[7];
    const float* cls_w1  = (const float*)d_in[8];
    const float* cls_b1  = (const float*)d_in[9];
    const float* cls_w2  = (const float*)d_in[10];
    const float* cls_b2  = (const float*)d_in[11];
    float* out = (float*)d_out;

    char* ws = (char*)d_ws;
    // Q (94,633,984 B) reused for bf16 uhat (94,371,840 B) after k_pool2t.
    // P1t (47,316,992 B region) reused for P2t (13,107,200 B) after k_conv2_mfma.
    __hip_bfloat16* Q    = (__hip_bfloat16*)(ws + 0);
    __hip_bfloat16* uhat = (__hip_bfloat16*)(ws + 0);
    __hip_bfloat16* P1t  = (__hip_bfloat16*)(ws + 94633984);
    __hip_bfloat16* P2t  = (__hip_bfloat16*)(ws + 94633984);
    float*          u    = (float*)(ws + 141950976);           // 9,437,184
    __hip_bfloat16* Awt  = (__hip_bfloat16*)(ws + 151388160);  // 5,308,416
    __hip_bfloat16* Aw2  = (__hip_bfloat16*)(ws + 156696576);  //   147,456
    float*          v    = (float*)(ws + 156844032);           //   163,840
    float*          bij  = (float*)(ws + 157007872);           //    46,080
    float*          cij  = (float*)(ws + 157053952);           //    46,080
    __hip_bfloat16* Aw1  = (__hip_bfloat16*)(ws + 157100032);  //     4,096
    // total: 157,104,128 bytes

    hipMemsetAsync(bij, 0, 11520 * sizeof(float), stream);

    k_prep_aw1<<<8, 256, 0, stream>>>(conv1_w, Aw1);
    k_prep_aw2<<<288, 256, 0, stream>>>(conv2_w, Aw2);
    k_prep_awt<<<10368, 256, 0, stream>>>(prim_w, Awt);
    k_conv1_mfma<<<9728, 256, 0, stream>>>(data, Aw1, conv1_b, P1t);
    k_conv2_mfma<<<2888, 256, 0, stream>>>(P1t, Aw2, conv2_b, Q);
    k_pool2t<<<51200, 256, 0, stream>>>(Q, P2t);
    k_primcaps_mfma<<<144, 256, 0, stream>>>(P2t, Awt, prim_b, u);
    k_squash<<<1152, 256, 0, stream>>>(u);
    k_uhat<<<92160, 256, 0, stream>>>(u, W, uhat);

    for (int it = 0; it < 3; it++) {
        k_softmax<<<10, 256, 0, stream>>>(bij, cij);
        k_sj_vj<<<2560, 256, 0, stream>>>(uhat, cij, v, out, it == 2 ? 1 : 0);
        if (it < 2) k_aij<<<1152, 256, 0, stream>>>(uhat, v, bij);
    }
    k_cls<<<2560, 128, 0, stream>>>(v, cls_w1, cls_b1, cls_w2, cls_b2, out);
}

// Round 5
// 731.928 us; speedup vs baseline: 9.1753x; 1.3082x over previous
//
#include <hip/hip_runtime.h>
#include <hip/hip_bf16.h>

// CapsNet forward. Round 5: split-K primcaps (864 blocks) + coalesced routing
// (uhat -> [b][r][co], cijT[r][c], block-per-b s_j). B=256,R=1152,C=10,O=16,I=8

typedef __bf16 bf16x8 __attribute__((ext_vector_type(8)));
typedef float  f32x4  __attribute__((ext_vector_type(4)));

static __device__ __forceinline__ ushort f2bf(float f) {
    __hip_bfloat16 h = __float2bfloat16(f);
    return *(ushort*)&h;
}

// ---------------- conv1_w (64,3,3,3) fp32 -> Aw1 [oc][k=ic*9+ky*3+kx] bf16, K pad 32
__global__ __launch_bounds__(256) void k_prep_aw1(
    const float* __restrict__ w1, __hip_bfloat16* __restrict__ Aw1)
{
    int t = blockIdx.x * 256 + threadIdx.x;              // 2048 threads
    int oc = t >> 5, k = t & 31;
    Aw1[t] = __float2bfloat16(k < 27 ? w1[oc * 27 + k] : 0.f);
}

// ---------------- conv1(3->64,3x3,s1,p0) + relu + maxpool(2,2,p1) via MFMA -------
__global__ __launch_bounds__(256) void k_conv1_mfma(
    const float* __restrict__ data, const __hip_bfloat16* __restrict__ Aw1,
    const float* __restrict__ b1, __hip_bfloat16* __restrict__ P1t)
{
    __shared__ float tile[960];          // [ic]*312 + [rloc]*78 + [lc]; lc = x_in+1
    const int tid = threadIdx.x;
    const int py = blockIdx.x % 38, b = blockIdx.x / 38;

    #pragma unroll
    for (int c = 0; c < 4; c++) {
        int idx = tid + c * 256;
        if (idx < 960) {
            float val = 0.f;
            if (idx < 936) {
                int ic = idx / 312, rem = idx % 312;
                int rl = rem / 78, lc = rem % 78;
                int ri = 2 * py - 1 + rl, xi = lc - 1;
                if ((unsigned)ri < 76u && (unsigned)xi < 76u)
                    val = data[(b * 3 + ic) * 5776 + ri * 76 + xi];
            }
            tile[idx] = val;
        }
    }

    const int wave = tid >> 6, lane = tid & 63;
    const int l15 = lane & 15, quad = lane >> 4;

    bf16x8 af = *(const bf16x8*)((const ushort*)Aw1 + (wave * 16 + l15) * 32 + quad * 8);

    int koff[8]; bool kok[8];
    #pragma unroll
    for (int j = 0; j < 8; j++) {
        int kk = quad * 8 + j;
        kok[j] = kk < 27;
        int ic = kk / 9, rem = kk - ic * 9, ky = rem / 3, kx = rem - ky * 3;
        koff[j] = kok[j] ? (ic * 312 + ky * 78 + kx) : 0;
    }

    float bias[4];
    #pragma unroll
    for (int r = 0; r < 4; r++) bias[r] = b1[wave * 16 + quad * 4 + r];

    const bool valid0 = (py > 0);
    const bool valid1 = (py < 37);

    __syncthreads();

    #pragma unroll
    for (int t5 = 0; t5 < 5; t5++) {
        int n_x = t5 * 16 + l15;                         // conv x = n_x - 1
        bool col_ok = (unsigned)(n_x - 1) < 74u;

        bf16x8 bf0, bf1;
        #pragma unroll
        for (int j = 0; j < 8; j++) {
            float v0 = tile[koff[j] + n_x];
            float v1 = tile[koff[j] + 78 + n_x];
            bool ok = col_ok && kok[j];
            bf0[j] = (__bf16)(ok ? v0 : 0.f);
            bf1[j] = (__bf16)(ok ? v1 : 0.f);
        }
        f32x4 z = {0.f, 0.f, 0.f, 0.f};
        f32x4 c0 = __builtin_amdgcn_mfma_f32_16x16x32_bf16(af, bf0, z, 0, 0, 0);
        f32x4 c1 = __builtin_amdgcn_mfma_f32_16x16x32_bf16(af, bf1, z, 0, 0, 0);

        f32x4 p;
        #pragma unroll
        for (int r = 0; r < 4; r++) {
            float r0 = (valid0 && col_ok) ? fmaxf(c0[r] + bias[r], 0.f) : 0.f;
            float r1 = (valid1 && col_ok) ? fmaxf(c1[r] + bias[r], 0.f) : 0.f;
            p[r] = fmaxf(r0, r1);
        }
        #pragma unroll
        for (int r = 0; r < 4; r++)
            p[r] = fmaxf(p[r], __shfl_xor(p[r], 1));

        if (!(l15 & 1)) {
            int px = t5 * 8 + (l15 >> 1);
            if (px < 38) {
                ushort4 pk;
                pk.x = f2bf(p[0]); pk.y = f2bf(p[1]);
                pk.z = f2bf(p[2]); pk.w = f2bf(p[3]);
                *(ushort4*)((ushort*)P1t + ((size_t)(b * 38 + py) * 38 + px) * 64
                            + wave * 16 + quad * 4) = pk;
            }
        }
    }
}

// ---------------- conv2_w (128,64,3,3) fp32 -> Aw2 [oc][(ky*3+kx)*64+ic] bf16 ----
__global__ __launch_bounds__(256) void k_prep_aw2(
    const float* __restrict__ w2, __hip_bfloat16* __restrict__ Aw2)
{
    int t = blockIdx.x * 256 + threadIdx.x;              // 128*576 threads
    int oc = t / 576, rem = t % 576;
    int k9 = rem >> 6, ic = rem & 63;
    Aw2[t] = __float2bfloat16(w2[(oc * 64 + ic) * 9 + k9]);
}

// ---------------- conv2 as MFMA GEMM + bias + relu ------------------------------
__global__ __launch_bounds__(256) void k_conv2_mfma(
    const __hip_bfloat16* __restrict__ P1t,   // [256][38][38][64]
    const __hip_bfloat16* __restrict__ Aw2,   // [128][576]
    const float* __restrict__ cb,             // [128]
    __hip_bfloat16* __restrict__ Q)
{
    __shared__ ushort lA[128 * 72];
    __shared__ ushort lB[128 * 72];
    const int tid  = threadIdx.x;
    const int bn   = blockIdx.x;              // 2888 N-blocks
    const int wave = tid >> 6, lane = tid & 63;
    const int wm   = wave & 1, wn = wave >> 1;
    const int lane15 = lane & 15, quad = lane >> 4;
    const int srow = tid & 127, shalf = tid >> 7;

    int n = bn * 128 + srow;
    int b = n / 1444, yx = n % 1444;
    int y = yx / 38, x = yx % 38;

    const __hip_bfloat16* Abase = Aw2 + srow * 576;
    ushort* lAw = &lA[srow * 72 + shalf * 32];
    ushort* lBw = &lB[srow * 72 + shalf * 32];
    const ushort* aRd = &lA[(wm * 64 + lane15) * 72 + quad * 8];
    const ushort* bRd = &lB[(wn * 64 + lane15) * 72 + quad * 8];

    f32x4 zero = {0.f, 0.f, 0.f, 0.f};
    f32x4 acc[4][4];
    #pragma unroll
    for (int i = 0; i < 4; i++)
        #pragma unroll
        for (int j = 0; j < 4; j++) acc[i][j] = zero;

    for (int kb = 0; kb < 9; kb++) {
        int ky = kb / 3, kx = kb - ky * 3;
        int iy = y + ky - 1, ix = x + kx - 1;
        bool ok = ((unsigned)iy < 38u) && ((unsigned)ix < 38u);

        const uint4* ga = (const uint4*)(Abase + kb * 64 + shalf * 32);
        uint4 av0 = ga[0], av1 = ga[1], av2 = ga[2], av3 = ga[3];
        uint4 z4 = {0u, 0u, 0u, 0u};
        uint4 bv0 = z4, bv1 = z4, bv2 = z4, bv3 = z4;
        if (ok) {
            const uint4* gb = (const uint4*)(P1t + (((b * 38 + iy) * 38 + ix) << 6) + shalf * 32);
            bv0 = gb[0]; bv1 = gb[1]; bv2 = gb[2]; bv3 = gb[3];
        }

        __syncthreads();
        ((uint4*)lAw)[0] = av0; ((uint4*)lAw)[1] = av1;
        ((uint4*)lAw)[2] = av2; ((uint4*)lAw)[3] = av3;
        ((uint4*)lBw)[0] = bv0; ((uint4*)lBw)[1] = bv1;
        ((uint4*)lBw)[2] = bv2; ((uint4*)lBw)[3] = bv3;
        __syncthreads();

        #pragma unroll
        for (int kk = 0; kk < 2; kk++) {
            bf16x8 af[4], bf[4];
            #pragma unroll
            for (int tm = 0; tm < 4; tm++)
                af[tm] = *(const bf16x8*)(aRd + tm * 16 * 72 + kk * 32);
            #pragma unroll
            for (int tn = 0; tn < 4; tn++)
                bf[tn] = *(const bf16x8*)(bRd + tn * 16 * 72 + kk * 32);
            #pragma unroll
            for (int tm = 0; tm < 4; tm++)
                #pragma unroll
                for (int tn = 0; tn < 4; tn++)
                    acc[tm][tn] = __builtin_amdgcn_mfma_f32_16x16x32_bf16(
                        af[tm], bf[tn], acc[tm][tn], 0, 0, 0);
        }
    }

    #pragma unroll
    for (int tm = 0; tm < 4; tm++) {
        int m0 = wm * 64 + tm * 16 + quad * 4;
        float b0 = cb[m0], b1 = cb[m0 + 1], b2 = cb[m0 + 2], b3 = cb[m0 + 3];
        #pragma unroll
        for (int tn = 0; tn < 4; tn++) {
            int nn = bn * 128 + wn * 64 + tn * 16 + lane15;
            f32x4 a = acc[tm][tn];
            ushort4 pk;
            pk.x = f2bf(fmaxf(a[0] + b0, 0.f));
            pk.y = f2bf(fmaxf(a[1] + b1, 0.f));
            pk.z = f2bf(fmaxf(a[2] + b2, 0.f));
            pk.w = f2bf(fmaxf(a[3] + b3, 0.f));
            *(ushort4*)((ushort*)Q + (size_t)nn * 128 + m0) = pk;
        }
    }
}

// ---------------- maxpool(2,2,p1) over Q -> P2t [256][20][20][128] ----------------
__global__ __launch_bounds__(256) void k_pool2t(
    const __hip_bfloat16* __restrict__ Q, __hip_bfloat16* __restrict__ P2t)
{
    int t = blockIdx.x * 256 + threadIdx.x;              // 256*400*128 threads
    int ic = t & 127, rest = t >> 7;
    int px = rest % 20, py = (rest / 20) % 20, b = rest / 400;
    float m = 0.f;
    #pragma unroll
    for (int dy = 0; dy < 2; dy++) {
        int y = 2 * py - 1 + dy;
        if ((unsigned)y >= 38u) continue;
        #pragma unroll
        for (int dx = 0; dx < 2; dx++) {
            int x = 2 * px - 1 + dx;
            if ((unsigned)x >= 38u) continue;
            m = fmaxf(m, __bfloat162float(Q[(((b * 38 + y) * 38 + x) << 7) + ic]));
        }
    }
    P2t[t] = __float2bfloat16(m);
}

// ---------------- prim_w (256,128,81) fp32 -> Awt [oc][(ky*9+kx)*128+ic] bf16 ----
__global__ __launch_bounds__(256) void k_prep_awt(
    const float* __restrict__ pw, __hip_bfloat16* __restrict__ Awt)
{
    int t = blockIdx.x * 256 + threadIdx.x;              // 256*10368 threads
    int oc = t / 10368, rem = t % 10368;
    int k81 = rem >> 7, ic = rem & 127;
    Awt[t] = __float2bfloat16(pw[(oc * 128 + ic) * 81 + k81]);
}

// ---------------- primcaps split-K MFMA GEMM -> 6 fp32 partials ------------------
// M=256 (2x128), N=9216 (72x128), K=10368: 6 chunks x 27 kb-iters of K=64.
// grid = 864 blocks: chunk = blk/144, tile = blk%144 (bm = tile&1, bn = tile>>1).
// partial layout per chunk: same as u ([b]*9216 + oc*36 + s), NO bias.
__global__ __launch_bounds__(256) void k_primcaps_mfma(
    const __hip_bfloat16* __restrict__ P2t,   // [256][20][20][128]
    const __hip_bfloat16* __restrict__ Awt,   // [256][10368]
    float* __restrict__ partU)                // [6][2359296]
{
    __shared__ ushort lA[128 * 72];
    __shared__ ushort lB[128 * 72];
    const int tid  = threadIdx.x;
    const int chunk = blockIdx.x / 144;
    const int tile  = blockIdx.x % 144;
    const int bm   = tile & 1;
    const int bn   = tile >> 1;
    const int wave = tid >> 6, lane = tid & 63;
    const int wm   = wave & 1, wn = wave >> 1;
    const int lane15 = lane & 15, quad = lane >> 4;
    const int srow = tid & 127, shalf = tid >> 7;

    int n  = bn * 128 + srow;
    int cb = n / 36, cs = n % 36;
    int cy = cs / 6, cx = cs % 6;
    const __hip_bfloat16* Bbase = P2t + ((cb * 20 + 2 * cy) * 20 + 2 * cx) * 128;
    const __hip_bfloat16* Abase = Awt + (bm * 128 + srow) * 10368;
    ushort* lAw = &lA[srow * 72 + shalf * 32];
    ushort* lBw = &lB[srow * 72 + shalf * 32];
    const ushort* aRd = &lA[(wm * 64 + lane15) * 72 + quad * 8];
    const ushort* bRd = &lB[(wn * 64 + lane15) * 72 + quad * 8];

    f32x4 zero = {0.f, 0.f, 0.f, 0.f};
    f32x4 acc[4][4];
    #pragma unroll
    for (int i = 0; i < 4; i++)
        #pragma unroll
        for (int j = 0; j < 4; j++) acc[i][j] = zero;

    const int kb0 = chunk * 27;
    for (int ki = 0; ki < 27; ki++) {
        int kb = kb0 + ki;
        int k81 = kb >> 1;
        int ky = k81 / 9, kx = k81 - ky * 9;
        int goffA = kb * 64 + shalf * 32;
        int goffB = (ky * 20 + kx) * 128 + (kb & 1) * 64 + shalf * 32;

        const uint4* ga = (const uint4*)(Abase + goffA);
        const uint4* gb = (const uint4*)(Bbase + goffB);
        uint4 av0 = ga[0], av1 = ga[1], av2 = ga[2], av3 = ga[3];
        uint4 bv0 = gb[0], bv1 = gb[1], bv2 = gb[2], bv3 = gb[3];

        __syncthreads();
        ((uint4*)lAw)[0] = av0; ((uint4*)lAw)[1] = av1;
        ((uint4*)lAw)[2] = av2; ((uint4*)lAw)[3] = av3;
        ((uint4*)lBw)[0] = bv0; ((uint4*)lBw)[1] = bv1;
        ((uint4*)lBw)[2] = bv2; ((uint4*)lBw)[3] = bv3;
        __syncthreads();

        #pragma unroll
        for (int kk = 0; kk < 2; kk++) {
            bf16x8 af[4], bf[4];
            #pragma unroll
            for (int tm = 0; tm < 4; tm++)
                af[tm] = *(const bf16x8*)(aRd + tm * 16 * 72 + kk * 32);
            #pragma unroll
            for (int tn = 0; tn < 4; tn++)
                bf[tn] = *(const bf16x8*)(bRd + tn * 16 * 72 + kk * 32);
            #pragma unroll
            for (int tm = 0; tm < 4; tm++)
                #pragma unroll
                for (int tn = 0; tn < 4; tn++)
                    acc[tm][tn] = __builtin_amdgcn_mfma_f32_16x16x32_bf16(
                        af[tm], bf[tn], acc[tm][tn], 0, 0, 0);
        }
    }

    float* base = partU + chunk * 2359296;
    #pragma unroll
    for (int tm = 0; tm < 4; tm++) {
        int m0 = bm * 128 + wm * 64 + tm * 16 + quad * 4;
        #pragma unroll
        for (int tn = 0; tn < 4; tn++) {
            int nn = bn * 128 + wn * 64 + tn * 16 + lane15;
            int ob = nn / 36, os = nn % 36;
            float* up = base + ob * 9216 + os;
            f32x4 a = acc[tm][tn];
            #pragma unroll
            for (int r = 0; r < 4; r++)
                up[(m0 + r) * 36] = a[r];
        }
    }
}

// ---------------- reduce 6 partials + bias + squash -> u [b][r][i] fp32 ----------
// thread t = capsule (b*1152+r); elements t*8 .. t*8+7 (contiguous in u layout).
__global__ __launch_bounds__(256) void k_reduce_squash(
    const float* __restrict__ partU, const float* __restrict__ pb,
    float* __restrict__ u)
{
    int t = blockIdx.x * 256 + threadIdx.x;              // 294912 threads
    float4 a = {0.f, 0.f, 0.f, 0.f}, b4 = {0.f, 0.f, 0.f, 0.f};
    #pragma unroll
    for (int p = 0; p < 6; p++) {
        const float4* pp = (const float4*)(partU + p * 2359296 + t * 8);
        float4 x = pp[0], y = pp[1];
        a.x += x.x; a.y += x.y; a.z += x.z; a.w += x.w;
        b4.x += y.x; b4.y += y.y; b4.z += y.z; b4.w += y.w;
    }
    // bias: element e at flat (t%1152)*8 + e within batch; oc = flat/36
    int lb = (t % 1152) * 8;
    int oc0 = lb / 36, s0 = lb - oc0 * 36;
    float vals[8] = {a.x, a.y, a.z, a.w, b4.x, b4.y, b4.z, b4.w};
    float sn = 0.f;
    #pragma unroll
    for (int e = 0; e < 8; e++) {
        int oc = oc0 + ((s0 + e) >= 36 ? 1 : 0);
        vals[e] += pb[oc];
        sn += vals[e] * vals[e];
    }
    float sc = sqrtf(sn) / (1.f + sn);
    float4 o0 = {vals[0]*sc, vals[1]*sc, vals[2]*sc, vals[3]*sc};
    float4 o1 = {vals[4]*sc, vals[5]*sc, vals[6]*sc, vals[7]*sc};
    *(float4*)(u + t * 8) = o0;
    *(float4*)(u + t * 8 + 4) = o1;
}

// ---------------- u_hat[b][r][co] = sum_i W[r,co,i]*u[b,r,i]  (bf16 out) -------
__global__ __launch_bounds__(256) void k_uhat(
    const float* __restrict__ u, const float* __restrict__ W,
    __hip_bfloat16* __restrict__ uhat)
{
    int t = blockIdx.x * 256 + threadIdx.x;              // 23,592,960 threads
    int co2 = t % 80, r = (t / 80) % 1152, b = t / 92160;
    const float4* up = (const float4*)(u + (b * 1152 + r) * 8);
    float4 u0 = up[0], u1 = up[1];
    const float4* wp = (const float4*)(W + (r * 160 + co2 * 2) * 8);
    float4 w0 = wp[0], w1 = wp[1], w2 = wp[2], w3 = wp[3];
    float s0 = u0.x*w0.x + u0.y*w0.y + u0.z*w0.z + u0.w*w0.w
             + u1.x*w1.x + u1.y*w1.y + u1.z*w1.z + u1.w*w1.w;
    float s1 = u0.x*w2.x + u0.y*w2.y + u0.z*w2.z + u0.w*w2.w
             + u1.x*w3.x + u1.y*w3.y + u1.z*w3.z + u1.w*w3.w;
    __hip_bfloat162 h;
    h.x = __float2bfloat16(s0);
    h.y = __float2bfloat16(s1);
    // layout [b][r][co]: offset (b*1152+r)*160 + co2*2 == t*2
    *(__hip_bfloat162*)(uhat + (size_t)t * 2) = h;
}

// ---------------- softmax over r per class -> cijT[r*10 + c] ----------------
__global__ __launch_bounds__(256) void k_softmax(
    const float* __restrict__ bij, float* __restrict__ cijT)
{
    int c = blockIdx.x, tid = threadIdx.x;
    __shared__ float red[256];
    const float* bp = bij + c * 1152;
    float mx = -1e30f;
    for (int r = tid; r < 1152; r += 256) mx = fmaxf(mx, bp[r]);
    red[tid] = mx; __syncthreads();
    for (int s = 128; s > 0; s >>= 1) { if (tid < s) red[tid] = fmaxf(red[tid], red[tid + s]); __syncthreads(); }
    mx = red[0]; __syncthreads();
    float sum = 0.f;
    for (int r = tid; r < 1152; r += 256) sum += expf(bp[r] - mx);
    red[tid] = sum; __syncthreads();
    for (int s = 128; s > 0; s >>= 1) { if (tid < s) red[tid] += red[tid + s]; __syncthreads(); }
    float inv = 1.f / red[0];
    for (int r = tid; r < 1152; r += 256) cijT[r * 10 + c] = expf(bp[r] - mx) * inv;
}

// ---------------- s_j + squash -> v[b][co] (+ final out). block per b -----------
// 640 threads: 4 r-groups x 160 co. uhat reads 320B-contiguous per (b,r).
__global__ __launch_bounds__(640) void k_sj_vj(
    const __hip_bfloat16* __restrict__ uhat, const float* __restrict__ cijT,
    float* __restrict__ v, float* __restrict__ out, int write_out)
{
    int b = blockIdx.x;                                   // 256 blocks
    int tid = threadIdx.x, co = tid % 160, rg = tid / 160;
    int c = co >> 4;
    const __hip_bfloat16* up = uhat + (size_t)b * 184320 + co;
    float a0 = 0.f, a1 = 0.f;
    #pragma unroll 2
    for (int r = rg; r < 1152; r += 8) {
        a0 += cijT[r * 10 + c]       * __bfloat162float(up[(size_t)r * 160]);
        a1 += cijT[(r + 4) * 10 + c] * __bfloat162float(up[(size_t)(r + 4) * 160]);
    }
    __shared__ float red[4][160];
    red[rg][co] = a0 + a1;
    __syncthreads();
    if (tid < 160) {
        float s = red[0][tid] + red[1][tid] + red[2][tid] + red[3][tid];
        float vv = s * fabsf(s) / (1.f + s * s);
        v[b * 160 + tid] = vv;
        if (write_out) out[b * 160 + tid] = vv;
    }
}

// ---------------- a_ij = mean_b <u_hat, v>; b_ij += a. block per r ---------------
__global__ __launch_bounds__(320) void k_aij(
    const __hip_bfloat16* __restrict__ uhat, const float* __restrict__ v,
    float* __restrict__ bij)
{
    int r = blockIdx.x, tid = threadIdx.x;
    int co = tid % 160, bg = tid / 160;
    float acc = 0.f;
    for (int b = bg; b < 256; b += 2)
        acc += __bfloat162float(uhat[((size_t)b * 1152 + r) * 160 + co]) * v[b * 160 + co];
    __shared__ float red[320];
    red[tid] = acc;
    __syncthreads();
    if (tid < 160) red[tid] += red[tid + 160];
    __syncthreads();
    if (tid < 10) {
        float s = 0.f;
        #pragma unroll
        for (int k = 0; k < 16; k++) s += red[tid * 16 + k];
        bij[tid * 1152 + r] += s * (1.f / 256.f);
    }
}

// ---------------- classifiers: sigmoid(w2 . relu(w1 . feat + b1) + b2) ----------
__global__ __launch_bounds__(128) void k_cls(
    const float* __restrict__ v, const float* __restrict__ w1,
    const float* __restrict__ b1, const float* __restrict__ w2,
    const float* __restrict__ b2, float* __restrict__ out)
{
    int bk = blockIdx.x;                                  // 2560 blocks
    int k = bk % 10, b = bk / 10;
    int tid = threadIdx.x;
    __shared__ float feat[160];
    __shared__ float red[128];
    for (int f = tid; f < 160; f += 128) feat[f] = v[b * 160 + f];
    __syncthreads();
    float h = 0.f;
    if (tid < 100) {
        float a = b1[k * 100 + tid];
        for (int f = 0; f < 160; f++) a += feat[f] * w1[(k * 160 + f) * 100 + tid];
        h = fmaxf(a, 0.f) * w2[k * 100 + tid];
    }
    red[tid] = h; __syncthreads();
    for (int s = 64; s > 0; s >>= 1) { if (tid < s) red[tid] += red[tid + s]; __syncthreads(); }
    if (tid == 0) {
        float logit = red[0] + b2[k];
        out[40960 + b * 10 + k] = 1.f / (1.f + expf(-logit));
    }
}

extern "C" void kernel_launch(void* const* d_in, const int* in_sizes, int n_in,
                              void* d_out, int out_size, void* d_ws, size_t ws_size,
                              hipStream_t stream) {
    const float* data    = (const float*)d_in[0];
    const float* conv1_w = (const float*)d_in[1];
    const float* conv1_b = (const float*)d_in[2];
    const float* conv2_w = (const float*)d_in[3];
    const float* conv2_b = (const float*)d_in[4];
    const float* prim_w  = (const float*)d_in[5];
    const float* prim_b  = (const float*)d_in[6];
    const float* W       = (const float*)d_in[7];
    const float* cls_w1  = (const float*)d_in[8];
    const float* cls_b1  = (const float*)d_in[9];
    const float* cls_w2  = (const float*)d_in[10];
    const float* cls_b2  = (const float*)d_in[11];
    float* out = (float*)d_out;

    char* ws = (char*)d_ws;
    // ws+0 region (94.6 MB): Q (conv2 out) -> partU (6x9.4 MB split-K partials)
    //                        -> uhat (94.4 MB). Sequential lifetime, safe reuse.
    __hip_bfloat16* Q     = (__hip_bfloat16*)(ws + 0);
    float*          partU = (float*)(ws + 0);
    __hip_bfloat16* uhat  = (__hip_bfloat16*)(ws + 0);
    __hip_bfloat16* P1t   = (__hip_bfloat16*)(ws + 94633984);
    __hip_bfloat16* P2t   = (__hip_bfloat16*)(ws + 94633984);
    float*          u     = (float*)(ws + 141950976);           // 9,437,184
    __hip_bfloat16* Awt   = (__hip_bfloat16*)(ws + 151388160);  // 5,308,416
    __hip_bfloat16* Aw2   = (__hip_bfloat16*)(ws + 156696576);  //   147,456
    float*          v     = (float*)(ws + 156844032);           //   163,840
    float*          bij   = (float*)(ws + 157007872);           //    46,080
    float*          cijT  = (float*)(ws + 157053952);           //    46,080
    __hip_bfloat16* Aw1   = (__hip_bfloat16*)(ws + 157100032);  //     4,096
    // total: 157,104,128 bytes

    hipMemsetAsync(bij, 0, 11520 * sizeof(float), stream);

    k_prep_aw1<<<8, 256, 0, stream>>>(conv1_w, Aw1);
    k_prep_aw2<<<288, 256, 0, stream>>>(conv2_w, Aw2);
    k_prep_awt<<<10368, 256, 0, stream>>>(prim_w, Awt);
    k_conv1_mfma<<<9728, 256, 0, stream>>>(data, Aw1, conv1_b, P1t);
    k_conv2_mfma<<<2888, 256, 0, stream>>>(P1t, Aw2, conv2_b, Q);
    k_pool2t<<<51200, 256, 0, stream>>>(Q, P2t);
    k_primcaps_mfma<<<864, 256, 0, stream>>>(P2t, Awt, partU);
    k_reduce_squash<<<1152, 256, 0, stream>>>(partU, prim_b, u);
    k_uhat<<<92160, 256, 0, stream>>>(u, W, uhat);

    for (int it = 0; it < 3; it++) {
        k_softmax<<<10, 256, 0, stream>>>(bij, cijT);
        k_sj_vj<<<256, 640, 0, stream>>>(uhat, cijT, v, out, it == 2 ? 1 : 0);
        if (it < 2) k_aij<<<1152, 320, 0, stream>>>(uhat, v, bij);
    }
    k_cls<<<2560, 128, 0, stream>>>(v, cls_w1, cls_b1, cls_w2, cls_b2, out);
}

// Round 7
// 711.612 us; speedup vs baseline: 9.4372x; 1.0285x over previous
//
#include <hip/hip_runtime.h>
#include <hip/hip_bf16.h>

// CapsNet forward. Round 7 (bisect): round-5 conv stack (verified) + new
// u_hat-free routing (k_sj / k_vj / k_mmat / k_aij_contract).
// B=256, R=1152, C=10, O=16, I=8

typedef __bf16 bf16x8 __attribute__((ext_vector_type(8)));
typedef float  f32x4  __attribute__((ext_vector_type(4)));
typedef ushort u16x8  __attribute__((ext_vector_type(8)));

static __device__ __forceinline__ ushort f2bf(float f) {
    __hip_bfloat16 h = __float2bfloat16(f);
    return *(ushort*)&h;
}
static __device__ __forceinline__ float b2f(ushort u) {
    return __uint_as_float(((unsigned)u) << 16);
}

// ---------------- conv1_w (64,3,3,3) fp32 -> Aw1 [oc][k=ic*9+ky*3+kx] bf16, K pad 32
__global__ __launch_bounds__(256) void k_prep_aw1(
    const float* __restrict__ w1, __hip_bfloat16* __restrict__ Aw1)
{
    int t = blockIdx.x * 256 + threadIdx.x;              // 2048 threads
    int oc = t >> 5, k = t & 31;
    Aw1[t] = __float2bfloat16(k < 27 ? w1[oc * 27 + k] : 0.f);
}

// ---------------- conv1(3->64,3x3,s1,p0) + relu + maxpool(2,2,p1) via MFMA -------
__global__ __launch_bounds__(256) void k_conv1_mfma(
    const float* __restrict__ data, const __hip_bfloat16* __restrict__ Aw1,
    const float* __restrict__ b1, __hip_bfloat16* __restrict__ P1t)
{
    __shared__ float tile[960];          // [ic]*312 + [rloc]*78 + [lc]; lc = x_in+1
    const int tid = threadIdx.x;
    const int py = blockIdx.x % 38, b = blockIdx.x / 38;

    #pragma unroll
    for (int c = 0; c < 4; c++) {
        int idx = tid + c * 256;
        if (idx < 960) {
            float val = 0.f;
            if (idx < 936) {
                int ic = idx / 312, rem = idx % 312;
                int rl = rem / 78, lc = rem % 78;
                int ri = 2 * py - 1 + rl, xi = lc - 1;
                if ((unsigned)ri < 76u && (unsigned)xi < 76u)
                    val = data[(b * 3 + ic) * 5776 + ri * 76 + xi];
            }
            tile[idx] = val;
        }
    }

    const int wave = tid >> 6, lane = tid & 63;
    const int l15 = lane & 15, quad = lane >> 4;

    bf16x8 af = *(const bf16x8*)((const ushort*)Aw1 + (wave * 16 + l15) * 32 + quad * 8);

    int koff[8]; bool kok[8];
    #pragma unroll
    for (int j = 0; j < 8; j++) {
        int kk = quad * 8 + j;
        kok[j] = kk < 27;
        int ic = kk / 9, rem = kk - ic * 9, ky = rem / 3, kx = rem - ky * 3;
        koff[j] = kok[j] ? (ic * 312 + ky * 78 + kx) : 0;
    }

    float bias[4];
    #pragma unroll
    for (int r = 0; r < 4; r++) bias[r] = b1[wave * 16 + quad * 4 + r];

    const bool valid0 = (py > 0);
    const bool valid1 = (py < 37);

    __syncthreads();

    #pragma unroll
    for (int t5 = 0; t5 < 5; t5++) {
        int n_x = t5 * 16 + l15;                         // conv x = n_x - 1
        bool col_ok = (unsigned)(n_x - 1) < 74u;

        bf16x8 bf0, bf1;
        #pragma unroll
        for (int j = 0; j < 8; j++) {
            float v0 = tile[koff[j] + n_x];
            float v1 = tile[koff[j] + 78 + n_x];
            bool ok = col_ok && kok[j];
            bf0[j] = (__bf16)(ok ? v0 : 0.f);
            bf1[j] = (__bf16)(ok ? v1 : 0.f);
        }
        f32x4 z = {0.f, 0.f, 0.f, 0.f};
        f32x4 c0 = __builtin_amdgcn_mfma_f32_16x16x32_bf16(af, bf0, z, 0, 0, 0);
        f32x4 c1 = __builtin_amdgcn_mfma_f32_16x16x32_bf16(af, bf1, z, 0, 0, 0);

        f32x4 p;
        #pragma unroll
        for (int r = 0; r < 4; r++) {
            float r0 = (valid0 && col_ok) ? fmaxf(c0[r] + bias[r], 0.f) : 0.f;
            float r1 = (valid1 && col_ok) ? fmaxf(c1[r] + bias[r], 0.f) : 0.f;
            p[r] = fmaxf(r0, r1);
        }
        #pragma unroll
        for (int r = 0; r < 4; r++)
            p[r] = fmaxf(p[r], __shfl_xor(p[r], 1));

        if (!(l15 & 1)) {
            int px = t5 * 8 + (l15 >> 1);
            if (px < 38) {
                ushort4 pk;
                pk.x = f2bf(p[0]); pk.y = f2bf(p[1]);
                pk.z = f2bf(p[2]); pk.w = f2bf(p[3]);
                *(ushort4*)((ushort*)P1t + ((size_t)(b * 38 + py) * 38 + px) * 64
                            + wave * 16 + quad * 4) = pk;
            }
        }
    }
}

// ---------------- conv2_w (128,64,3,3) fp32 -> Aw2 [oc][(ky*3+kx)*64+ic] bf16 ----
__global__ __launch_bounds__(256) void k_prep_aw2(
    const float* __restrict__ w2, __hip_bfloat16* __restrict__ Aw2)
{
    int t = blockIdx.x * 256 + threadIdx.x;              // 128*576 threads
    int oc = t / 576, rem = t % 576;
    int k9 = rem >> 6, ic = rem & 63;
    Aw2[t] = __float2bfloat16(w2[(oc * 64 + ic) * 9 + k9]);
}

// ---------------- conv2 as MFMA GEMM + bias + relu (round-5 verified) -----------
__global__ __launch_bounds__(256) void k_conv2_mfma(
    const __hip_bfloat16* __restrict__ P1t,   // [256][38][38][64]
    const __hip_bfloat16* __restrict__ Aw2,   // [128][576]
    const float* __restrict__ cb,             // [128]
    __hip_bfloat16* __restrict__ Q)
{
    __shared__ ushort lA[128 * 72];
    __shared__ ushort lB[128 * 72];
    const int tid  = threadIdx.x;
    const int bn   = blockIdx.x;              // 2888 N-blocks
    const int wave = tid >> 6, lane = tid & 63;
    const int wm   = wave & 1, wn = wave >> 1;
    const int lane15 = lane & 15, quad = lane >> 4;
    const int srow = tid & 127, shalf = tid >> 7;

    int n = bn * 128 + srow;
    int b = n / 1444, yx = n % 1444;
    int y = yx / 38, x = yx % 38;

    const __hip_bfloat16* Abase = Aw2 + srow * 576;
    ushort* lAw = &lA[srow * 72 + shalf * 32];
    ushort* lBw = &lB[srow * 72 + shalf * 32];
    const ushort* aRd = &lA[(wm * 64 + lane15) * 72 + quad * 8];
    const ushort* bRd = &lB[(wn * 64 + lane15) * 72 + quad * 8];

    f32x4 zero = {0.f, 0.f, 0.f, 0.f};
    f32x4 acc[4][4];
    #pragma unroll
    for (int i = 0; i < 4; i++)
        #pragma unroll
        for (int j = 0; j < 4; j++) acc[i][j] = zero;

    for (int kb = 0; kb < 9; kb++) {
        int ky = kb / 3, kx = kb - ky * 3;
        int iy = y + ky - 1, ix = x + kx - 1;
        bool ok = ((unsigned)iy < 38u) && ((unsigned)ix < 38u);

        const uint4* ga = (const uint4*)(Abase + kb * 64 + shalf * 32);
        uint4 av0 = ga[0], av1 = ga[1], av2 = ga[2], av3 = ga[3];
        uint4 z4 = {0u, 0u, 0u, 0u};
        uint4 bv0 = z4, bv1 = z4, bv2 = z4, bv3 = z4;
        if (ok) {
            const uint4* gb = (const uint4*)(P1t + (((b * 38 + iy) * 38 + ix) << 6) + shalf * 32);
            bv0 = gb[0]; bv1 = gb[1]; bv2 = gb[2]; bv3 = gb[3];
        }

        __syncthreads();
        ((uint4*)lAw)[0] = av0; ((uint4*)lAw)[1] = av1;
        ((uint4*)lAw)[2] = av2; ((uint4*)lAw)[3] = av3;
        ((uint4*)lBw)[0] = bv0; ((uint4*)lBw)[1] = bv1;
        ((uint4*)lBw)[2] = bv2; ((uint4*)lBw)[3] = bv3;
        __syncthreads();

        #pragma unroll
        for (int kk = 0; kk < 2; kk++) {
            bf16x8 af[4], bf[4];
            #pragma unroll
            for (int tm = 0; tm < 4; tm++)
                af[tm] = *(const bf16x8*)(aRd + tm * 16 * 72 + kk * 32);
            #pragma unroll
            for (int tn = 0; tn < 4; tn++)
                bf[tn] = *(const bf16x8*)(bRd + tn * 16 * 72 + kk * 32);
            #pragma unroll
            for (int tm = 0; tm < 4; tm++)
                #pragma unroll
                for (int tn = 0; tn < 4; tn++)
                    acc[tm][tn] = __builtin_amdgcn_mfma_f32_16x16x32_bf16(
                        af[tm], bf[tn], acc[tm][tn], 0, 0, 0);
        }
    }

    #pragma unroll
    for (int tm = 0; tm < 4; tm++) {
        int m0 = wm * 64 + tm * 16 + quad * 4;
        float b0 = cb[m0], b1 = cb[m0 + 1], b2 = cb[m0 + 2], b3 = cb[m0 + 3];
        #pragma unroll
        for (int tn = 0; tn < 4; tn++) {
            int nn = bn * 128 + wn * 64 + tn * 16 + lane15;
            f32x4 a = acc[tm][tn];
            ushort4 pk;
            pk.x = f2bf(fmaxf(a[0] + b0, 0.f));
            pk.y = f2bf(fmaxf(a[1] + b1, 0.f));
            pk.z = f2bf(fmaxf(a[2] + b2, 0.f));
            pk.w = f2bf(fmaxf(a[3] + b3, 0.f));
            *(ushort4*)((ushort*)Q + (size_t)nn * 128 + m0) = pk;
        }
    }
}

// ---------------- maxpool(2,2,p1) over Q -> P2t [256][20][20][128] ----------------
__global__ __launch_bounds__(256) void k_pool2t(
    const __hip_bfloat16* __restrict__ Q, __hip_bfloat16* __restrict__ P2t)
{
    int t = blockIdx.x * 256 + threadIdx.x;              // 256*400*128 threads
    int ic = t & 127, rest = t >> 7;
    int px = rest % 20, py = (rest / 20) % 20, b = rest / 400;
    float m = 0.f;
    #pragma unroll
    for (int dy = 0; dy < 2; dy++) {
        int y = 2 * py - 1 + dy;
        if ((unsigned)y >= 38u) continue;
        #pragma unroll
        for (int dx = 0; dx < 2; dx++) {
            int x = 2 * px - 1 + dx;
            if ((unsigned)x >= 38u) continue;
            m = fmaxf(m, __bfloat162float(Q[(((b * 38 + y) * 38 + x) << 7) + ic]));
        }
    }
    P2t[t] = __float2bfloat16(m);
}

// ---------------- prim_w (256,128,81) fp32 -> Awt [oc][(ky*9+kx)*128+ic] bf16 ----
__global__ __launch_bounds__(256) void k_prep_awt(
    const float* __restrict__ pw, __hip_bfloat16* __restrict__ Awt)
{
    int t = blockIdx.x * 256 + threadIdx.x;              // 256*10368 threads
    int oc = t / 10368, rem = t % 10368;
    int k81 = rem >> 7, ic = rem & 127;
    Awt[t] = __float2bfloat16(pw[(oc * 128 + ic) * 81 + k81]);
}

// ---------------- W (1152,10,16,8) fp32 -> Wt [k=r*8+i][co=c*16+o] bf16 ----------
__global__ __launch_bounds__(256) void k_prep_wt(
    const float* __restrict__ W, __hip_bfloat16* __restrict__ Wt)
{
    int t = blockIdx.x * 256 + threadIdx.x;              // 1,474,560 threads
    int k = t / 160, co = t % 160;
    int r = k >> 3, i = k & 7, c = co >> 4, o = co & 15;
    Wt[t] = __float2bfloat16(W[(((size_t)r * 10 + c) * 16 + o) * 8 + i]);
}

// ---------------- primcaps split-K MFMA GEMM -> 6 fp32 partials ------------------
__global__ __launch_bounds__(256) void k_primcaps_mfma(
    const __hip_bfloat16* __restrict__ P2t,   // [256][20][20][128]
    const __hip_bfloat16* __restrict__ Awt,   // [256][10368]
    float* __restrict__ partU)                // [6][2359296]
{
    __shared__ ushort lA[128 * 72];
    __shared__ ushort lB[128 * 72];
    const int tid  = threadIdx.x;
    const int chunk = blockIdx.x / 144;
    const int tile  = blockIdx.x % 144;
    const int bm   = tile & 1;
    const int bn   = tile >> 1;
    const int wave = tid >> 6, lane = tid & 63;
    const int wm   = wave & 1, wn = wave >> 1;
    const int lane15 = lane & 15, quad = lane >> 4;
    const int srow = tid & 127, shalf = tid >> 7;

    int n  = bn * 128 + srow;
    int cb = n / 36, cs = n % 36;
    int cy = cs / 6, cx = cs % 6;
    const __hip_bfloat16* Bbase = P2t + ((cb * 20 + 2 * cy) * 20 + 2 * cx) * 128;
    const __hip_bfloat16* Abase = Awt + (bm * 128 + srow) * 10368;
    ushort* lAw = &lA[srow * 72 + shalf * 32];
    ushort* lBw = &lB[srow * 72 + shalf * 32];
    const ushort* aRd = &lA[(wm * 64 + lane15) * 72 + quad * 8];
    const ushort* bRd = &lB[(wn * 64 + lane15) * 72 + quad * 8];

    f32x4 zero = {0.f, 0.f, 0.f, 0.f};
    f32x4 acc[4][4];
    #pragma unroll
    for (int i = 0; i < 4; i++)
        #pragma unroll
        for (int j = 0; j < 4; j++) acc[i][j] = zero;

    const int kb0 = chunk * 27;
    for (int ki = 0; ki < 27; ki++) {
        int kb = kb0 + ki;
        int k81 = kb >> 1;
        int ky = k81 / 9, kx = k81 - ky * 9;
        int goffA = kb * 64 + shalf * 32;
        int goffB = (ky * 20 + kx) * 128 + (kb & 1) * 64 + shalf * 32;

        const uint4* ga = (const uint4*)(Abase + goffA);
        const uint4* gb = (const uint4*)(Bbase + goffB);
        uint4 av0 = ga[0], av1 = ga[1], av2 = ga[2], av3 = ga[3];
        uint4 bv0 = gb[0], bv1 = gb[1], bv2 = gb[2], bv3 = gb[3];

        __syncthreads();
        ((uint4*)lAw)[0] = av0; ((uint4*)lAw)[1] = av1;
        ((uint4*)lAw)[2] = av2; ((uint4*)lAw)[3] = av3;
        ((uint4*)lBw)[0] = bv0; ((uint4*)lBw)[1] = bv1;
        ((uint4*)lBw)[2] = bv2; ((uint4*)lBw)[3] = bv3;
        __syncthreads();

        #pragma unroll
        for (int kk = 0; kk < 2; kk++) {
            bf16x8 af[4], bf[4];
            #pragma unroll
            for (int tm = 0; tm < 4; tm++)
                af[tm] = *(const bf16x8*)(aRd + tm * 16 * 72 + kk * 32);
            #pragma unroll
            for (int tn = 0; tn < 4; tn++)
                bf[tn] = *(const bf16x8*)(bRd + tn * 16 * 72 + kk * 32);
            #pragma unroll
            for (int tm = 0; tm < 4; tm++)
                #pragma unroll
                for (int tn = 0; tn < 4; tn++)
                    acc[tm][tn] = __builtin_amdgcn_mfma_f32_16x16x32_bf16(
                        af[tm], bf[tn], acc[tm][tn], 0, 0, 0);
        }
    }

    float* base = partU + chunk * 2359296;
    #pragma unroll
    for (int tm = 0; tm < 4; tm++) {
        int m0 = bm * 128 + wm * 64 + tm * 16 + quad * 4;
        #pragma unroll
        for (int tn = 0; tn < 4; tn++) {
            int nn = bn * 128 + wn * 64 + tn * 16 + lane15;
            int ob = nn / 36, os = nn % 36;
            float* up = base + ob * 9216 + os;
            f32x4 a = acc[tm][tn];
            #pragma unroll
            for (int r = 0; r < 4; r++)
                up[(m0 + r) * 36] = a[r];
        }
    }
}

// ---------------- reduce 6 partials + bias + squash -> u_bf [b][k] bf16 ----------
__global__ __launch_bounds__(256) void k_reduce_squash(
    const float* __restrict__ partU, const float* __restrict__ pb,
    ushort* __restrict__ u_bf)
{
    int t = blockIdx.x * 256 + threadIdx.x;              // 294912 threads
    float4 a = {0.f, 0.f, 0.f, 0.f}, b4 = {0.f, 0.f, 0.f, 0.f};
    #pragma unroll
    for (int p = 0; p < 6; p++) {
        const float4* pp = (const float4*)(partU + p * 2359296 + t * 8);
        float4 x = pp[0], y = pp[1];
        a.x += x.x; a.y += x.y; a.z += x.z; a.w += x.w;
        b4.x += y.x; b4.y += y.y; b4.z += y.z; b4.w += y.w;
    }
    int lb = (t % 1152) * 8;
    int oc0 = lb / 36, s0 = lb - oc0 * 36;
    float vals[8] = {a.x, a.y, a.z, a.w, b4.x, b4.y, b4.z, b4.w};
    float sn = 0.f;
    #pragma unroll
    for (int e = 0; e < 8; e++) {
        int oc = oc0 + ((s0 + e) >= 36 ? 1 : 0);
        vals[e] += pb[oc];
        sn += vals[e] * vals[e];
    }
    float sc = sqrtf(sn) / (1.f + sn);
    u16x8 o8;
    #pragma unroll
    for (int e = 0; e < 8; e++) o8[e] = f2bf(vals[e] * sc);
    *(u16x8*)(u_bf + (size_t)t * 8) = o8;
}

// ---------------- softmax over r per class -> cijT[r*10 + c] ----------------
__global__ __launch_bounds__(256) void k_softmax(
    const float* __restrict__ bij, float* __restrict__ cijT)
{
    int c = blockIdx.x, tid = threadIdx.x;
    __shared__ float red[256];
    const float* bp = bij + c * 1152;
    float mx = -1e30f;
    for (int r = tid; r < 1152; r += 256) mx = fmaxf(mx, bp[r]);
    red[tid] = mx; __syncthreads();
    for (int s = 128; s > 0; s >>= 1) { if (tid < s) red[tid] = fmaxf(red[tid], red[tid + s]); __syncthreads(); }
    mx = red[0]; __syncthreads();
    float sum = 0.f;
    for (int r = tid; r < 1152; r += 256) sum += expf(bp[r] - mx);
    red[tid] = sum; __syncthreads();
    for (int s = 128; s > 0; s >>= 1) { if (tid < s) red[tid] += red[tid + s]; __syncthreads(); }
    float inv = 1.f / red[0];
    for (int r = tid; r < 1152; r += 256) cijT[r * 10 + c] = expf(bp[r] - mx) * inv;
}

// ---------------- s_j partials: s[b,co] = sum_k c[r(k),c]*Wt[k,co]*u[b,k] -------
// grid 256 = 32 btiles x 8 kchunks; 320 threads (co=tid%160, half=tid/160).
__global__ __launch_bounds__(320) void k_sj(
    const ushort* __restrict__ u_bf,          // [256][9216] bf16
    const __hip_bfloat16* __restrict__ Wt,    // [9216][160] bf16
    const float* __restrict__ cijT,           // [1152][10]
    float* __restrict__ partS)                // [16][256*160]
{
    __shared__ ushort ush[8 * 1152];
    __shared__ float cf[1440];
    const int tid = threadIdx.x;
    const int bt = blockIdx.x & 31, kc = blockIdx.x >> 5;
    const int co = tid % 160, half = tid / 160;

    for (int i = tid; i < 1152; i += 320)     // 8 b x 144 uint4
        ((uint4*)ush)[i] = ((const uint4*)u_bf)[(size_t)(bt * 8 + (i / 144)) * 1152
                                                + kc * 144 + (i % 144)];
    for (int i = tid; i < 1440; i += 320)
        cf[i] = cijT[kc * 1440 + i];
    __syncthreads();

    const int cc = co >> 4;
    const ushort* wp = (const ushort*)Wt + ((size_t)kc * 1152 + half * 576) * 160 + co;

    float acc[8] = {0.f, 0.f, 0.f, 0.f, 0.f, 0.f, 0.f, 0.f};
    for (int rr = 0; rr < 72; rr++) {
        float cl = cf[(half * 72 + rr) * 10 + cc];
        float wv[8];
        #pragma unroll
        for (int ii = 0; ii < 8; ii++)
            wv[ii] = b2f(wp[(rr * 8 + ii) * 160]) * cl;
        int kbase = half * 576 + rr * 8;
        #pragma unroll
        for (int bb = 0; bb < 8; bb++) {
            u16x8 uq = *(const u16x8*)&ush[bb * 1152 + kbase];
            #pragma unroll
            for (int ii = 0; ii < 8; ii++)
                acc[bb] += wv[ii] * b2f(uq[ii]);
        }
    }
    float* ps = partS + (kc * 2 + half) * 40960;
    #pragma unroll
    for (int bb = 0; bb < 8; bb++)
        ps[(bt * 8 + bb) * 160 + co] = acc[bb];
}

// ---------------- v = squash(sum partS) (+ final out) ----------------
__global__ __launch_bounds__(256) void k_vj(
    const float* __restrict__ partS, float* __restrict__ v,
    float* __restrict__ out, int write_out)
{
    int t = blockIdx.x * 256 + threadIdx.x;              // 40960 threads
    float s = 0.f;
    #pragma unroll
    for (int p = 0; p < 16; p++) s += partS[p * 40960 + t];
    float vv = s * fabsf(s) / (1.f + s * s);
    v[t] = vv;
    if (write_out) out[t] = vv;
}

// ---------------- M[k][co] = (1/256) sum_b u[b,k]*v[b,co] ----------------
__global__ __launch_bounds__(320) void k_mmat(
    const ushort* __restrict__ u_bf, const float* __restrict__ v,
    float* __restrict__ Mmat)                 // [9216][160]
{
    const int tid = threadIdx.x;
    const int kb = blockIdx.x;
    const int co = tid % 160, bh = tid / 160;
    float acc[8] = {0.f, 0.f, 0.f, 0.f, 0.f, 0.f, 0.f, 0.f};
    for (int b = bh; b < 256; b += 2) {
        float vv = v[b * 160 + co];
        u16x8 uq = *(const u16x8*)(u_bf + (size_t)b * 9216 + kb * 8);
        #pragma unroll
        for (int j = 0; j < 8; j++) acc[j] += vv * b2f(uq[j]);
    }
    __shared__ float red[2560];               // [j][bh][co]
    #pragma unroll
    for (int j = 0; j < 8; j++) red[j * 320 + bh * 160 + co] = acc[j];
    __syncthreads();
    if (tid < 160) {
        #pragma unroll
        for (int j = 0; j < 8; j++)
            Mmat[(size_t)(kb * 8 + j) * 160 + tid] =
                (red[j * 320 + tid] + red[j * 320 + 160 + tid]) * (1.f / 256.f);
    }
}

// ---------------- a[r,c] = sum_{o,i} W[r,c,o,i]*M[r*8+i][c*16+o]; bij += a ------
__global__ __launch_bounds__(256) void k_aij_contract(
    const float* __restrict__ W, const float* __restrict__ Mmat,
    float* __restrict__ bij)
{
    int t = blockIdx.x * 256 + threadIdx.x;              // 11520 threads
    if (t >= 11520) return;
    int r = t / 10, c = t % 10;
    const float* wp = W + (size_t)t * 128;               // W[r][c][:][:]
    float acc = 0.f;
    #pragma unroll
    for (int i = 0; i < 8; i++) {
        const float* mrow = Mmat + (size_t)(r * 8 + i) * 160 + c * 16;
        #pragma unroll
        for (int o = 0; o < 16; o++)
            acc += wp[o * 8 + i] * mrow[o];
    }
    bij[c * 1152 + r] += acc;                            // mean factor in Mmat
}

// ---------------- classifiers: sigmoid(w2 . relu(w1 . feat + b1) + b2) ----------
__global__ __launch_bounds__(128) void k_cls(
    const float* __restrict__ v, const float* __restrict__ w1,
    const float* __restrict__ b1, const float* __restrict__ w2,
    const float* __restrict__ b2, float* __restrict__ out)
{
    int bk = blockIdx.x;                                  // 2560 blocks
    int k = bk % 10, b = bk / 10;
    int tid = threadIdx.x;
    __shared__ float feat[160];
    __shared__ float red[128];
    for (int f = tid; f < 160; f += 128) feat[f] = v[b * 160 + f];
    __syncthreads();
    float h = 0.f;
    if (tid < 100) {
        float a = b1[k * 100 + tid];
        for (int f = 0; f < 160; f++) a += feat[f] * w1[(k * 160 + f) * 100 + tid];
        h = fmaxf(a, 0.f) * w2[k * 100 + tid];
    }
    red[tid] = h; __syncthreads();
    for (int s = 64; s > 0; s >>= 1) { if (tid < s) red[tid] += red[tid + s]; __syncthreads(); }
    if (tid == 0) {
        float logit = red[0] + b2[k];
        out[40960 + b * 10 + k] = 1.f / (1.f + expf(-logit));
    }
}

extern "C" void kernel_launch(void* const* d_in, const int* in_sizes, int n_in,
                              void* d_out, int out_size, void* d_ws, size_t ws_size,
                              hipStream_t stream) {
    const float* data    = (const float*)d_in[0];
    const float* conv1_w = (const float*)d_in[1];
    const float* conv1_b = (const float*)d_in[2];
    const float* conv2_w = (const float*)d_in[3];
    const float* conv2_b = (const float*)d_in[4];
    const float* prim_w  = (const float*)d_in[5];
    const float* prim_b  = (const float*)d_in[6];
    const float* W       = (const float*)d_in[7];
    const float* cls_w1  = (const float*)d_in[8];
    const float* cls_b1  = (const float*)d_in[9];
    const float* cls_w2  = (const float*)d_in[10];
    const float* cls_b2  = (const float*)d_in[11];
    float* out = (float*)d_out;

    char* ws = (char*)d_ws;
    // ws+0 (94.6 MB): Q (conv2 out) -> partU (56.6 MB split-K partials). Q is dead
    // after k_pool2t; partU written by k_primcaps_mfma afterwards. Sequential.
    // ws+94,633,984 (47.3 MB): P1t -> P2t (P1t dead after conv2). Sequential.
    __hip_bfloat16* Q     = (__hip_bfloat16*)(ws + 0);
    float*          partU = (float*)(ws + 0);
    __hip_bfloat16* P1t   = (__hip_bfloat16*)(ws + 94633984);
    __hip_bfloat16* P2t   = (__hip_bfloat16*)(ws + 94633984);
    __hip_bfloat16* Awt   = (__hip_bfloat16*)(ws + 141950976);  //  5,308,416
    __hip_bfloat16* Wt    = (__hip_bfloat16*)(ws + 147259392);  //  2,949,120
    ushort*         u_bf  = (ushort*)(ws + 150208512);          //  4,718,592
    float*          partS = (float*)(ws + 154927104);           //  2,621,440
    float*          Mmat  = (float*)(ws + 157548544);           //  5,898,240
    float*          v     = (float*)(ws + 163446784);           //    163,840
    float*          bij   = (float*)(ws + 163610624);           //     46,080
    float*          cijT  = (float*)(ws + 163656704);           //     46,080
    __hip_bfloat16* Aw2   = (__hip_bfloat16*)(ws + 163702784);  //    147,456
    __hip_bfloat16* Aw1   = (__hip_bfloat16*)(ws + 163850240);  //      4,096
    // total: 163,854,336 bytes (<= round-1 proven footprint 167,372,800)

    hipMemsetAsync(bij, 0, 11520 * sizeof(float), stream);

    k_prep_aw1<<<8, 256, 0, stream>>>(conv1_w, Aw1);
    k_prep_aw2<<<288, 256, 0, stream>>>(conv2_w, Aw2);
    k_prep_awt<<<10368, 256, 0, stream>>>(prim_w, Awt);
    k_prep_wt<<<5760, 256, 0, stream>>>(W, Wt);
    k_conv1_mfma<<<9728, 256, 0, stream>>>(data, Aw1, conv1_b, P1t);
    k_conv2_mfma<<<2888, 256, 0, stream>>>(P1t, Aw2, conv2_b, Q);
    k_pool2t<<<51200, 256, 0, stream>>>(Q, P2t);
    k_primcaps_mfma<<<864, 256, 0, stream>>>(P2t, Awt, partU);
    k_reduce_squash<<<1152, 256, 0, stream>>>(partU, prim_b, u_bf);

    for (int it = 0; it < 3; it++) {
        k_softmax<<<10, 256, 0, stream>>>(bij, cijT);
        k_sj<<<256, 320, 0, stream>>>(u_bf, Wt, cijT, partS);
        k_vj<<<160, 256, 0, stream>>>(partS, v, out, it == 2 ? 1 : 0);
        if (it < 2) {
            k_mmat<<<1152, 320, 0, stream>>>(u_bf, v, Mmat);
            k_aij_contract<<<45, 256, 0, stream>>>(W, Mmat, bij);
        }
    }
    k_cls<<<2560, 128, 0, stream>>>(v, cls_w1, cls_b1, cls_w2, cls_b2, out);
}

// Round 8
// 710.032 us; speedup vs baseline: 9.4582x; 1.0022x over previous
//
#include <hip/hip_runtime.h>
#include <hip/hip_bf16.h>

// CapsNet forward. Round 8: routing chain fused (softmax folded into sj via
// expb, mmat+aij one kernel per route, vj+cls one kernel per batch).
// Conv stack byte-identical to round 7 (verified). B=256,R=1152,C=10,O=16,I=8

typedef __bf16 bf16x8 __attribute__((ext_vector_type(8)));
typedef float  f32x4  __attribute__((ext_vector_type(4)));
typedef ushort u16x8  __attribute__((ext_vector_type(8)));

static __device__ __forceinline__ ushort f2bf(float f) {
    __hip_bfloat16 h = __float2bfloat16(f);
    return *(ushort*)&h;
}
static __device__ __forceinline__ float b2f(ushort u) {
    return __uint_as_float(((unsigned)u) << 16);
}

// ---------------- conv1_w (64,3,3,3) fp32 -> Aw1 [oc][k=ic*9+ky*3+kx] bf16, K pad 32
__global__ __launch_bounds__(256) void k_prep_aw1(
    const float* __restrict__ w1, __hip_bfloat16* __restrict__ Aw1)
{
    int t = blockIdx.x * 256 + threadIdx.x;              // 2048 threads
    int oc = t >> 5, k = t & 31;
    Aw1[t] = __float2bfloat16(k < 27 ? w1[oc * 27 + k] : 0.f);
}

// ---------------- conv1(3->64,3x3,s1,p0) + relu + maxpool(2,2,p1) via MFMA -------
__global__ __launch_bounds__(256) void k_conv1_mfma(
    const float* __restrict__ data, const __hip_bfloat16* __restrict__ Aw1,
    const float* __restrict__ b1, __hip_bfloat16* __restrict__ P1t)
{
    __shared__ float tile[960];          // [ic]*312 + [rloc]*78 + [lc]; lc = x_in+1
    const int tid = threadIdx.x;
    const int py = blockIdx.x % 38, b = blockIdx.x / 38;

    #pragma unroll
    for (int c = 0; c < 4; c++) {
        int idx = tid + c * 256;
        if (idx < 960) {
            float val = 0.f;
            if (idx < 936) {
                int ic = idx / 312, rem = idx % 312;
                int rl = rem / 78, lc = rem % 78;
                int ri = 2 * py - 1 + rl, xi = lc - 1;
                if ((unsigned)ri < 76u && (unsigned)xi < 76u)
                    val = data[(b * 3 + ic) * 5776 + ri * 76 + xi];
            }
            tile[idx] = val;
        }
    }

    const int wave = tid >> 6, lane = tid & 63;
    const int l15 = lane & 15, quad = lane >> 4;

    bf16x8 af = *(const bf16x8*)((const ushort*)Aw1 + (wave * 16 + l15) * 32 + quad * 8);

    int koff[8]; bool kok[8];
    #pragma unroll
    for (int j = 0; j < 8; j++) {
        int kk = quad * 8 + j;
        kok[j] = kk < 27;
        int ic = kk / 9, rem = kk - ic * 9, ky = rem / 3, kx = rem - ky * 3;
        koff[j] = kok[j] ? (ic * 312 + ky * 78 + kx) : 0;
    }

    float bias[4];
    #pragma unroll
    for (int r = 0; r < 4; r++) bias[r] = b1[wave * 16 + quad * 4 + r];

    const bool valid0 = (py > 0);
    const bool valid1 = (py < 37);

    __syncthreads();

    #pragma unroll
    for (int t5 = 0; t5 < 5; t5++) {
        int n_x = t5 * 16 + l15;                         // conv x = n_x - 1
        bool col_ok = (unsigned)(n_x - 1) < 74u;

        bf16x8 bf0, bf1;
        #pragma unroll
        for (int j = 0; j < 8; j++) {
            float v0 = tile[koff[j] + n_x];
            float v1 = tile[koff[j] + 78 + n_x];
            bool ok = col_ok && kok[j];
            bf0[j] = (__bf16)(ok ? v0 : 0.f);
            bf1[j] = (__bf16)(ok ? v1 : 0.f);
        }
        f32x4 z = {0.f, 0.f, 0.f, 0.f};
        f32x4 c0 = __builtin_amdgcn_mfma_f32_16x16x32_bf16(af, bf0, z, 0, 0, 0);
        f32x4 c1 = __builtin_amdgcn_mfma_f32_16x16x32_bf16(af, bf1, z, 0, 0, 0);

        f32x4 p;
        #pragma unroll
        for (int r = 0; r < 4; r++) {
            float r0 = (valid0 && col_ok) ? fmaxf(c0[r] + bias[r], 0.f) : 0.f;
            float r1 = (valid1 && col_ok) ? fmaxf(c1[r] + bias[r], 0.f) : 0.f;
            p[r] = fmaxf(r0, r1);
        }
        #pragma unroll
        for (int r = 0; r < 4; r++)
            p[r] = fmaxf(p[r], __shfl_xor(p[r], 1));

        if (!(l15 & 1)) {
            int px = t5 * 8 + (l15 >> 1);
            if (px < 38) {
                ushort4 pk;
                pk.x = f2bf(p[0]); pk.y = f2bf(p[1]);
                pk.z = f2bf(p[2]); pk.w = f2bf(p[3]);
                *(ushort4*)((ushort*)P1t + ((size_t)(b * 38 + py) * 38 + px) * 64
                            + wave * 16 + quad * 4) = pk;
            }
        }
    }
}

// ---------------- conv2_w (128,64,3,3) fp32 -> Aw2 [oc][(ky*3+kx)*64+ic] bf16 ----
__global__ __launch_bounds__(256) void k_prep_aw2(
    const float* __restrict__ w2, __hip_bfloat16* __restrict__ Aw2)
{
    int t = blockIdx.x * 256 + threadIdx.x;              // 128*576 threads
    int oc = t / 576, rem = t % 576;
    int k9 = rem >> 6, ic = rem & 63;
    Aw2[t] = __float2bfloat16(w2[(oc * 64 + ic) * 9 + k9]);
}

// ---------------- conv2 as MFMA GEMM + bias + relu ------------------------------
__global__ __launch_bounds__(256) void k_conv2_mfma(
    const __hip_bfloat16* __restrict__ P1t,   // [256][38][38][64]
    const __hip_bfloat16* __restrict__ Aw2,   // [128][576]
    const float* __restrict__ cb,             // [128]
    __hip_bfloat16* __restrict__ Q)
{
    __shared__ ushort lA[128 * 72];
    __shared__ ushort lB[128 * 72];
    const int tid  = threadIdx.x;
    const int bn   = blockIdx.x;              // 2888 N-blocks
    const int wave = tid >> 6, lane = tid & 63;
    const int wm   = wave & 1, wn = wave >> 1;
    const int lane15 = lane & 15, quad = lane >> 4;
    const int srow = tid & 127, shalf = tid >> 7;

    int n = bn * 128 + srow;
    int b = n / 1444, yx = n % 1444;
    int y = yx / 38, x = yx % 38;

    const __hip_bfloat16* Abase = Aw2 + srow * 576;
    ushort* lAw = &lA[srow * 72 + shalf * 32];
    ushort* lBw = &lB[srow * 72 + shalf * 32];
    const ushort* aRd = &lA[(wm * 64 + lane15) * 72 + quad * 8];
    const ushort* bRd = &lB[(wn * 64 + lane15) * 72 + quad * 8];

    f32x4 zero = {0.f, 0.f, 0.f, 0.f};
    f32x4 acc[4][4];
    #pragma unroll
    for (int i = 0; i < 4; i++)
        #pragma unroll
        for (int j = 0; j < 4; j++) acc[i][j] = zero;

    for (int kb = 0; kb < 9; kb++) {
        int ky = kb / 3, kx = kb - ky * 3;
        int iy = y + ky - 1, ix = x + kx - 1;
        bool ok = ((unsigned)iy < 38u) && ((unsigned)ix < 38u);

        const uint4* ga = (const uint4*)(Abase + kb * 64 + shalf * 32);
        uint4 av0 = ga[0], av1 = ga[1], av2 = ga[2], av3 = ga[3];
        uint4 z4 = {0u, 0u, 0u, 0u};
        uint4 bv0 = z4, bv1 = z4, bv2 = z4, bv3 = z4;
        if (ok) {
            const uint4* gb = (const uint4*)(P1t + (((b * 38 + iy) * 38 + ix) << 6) + shalf * 32);
            bv0 = gb[0]; bv1 = gb[1]; bv2 = gb[2]; bv3 = gb[3];
        }

        __syncthreads();
        ((uint4*)lAw)[0] = av0; ((uint4*)lAw)[1] = av1;
        ((uint4*)lAw)[2] = av2; ((uint4*)lAw)[3] = av3;
        ((uint4*)lBw)[0] = bv0; ((uint4*)lBw)[1] = bv1;
        ((uint4*)lBw)[2] = bv2; ((uint4*)lBw)[3] = bv3;
        __syncthreads();

        #pragma unroll
        for (int kk = 0; kk < 2; kk++) {
            bf16x8 af[4], bf[4];
            #pragma unroll
            for (int tm = 0; tm < 4; tm++)
                af[tm] = *(const bf16x8*)(aRd + tm * 16 * 72 + kk * 32);
            #pragma unroll
            for (int tn = 0; tn < 4; tn++)
                bf[tn] = *(const bf16x8*)(bRd + tn * 16 * 72 + kk * 32);
            #pragma unroll
            for (int tm = 0; tm < 4; tm++)
                #pragma unroll
                for (int tn = 0; tn < 4; tn++)
                    acc[tm][tn] = __builtin_amdgcn_mfma_f32_16x16x32_bf16(
                        af[tm], bf[tn], acc[tm][tn], 0, 0, 0);
        }
    }

    #pragma unroll
    for (int tm = 0; tm < 4; tm++) {
        int m0 = wm * 64 + tm * 16 + quad * 4;
        float b0 = cb[m0], b1 = cb[m0 + 1], b2 = cb[m0 + 2], b3 = cb[m0 + 3];
        #pragma unroll
        for (int tn = 0; tn < 4; tn++) {
            int nn = bn * 128 + wn * 64 + tn * 16 + lane15;
            f32x4 a = acc[tm][tn];
            ushort4 pk;
            pk.x = f2bf(fmaxf(a[0] + b0, 0.f));
            pk.y = f2bf(fmaxf(a[1] + b1, 0.f));
            pk.z = f2bf(fmaxf(a[2] + b2, 0.f));
            pk.w = f2bf(fmaxf(a[3] + b3, 0.f));
            *(ushort4*)((ushort*)Q + (size_t)nn * 128 + m0) = pk;
        }
    }
}

// ---------------- maxpool(2,2,p1) over Q -> P2t [256][20][20][128] ----------------
__global__ __launch_bounds__(256) void k_pool2t(
    const __hip_bfloat16* __restrict__ Q, __hip_bfloat16* __restrict__ P2t)
{
    int t = blockIdx.x * 256 + threadIdx.x;              // 256*400*128 threads
    int ic = t & 127, rest = t >> 7;
    int px = rest % 20, py = (rest / 20) % 20, b = rest / 400;
    float m = 0.f;
    #pragma unroll
    for (int dy = 0; dy < 2; dy++) {
        int y = 2 * py - 1 + dy;
        if ((unsigned)y >= 38u) continue;
        #pragma unroll
        for (int dx = 0; dx < 2; dx++) {
            int x = 2 * px - 1 + dx;
            if ((unsigned)x >= 38u) continue;
            m = fmaxf(m, __bfloat162float(Q[(((b * 38 + y) * 38 + x) << 7) + ic]));
        }
    }
    P2t[t] = __float2bfloat16(m);
}

// ---------------- prim_w (256,128,81) fp32 -> Awt [oc][(ky*9+kx)*128+ic] bf16 ----
__global__ __launch_bounds__(256) void k_prep_awt(
    const float* __restrict__ pw, __hip_bfloat16* __restrict__ Awt)
{
    int t = blockIdx.x * 256 + threadIdx.x;              // 256*10368 threads
    int oc = t / 10368, rem = t % 10368;
    int k81 = rem >> 7, ic = rem & 127;
    Awt[t] = __float2bfloat16(pw[(oc * 128 + ic) * 81 + k81]);
}

// ---------------- W (1152,10,16,8) fp32 -> Wt [k=r*8+i][co=c*16+o] bf16 ----------
__global__ __launch_bounds__(256) void k_prep_wt(
    const float* __restrict__ W, __hip_bfloat16* __restrict__ Wt)
{
    int t = blockIdx.x * 256 + threadIdx.x;              // 1,474,560 threads
    int k = t / 160, co = t % 160;
    int r = k >> 3, i = k & 7, c = co >> 4, o = co & 15;
    Wt[t] = __float2bfloat16(W[(((size_t)r * 10 + c) * 16 + o) * 8 + i]);
}

// ---------------- primcaps split-K MFMA GEMM -> 6 fp32 partials ------------------
__global__ __launch_bounds__(256) void k_primcaps_mfma(
    const __hip_bfloat16* __restrict__ P2t,   // [256][20][20][128]
    const __hip_bfloat16* __restrict__ Awt,   // [256][10368]
    float* __restrict__ partU)                // [6][2359296]
{
    __shared__ ushort lA[128 * 72];
    __shared__ ushort lB[128 * 72];
    const int tid  = threadIdx.x;
    const int chunk = blockIdx.x / 144;
    const int tile  = blockIdx.x % 144;
    const int bm   = tile & 1;
    const int bn   = tile >> 1;
    const int wave = tid >> 6, lane = tid & 63;
    const int wm   = wave & 1, wn = wave >> 1;
    const int lane15 = lane & 15, quad = lane >> 4;
    const int srow = tid & 127, shalf = tid >> 7;

    int n  = bn * 128 + srow;
    int cb = n / 36, cs = n % 36;
    int cy = cs / 6, cx = cs % 6;
    const __hip_bfloat16* Bbase = P2t + ((cb * 20 + 2 * cy) * 20 + 2 * cx) * 128;
    const __hip_bfloat16* Abase = Awt + (bm * 128 + srow) * 10368;
    ushort* lAw = &lA[srow * 72 + shalf * 32];
    ushort* lBw = &lB[srow * 72 + shalf * 32];
    const ushort* aRd = &lA[(wm * 64 + lane15) * 72 + quad * 8];
    const ushort* bRd = &lB[(wn * 64 + lane15) * 72 + quad * 8];

    f32x4 zero = {0.f, 0.f, 0.f, 0.f};
    f32x4 acc[4][4];
    #pragma unroll
    for (int i = 0; i < 4; i++)
        #pragma unroll
        for (int j = 0; j < 4; j++) acc[i][j] = zero;

    const int kb0 = chunk * 27;
    for (int ki = 0; ki < 27; ki++) {
        int kb = kb0 + ki;
        int k81 = kb >> 1;
        int ky = k81 / 9, kx = k81 - ky * 9;
        int goffA = kb * 64 + shalf * 32;
        int goffB = (ky * 20 + kx) * 128 + (kb & 1) * 64 + shalf * 32;

        const uint4* ga = (const uint4*)(Abase + goffA);
        const uint4* gb = (const uint4*)(Bbase + goffB);
        uint4 av0 = ga[0], av1 = ga[1], av2 = ga[2], av3 = ga[3];
        uint4 bv0 = gb[0], bv1 = gb[1], bv2 = gb[2], bv3 = gb[3];

        __syncthreads();
        ((uint4*)lAw)[0] = av0; ((uint4*)lAw)[1] = av1;
        ((uint4*)lAw)[2] = av2; ((uint4*)lAw)[3] = av3;
        ((uint4*)lBw)[0] = bv0; ((uint4*)lBw)[1] = bv1;
        ((uint4*)lBw)[2] = bv2; ((uint4*)lBw)[3] = bv3;
        __syncthreads();

        #pragma unroll
        for (int kk = 0; kk < 2; kk++) {
            bf16x8 af[4], bf[4];
            #pragma unroll
            for (int tm = 0; tm < 4; tm++)
                af[tm] = *(const bf16x8*)(aRd + tm * 16 * 72 + kk * 32);
            #pragma unroll
            for (int tn = 0; tn < 4; tn++)
                bf[tn] = *(const bf16x8*)(bRd + tn * 16 * 72 + kk * 32);
            #pragma unroll
            for (int tm = 0; tm < 4; tm++)
                #pragma unroll
                for (int tn = 0; tn < 4; tn++)
                    acc[tm][tn] = __builtin_amdgcn_mfma_f32_16x16x32_bf16(
                        af[tm], bf[tn], acc[tm][tn], 0, 0, 0);
        }
    }

    float* base = partU + chunk * 2359296;
    #pragma unroll
    for (int tm = 0; tm < 4; tm++) {
        int m0 = bm * 128 + wm * 64 + tm * 16 + quad * 4;
        #pragma unroll
        for (int tn = 0; tn < 4; tn++) {
            int nn = bn * 128 + wn * 64 + tn * 16 + lane15;
            int ob = nn / 36, os = nn % 36;
            float* up = base + ob * 9216 + os;
            f32x4 a = acc[tm][tn];
            #pragma unroll
            for (int r = 0; r < 4; r++)
                up[(m0 + r) * 36] = a[r];
        }
    }
}

// ---------------- reduce 6 partials + bias + squash -> u_bf [b][k] bf16 ----------
__global__ __launch_bounds__(256) void k_reduce_squash(
    const float* __restrict__ partU, const float* __restrict__ pb,
    ushort* __restrict__ u_bf)
{
    int t = blockIdx.x * 256 + threadIdx.x;              // 294912 threads
    float4 a = {0.f, 0.f, 0.f, 0.f}, b4 = {0.f, 0.f, 0.f, 0.f};
    #pragma unroll
    for (int p = 0; p < 6; p++) {
        const float4* pp = (const float4*)(partU + p * 2359296 + t * 8);
        float4 x = pp[0], y = pp[1];
        a.x += x.x; a.y += x.y; a.z += x.z; a.w += x.w;
        b4.x += y.x; b4.y += y.y; b4.z += y.z; b4.w += y.w;
    }
    int lb = (t % 1152) * 8;
    int oc0 = lb / 36, s0 = lb - oc0 * 36;
    float vals[8] = {a.x, a.y, a.z, a.w, b4.x, b4.y, b4.z, b4.w};
    float sn = 0.f;
    #pragma unroll
    for (int e = 0; e < 8; e++) {
        int oc = oc0 + ((s0 + e) >= 36 ? 1 : 0);
        vals[e] += pb[oc];
        sn += vals[e] * vals[e];
    }
    float sc = sqrtf(sn) / (1.f + sn);
    u16x8 o8;
    #pragma unroll
    for (int e = 0; e < 8; e++) o8[e] = f2bf(vals[e] * sc);
    *(u16x8*)(u_bf + (size_t)t * 8) = o8;
}

// ---------------- s_j with inline softmax: s[b,co] = sum_k c[r,c]*Wt[k,co]*u[b,k]
// iter==0: c = 1/1152 exactly (softmax of zeros). iter>0: c = expb[r,c]/S[c],
// S computed redundantly per block (expb is 46KB, L2-resident).
// grid 256 = 32 btiles x 8 kchunks; 320 threads (co=tid%160, half=tid/160).
__global__ __launch_bounds__(320) void k_sj_fused(
    const ushort* __restrict__ u_bf,          // [256][9216] bf16
    const __hip_bfloat16* __restrict__ Wt,    // [9216][160] bf16
    const float* __restrict__ expb,           // [1152][10]
    float* __restrict__ partS,                // [16][256*160]
    int iter)
{
    __shared__ ushort ush[8 * 1152];
    __shared__ float cf[1440];
    __shared__ float sred[320];
    __shared__ float sinv[10];
    const int tid = threadIdx.x;
    const int bt = blockIdx.x & 31, kc = blockIdx.x >> 5;
    const int co = tid % 160, half = tid / 160;

    if (iter > 0) {
        int c = tid % 10, g = tid / 10;                  // 10 x 32 partition
        float s = 0.f;
        for (int r = g; r < 1152; r += 32) s += expb[r * 10 + c];
        sred[tid] = s;
        for (int i = tid; i < 1440; i += 320) cf[i] = expb[kc * 1440 + i];
        __syncthreads();
        if (tid < 10) {
            float t2 = 0.f;
            #pragma unroll
            for (int gg = 0; gg < 32; gg++) t2 += sred[tid + gg * 10];
            sinv[tid] = 1.f / t2;
        }
    }
    for (int i = tid; i < 1152; i += 320)     // 8 b x 144 uint4
        ((uint4*)ush)[i] = ((const uint4*)u_bf)[(size_t)(bt * 8 + (i / 144)) * 1152
                                                + kc * 144 + (i % 144)];
    __syncthreads();

    const int cc = co >> 4;
    const float scl = (iter > 0) ? sinv[cc] : 0.f;
    const float cuni = 1.f / 1152.f;
    const ushort* wp = (const ushort*)Wt + ((size_t)kc * 1152 + half * 576) * 160 + co;

    float acc[8] = {0.f, 0.f, 0.f, 0.f, 0.f, 0.f, 0.f, 0.f};
    for (int rr = 0; rr < 72; rr++) {
        float cl = (iter == 0) ? cuni : cf[(half * 72 + rr) * 10 + cc] * scl;
        float wv[8];
        #pragma unroll
        for (int ii = 0; ii < 8; ii++)
            wv[ii] = b2f(wp[(rr * 8 + ii) * 160]) * cl;
        int kbase = half * 576 + rr * 8;
        #pragma unroll
        for (int bb = 0; bb < 8; bb++) {
            u16x8 uq = *(const u16x8*)&ush[bb * 1152 + kbase];
            #pragma unroll
            for (int ii = 0; ii < 8; ii++)
                acc[bb] += wv[ii] * b2f(uq[ii]);
        }
    }
    float* ps = partS + (kc * 2 + half) * 40960;
    #pragma unroll
    for (int bb = 0; bb < 8; bb++)
        ps[(bt * 8 + bb) * 160 + co] = acc[bb];
}

// ---------------- v = squash(sum partS); final iter also runs classifiers -------
// block per b (256), 320 threads.
__global__ __launch_bounds__(320) void k_vj_cls(
    const float* __restrict__ partS, float* __restrict__ v,
    const float* __restrict__ w1, const float* __restrict__ b1,
    const float* __restrict__ w2, const float* __restrict__ b2,
    float* __restrict__ out, int write_out)
{
    const int b = blockIdx.x;
    const int tid = threadIdx.x;
    __shared__ float feat[160];
    if (tid < 160) {
        float s = 0.f;
        #pragma unroll
        for (int p = 0; p < 16; p++) s += partS[p * 40960 + b * 160 + tid];
        float vv = s * fabsf(s) / (1.f + s * s);
        v[b * 160 + tid] = vv;
        feat[tid] = vv;
        if (write_out) out[b * 160 + tid] = vv;
    }
    if (!write_out) return;
    __syncthreads();
    int k = tid >> 5, j = tid & 31;                      // 10 classifiers x 32 lanes
    float acc = 0.f;
    for (int h = j; h < 100; h += 32) {
        float a = b1[k * 100 + h];
        for (int f = 0; f < 160; f++) a += feat[f] * w1[(k * 160 + f) * 100 + h];
        acc += fmaxf(a, 0.f) * w2[k * 100 + h];
    }
    #pragma unroll
    for (int d = 16; d > 0; d >>= 1) acc += __shfl_xor(acc, d);
    if (j == 0)
        out[40960 + b * 10 + k] = 1.f / (1.f + expf(-(acc + b2[k])));
}

// ---------------- M rows for route r + a_ij + bij update + expb -----------------
// block r (1152), 320 threads. M[i][co] = (1/256) sum_b u[b,r*8+i]*v[b,co] kept in
// LDS; a[r,c] = sum_{o,i} W[r,c,o,i]*M[i][c*16+o]; bij += a; expb = exp(bij).
__global__ __launch_bounds__(320) void k_mmat_aij(
    const ushort* __restrict__ u_bf, const float* __restrict__ v,
    const float* __restrict__ W, float* __restrict__ bij,
    float* __restrict__ expb)
{
    const int r = blockIdx.x;
    const int tid = threadIdx.x;
    const int co = tid % 160, bh = tid / 160;
    float acc[8] = {0.f, 0.f, 0.f, 0.f, 0.f, 0.f, 0.f, 0.f};
    for (int b = bh; b < 256; b += 2) {
        float vv = v[b * 160 + co];
        u16x8 uq = *(const u16x8*)(u_bf + (size_t)b * 9216 + r * 8);
        #pragma unroll
        for (int j = 0; j < 8; j++) acc[j] += vv * b2f(uq[j]);
    }
    __shared__ float red[2560];               // [j][bh][co]
    __shared__ float Ml[8][160];
    #pragma unroll
    for (int j = 0; j < 8; j++) red[j * 320 + bh * 160 + co] = acc[j];
    __syncthreads();
    if (tid < 160) {
        #pragma unroll
        for (int j = 0; j < 8; j++)
            Ml[j][tid] = (red[j * 320 + tid] + red[j * 320 + 160 + tid]) * (1.f / 256.f);
    }
    __syncthreads();
    int c = tid >> 5, j32 = tid & 31;                    // 10 c x 32 lanes
    const float* wr = W + ((size_t)r * 10 + c) * 128;    // W[r][c][o][i] flat
    float a2 = 0.f;
    #pragma unroll
    for (int m = 0; m < 4; m++) {
        int idx = j32 + m * 32;                          // = o*8 + i
        int o = idx >> 3, i = idx & 7;
        a2 += wr[idx] * Ml[i][c * 16 + o];
    }
    #pragma unroll
    for (int d = 16; d > 0; d >>= 1) a2 += __shfl_xor(a2, d);
    if (j32 == 0) {
        float nb = bij[c * 1152 + r] + a2;
        bij[c * 1152 + r] = nb;
        expb[r * 10 + c] = expf(nb);                     // |nb| small: no max-sub needed
    }
}

extern "C" void kernel_launch(void* const* d_in, const int* in_sizes, int n_in,
                              void* d_out, int out_size, void* d_ws, size_t ws_size,
                              hipStream_t stream) {
    const float* data    = (const float*)d_in[0];
    const float* conv1_w = (const float*)d_in[1];
    const float* conv1_b = (const float*)d_in[2];
    const float* conv2_w = (const float*)d_in[3];
    const float* conv2_b = (const float*)d_in[4];
    const float* prim_w  = (const float*)d_in[5];
    const float* prim_b  = (const float*)d_in[6];
    const float* W       = (const float*)d_in[7];
    const float* cls_w1  = (const float*)d_in[8];
    const float* cls_b1  = (const float*)d_in[9];
    const float* cls_w2  = (const float*)d_in[10];
    const float* cls_b2  = (const float*)d_in[11];
    float* out = (float*)d_out;

    char* ws = (char*)d_ws;
    // ws+0 (94.6 MB): Q (conv2 out) -> partU (56.6 MB split-K partials).
    // ws+94,633,984 (47.3 MB): P1t -> P2t. Both sequential-lifetime reuses.
    __hip_bfloat16* Q     = (__hip_bfloat16*)(ws + 0);
    float*          partU = (float*)(ws + 0);
    __hip_bfloat16* P1t   = (__hip_bfloat16*)(ws + 94633984);
    __hip_bfloat16* P2t   = (__hip_bfloat16*)(ws + 94633984);
    __hip_bfloat16* Awt   = (__hip_bfloat16*)(ws + 141950976);  //  5,308,416
    __hip_bfloat16* Wt    = (__hip_bfloat16*)(ws + 147259392);  //  2,949,120
    ushort*         u_bf  = (ushort*)(ws + 150208512);          //  4,718,592
    float*          partS = (float*)(ws + 154927104);           //  2,621,440
    float*          v     = (float*)(ws + 163446784);           //    163,840
    float*          bij   = (float*)(ws + 163610624);           //     46,080
    float*          expb  = (float*)(ws + 163656704);           //     46,080
    __hip_bfloat16* Aw2   = (__hip_bfloat16*)(ws + 163702784);  //    147,456
    __hip_bfloat16* Aw1   = (__hip_bfloat16*)(ws + 163850240);  //      4,096
    // total: 163,854,336 bytes

    hipMemsetAsync(bij, 0, 11520 * sizeof(float), stream);

    k_prep_aw1<<<8, 256, 0, stream>>>(conv1_w, Aw1);
    k_prep_aw2<<<288, 256, 0, stream>>>(conv2_w, Aw2);
    k_prep_awt<<<10368, 256, 0, stream>>>(prim_w, Awt);
    k_prep_wt<<<5760, 256, 0, stream>>>(W, Wt);
    k_conv1_mfma<<<9728, 256, 0, stream>>>(data, Aw1, conv1_b, P1t);
    k_conv2_mfma<<<2888, 256, 0, stream>>>(P1t, Aw2, conv2_b, Q);
    k_pool2t<<<51200, 256, 0, stream>>>(Q, P2t);
    k_primcaps_mfma<<<864, 256, 0, stream>>>(P2t, Awt, partU);
    k_reduce_squash<<<1152, 256, 0, stream>>>(partU, prim_b, u_bf);

    for (int it = 0; it < 3; it++) {
        k_sj_fused<<<256, 320, 0, stream>>>(u_bf, Wt, expb, partS, it);
        k_vj_cls<<<256, 320, 0, stream>>>(partS, v, cls_w1, cls_b1, cls_w2,
                                          cls_b2, out, it == 2 ? 1 : 0);
        if (it < 2)
            k_mmat_aij<<<1152, 320, 0, stream>>>(u_bf, v, W, bij, expb);
    }
}

// Round 9
// 659.200 us; speedup vs baseline: 10.1876x; 1.0771x over previous
//
#include <hip/hip_runtime.h>
#include <hip/hip_bf16.h>

// CapsNet forward. Round 9: conv2 N-tile 256 (512 thr, 2x4 waves, halved
// barrier-drains, shared A staging); 4 prep kernels fused into one.
// Rest byte-identical to round 8 (passing). B=256,R=1152,C=10,O=16,I=8

typedef __bf16 bf16x8 __attribute__((ext_vector_type(8)));
typedef float  f32x4  __attribute__((ext_vector_type(4)));
typedef ushort u16x8  __attribute__((ext_vector_type(8)));

static __device__ __forceinline__ ushort f2bf(float f) {
    __hip_bfloat16 h = __float2bfloat16(f);
    return *(ushort*)&h;
}
static __device__ __forceinline__ float b2f(ushort u) {
    return __uint_as_float(((unsigned)u) << 16);
}

// ---------------- fused weight prep: Awt | Wt | Aw2 | Aw1 ------------------------
// thread ranges: [0,2654208) Awt, [.., 4128768) Wt, [.., 4202496) Aw2, [..] Aw1
__global__ __launch_bounds__(256) void k_prep_all(
    const float* __restrict__ w1, const float* __restrict__ w2,
    const float* __restrict__ pw, const float* __restrict__ W,
    __hip_bfloat16* __restrict__ Aw1, __hip_bfloat16* __restrict__ Aw2,
    __hip_bfloat16* __restrict__ Awt, __hip_bfloat16* __restrict__ Wt)
{
    int t = blockIdx.x * 256 + threadIdx.x;              // 4,204,544 threads
    if (t < 2654208) {
        int oc = t / 10368, rem = t % 10368;
        int k81 = rem >> 7, ic = rem & 127;
        Awt[t] = __float2bfloat16(pw[(oc * 128 + ic) * 81 + k81]);
    } else if (t < 4128768) {
        int q = t - 2654208;
        int k = q / 160, co = q % 160;
        int r = k >> 3, i = k & 7, c = co >> 4, o = co & 15;
        Wt[q] = __float2bfloat16(W[(((size_t)r * 10 + c) * 16 + o) * 8 + i]);
    } else if (t < 4202496) {
        int q = t - 4128768;
        int oc = q / 576, rem = q % 576;
        int k9 = rem >> 6, ic = rem & 63;
        Aw2[q] = __float2bfloat16(w2[(oc * 64 + ic) * 9 + k9]);
    } else {
        int q = t - 4202496;
        int oc = q >> 5, k = q & 31;
        Aw1[q] = __float2bfloat16(k < 27 ? w1[oc * 27 + k] : 0.f);
    }
}

// ---------------- conv1(3->64,3x3,s1,p0) + relu + maxpool(2,2,p1) via MFMA -------
__global__ __launch_bounds__(256) void k_conv1_mfma(
    const float* __restrict__ data, const __hip_bfloat16* __restrict__ Aw1,
    const float* __restrict__ b1, __hip_bfloat16* __restrict__ P1t)
{
    __shared__ float tile[960];          // [ic]*312 + [rloc]*78 + [lc]; lc = x_in+1
    const int tid = threadIdx.x;
    const int py = blockIdx.x % 38, b = blockIdx.x / 38;

    #pragma unroll
    for (int c = 0; c < 4; c++) {
        int idx = tid + c * 256;
        if (idx < 960) {
            float val = 0.f;
            if (idx < 936) {
                int ic = idx / 312, rem = idx % 312;
                int rl = rem / 78, lc = rem % 78;
                int ri = 2 * py - 1 + rl, xi = lc - 1;
                if ((unsigned)ri < 76u && (unsigned)xi < 76u)
                    val = data[(b * 3 + ic) * 5776 + ri * 76 + xi];
            }
            tile[idx] = val;
        }
    }

    const int wave = tid >> 6, lane = tid & 63;
    const int l15 = lane & 15, quad = lane >> 4;

    bf16x8 af = *(const bf16x8*)((const ushort*)Aw1 + (wave * 16 + l15) * 32 + quad * 8);

    int koff[8]; bool kok[8];
    #pragma unroll
    for (int j = 0; j < 8; j++) {
        int kk = quad * 8 + j;
        kok[j] = kk < 27;
        int ic = kk / 9, rem = kk - ic * 9, ky = rem / 3, kx = rem - ky * 3;
        koff[j] = kok[j] ? (ic * 312 + ky * 78 + kx) : 0;
    }

    float bias[4];
    #pragma unroll
    for (int r = 0; r < 4; r++) bias[r] = b1[wave * 16 + quad * 4 + r];

    const bool valid0 = (py > 0);
    const bool valid1 = (py < 37);

    __syncthreads();

    #pragma unroll
    for (int t5 = 0; t5 < 5; t5++) {
        int n_x = t5 * 16 + l15;                         // conv x = n_x - 1
        bool col_ok = (unsigned)(n_x - 1) < 74u;

        bf16x8 bf0, bf1;
        #pragma unroll
        for (int j = 0; j < 8; j++) {
            float v0 = tile[koff[j] + n_x];
            float v1 = tile[koff[j] + 78 + n_x];
            bool ok = col_ok && kok[j];
            bf0[j] = (__bf16)(ok ? v0 : 0.f);
            bf1[j] = (__bf16)(ok ? v1 : 0.f);
        }
        f32x4 z = {0.f, 0.f, 0.f, 0.f};
        f32x4 c0 = __builtin_amdgcn_mfma_f32_16x16x32_bf16(af, bf0, z, 0, 0, 0);
        f32x4 c1 = __builtin_amdgcn_mfma_f32_16x16x32_bf16(af, bf1, z, 0, 0, 0);

        f32x4 p;
        #pragma unroll
        for (int r = 0; r < 4; r++) {
            float r0 = (valid0 && col_ok) ? fmaxf(c0[r] + bias[r], 0.f) : 0.f;
            float r1 = (valid1 && col_ok) ? fmaxf(c1[r] + bias[r], 0.f) : 0.f;
            p[r] = fmaxf(r0, r1);
        }
        #pragma unroll
        for (int r = 0; r < 4; r++)
            p[r] = fmaxf(p[r], __shfl_xor(p[r], 1));

        if (!(l15 & 1)) {
            int px = t5 * 8 + (l15 >> 1);
            if (px < 38) {
                ushort4 pk;
                pk.x = f2bf(p[0]); pk.y = f2bf(p[1]);
                pk.z = f2bf(p[2]); pk.w = f2bf(p[3]);
                *(ushort4*)((ushort*)P1t + ((size_t)(b * 38 + py) * 38 + px) * 64
                            + wave * 16 + quad * 4) = pk;
            }
        }
    }
}

// ---------------- conv2 as MFMA GEMM + bias + relu, N=256 tile ------------------
// M=128 (oc), N=369664 (1444 tiles of 256), K=576. 512 threads, 2x4 waves of
// 64x64. A-tile (128x64) staged once per kb, shared by both N-halves.
// out: Q [256][38][38][128] bf16 (oc innermost). Bit-identical math to round 8.
__global__ __launch_bounds__(512) void k_conv2_mfma(
    const __hip_bfloat16* __restrict__ P1t,   // [256][38][38][64]
    const __hip_bfloat16* __restrict__ Aw2,   // [128][576]
    const float* __restrict__ cb,             // [128]
    __hip_bfloat16* __restrict__ Q)
{
    __shared__ ushort lA[128 * 72];           // 18,432 B
    __shared__ ushort lB[256 * 72];           // 36,864 B
    const int tid  = threadIdx.x;
    const int bn   = blockIdx.x;              // 1444 N-blocks
    const int wave = tid >> 6, lane = tid & 63;
    const int wm   = wave & 1, wn = wave >> 1;      // 2 x 4 waves
    const int lane15 = lane & 15, quad = lane >> 4;

    // staging assignment: A: 4 threads/row x 16 elems; B: 2 threads/row x 32 elems
    const int arow = tid >> 2, apart = tid & 3;
    const int brow = tid >> 1, bpart = tid & 1;

    int n = bn * 256 + brow;
    int b = n / 1444, yx = n % 1444;
    int y = yx / 38, x = yx % 38;

    const __hip_bfloat16* Abase = Aw2 + arow * 576;
    ushort* lAw = &lA[arow * 72 + apart * 16];
    ushort* lBw = &lB[brow * 72 + bpart * 32];
    const ushort* aRd = &lA[(wm * 64 + lane15) * 72 + quad * 8];
    const ushort* bRd = &lB[(wn * 64 + lane15) * 72 + quad * 8];

    f32x4 zero = {0.f, 0.f, 0.f, 0.f};
    f32x4 acc[4][4];
    #pragma unroll
    for (int i = 0; i < 4; i++)
        #pragma unroll
        for (int j = 0; j < 4; j++) acc[i][j] = zero;

    for (int kb = 0; kb < 9; kb++) {                      // tap (ky,kx), 64 ic each
        int ky = kb / 3, kx = kb - ky * 3;
        int iy = y + ky - 1, ix = x + kx - 1;
        bool ok = ((unsigned)iy < 38u) && ((unsigned)ix < 38u);

        const uint4* ga = (const uint4*)(Abase + kb * 64 + apart * 16);
        uint4 av0 = ga[0], av1 = ga[1];
        uint4 z4 = {0u, 0u, 0u, 0u};
        uint4 bv0 = z4, bv1 = z4, bv2 = z4, bv3 = z4;
        if (ok) {
            const uint4* gb = (const uint4*)(P1t + (((b * 38 + iy) * 38 + ix) << 6) + bpart * 32);
            bv0 = gb[0]; bv1 = gb[1]; bv2 = gb[2]; bv3 = gb[3];
        }

        __syncthreads();               // previous iter's LDS reads complete
        ((uint4*)lAw)[0] = av0; ((uint4*)lAw)[1] = av1;
        ((uint4*)lBw)[0] = bv0; ((uint4*)lBw)[1] = bv1;
        ((uint4*)lBw)[2] = bv2; ((uint4*)lBw)[3] = bv3;
        __syncthreads();

        #pragma unroll
        for (int kk = 0; kk < 2; kk++) {
            bf16x8 af[4], bf[4];
            #pragma unroll
            for (int tm = 0; tm < 4; tm++)
                af[tm] = *(const bf16x8*)(aRd + tm * 16 * 72 + kk * 32);
            #pragma unroll
            for (int tn = 0; tn < 4; tn++)
                bf[tn] = *(const bf16x8*)(bRd + tn * 16 * 72 + kk * 32);
            #pragma unroll
            for (int tm = 0; tm < 4; tm++)
                #pragma unroll
                for (int tn = 0; tn < 4; tn++)
                    acc[tm][tn] = __builtin_amdgcn_mfma_f32_16x16x32_bf16(
                        af[tm], bf[tn], acc[tm][tn], 0, 0, 0);
        }
    }

    #pragma unroll
    for (int tm = 0; tm < 4; tm++) {
        int m0 = wm * 64 + tm * 16 + quad * 4;
        float b0 = cb[m0], b1 = cb[m0 + 1], b2 = cb[m0 + 2], b3 = cb[m0 + 3];
        #pragma unroll
        for (int tn = 0; tn < 4; tn++) {
            int nn = bn * 256 + wn * 64 + tn * 16 + lane15;
            f32x4 a = acc[tm][tn];
            ushort4 pk;
            pk.x = f2bf(fmaxf(a[0] + b0, 0.f));
            pk.y = f2bf(fmaxf(a[1] + b1, 0.f));
            pk.z = f2bf(fmaxf(a[2] + b2, 0.f));
            pk.w = f2bf(fmaxf(a[3] + b3, 0.f));
            *(ushort4*)((ushort*)Q + (size_t)nn * 128 + m0) = pk;
        }
    }
}

// ---------------- maxpool(2,2,p1) over Q -> P2t [256][20][20][128] ----------------
__global__ __launch_bounds__(256) void k_pool2t(
    const __hip_bfloat16* __restrict__ Q, __hip_bfloat16* __restrict__ P2t)
{
    int t = blockIdx.x * 256 + threadIdx.x;              // 256*400*128 threads
    int ic = t & 127, rest = t >> 7;
    int px = rest % 20, py = (rest / 20) % 20, b = rest / 400;
    float m = 0.f;
    #pragma unroll
    for (int dy = 0; dy < 2; dy++) {
        int y = 2 * py - 1 + dy;
        if ((unsigned)y >= 38u) continue;
        #pragma unroll
        for (int dx = 0; dx < 2; dx++) {
            int x = 2 * px - 1 + dx;
            if ((unsigned)x >= 38u) continue;
            m = fmaxf(m, __bfloat162float(Q[(((b * 38 + y) * 38 + x) << 7) + ic]));
        }
    }
    P2t[t] = __float2bfloat16(m);
}

// ---------------- primcaps split-K MFMA GEMM -> 6 fp32 partials ------------------
__global__ __launch_bounds__(256) void k_primcaps_mfma(
    const __hip_bfloat16* __restrict__ P2t,   // [256][20][20][128]
    const __hip_bfloat16* __restrict__ Awt,   // [256][10368]
    float* __restrict__ partU)                // [6][2359296]
{
    __shared__ ushort lA[128 * 72];
    __shared__ ushort lB[128 * 72];
    const int tid  = threadIdx.x;
    const int chunk = blockIdx.x / 144;
    const int tile  = blockIdx.x % 144;
    const int bm   = tile & 1;
    const int bn   = tile >> 1;
    const int wave = tid >> 6, lane = tid & 63;
    const int wm   = wave & 1, wn = wave >> 1;
    const int lane15 = lane & 15, quad = lane >> 4;
    const int srow = tid & 127, shalf = tid >> 7;

    int n  = bn * 128 + srow;
    int cb = n / 36, cs = n % 36;
    int cy = cs / 6, cx = cs % 6;
    const __hip_bfloat16* Bbase = P2t + ((cb * 20 + 2 * cy) * 20 + 2 * cx) * 128;
    const __hip_bfloat16* Abase = Awt + (bm * 128 + srow) * 10368;
    ushort* lAw = &lA[srow * 72 + shalf * 32];
    ushort* lBw = &lB[srow * 72 + shalf * 32];
    const ushort* aRd = &lA[(wm * 64 + lane15) * 72 + quad * 8];
    const ushort* bRd = &lB[(wn * 64 + lane15) * 72 + quad * 8];

    f32x4 zero = {0.f, 0.f, 0.f, 0.f};
    f32x4 acc[4][4];
    #pragma unroll
    for (int i = 0; i < 4; i++)
        #pragma unroll
        for (int j = 0; j < 4; j++) acc[i][j] = zero;

    const int kb0 = chunk * 27;
    for (int ki = 0; ki < 27; ki++) {
        int kb = kb0 + ki;
        int k81 = kb >> 1;
        int ky = k81 / 9, kx = k81 - ky * 9;
        int goffA = kb * 64 + shalf * 32;
        int goffB = (ky * 20 + kx) * 128 + (kb & 1) * 64 + shalf * 32;

        const uint4* ga = (const uint4*)(Abase + goffA);
        const uint4* gb = (const uint4*)(Bbase + goffB);
        uint4 av0 = ga[0], av1 = ga[1], av2 = ga[2], av3 = ga[3];
        uint4 bv0 = gb[0], bv1 = gb[1], bv2 = gb[2], bv3 = gb[3];

        __syncthreads();
        ((uint4*)lAw)[0] = av0; ((uint4*)lAw)[1] = av1;
        ((uint4*)lAw)[2] = av2; ((uint4*)lAw)[3] = av3;
        ((uint4*)lBw)[0] = bv0; ((uint4*)lBw)[1] = bv1;
        ((uint4*)lBw)[2] = bv2; ((uint4*)lBw)[3] = bv3;
        __syncthreads();

        #pragma unroll
        for (int kk = 0; kk < 2; kk++) {
            bf16x8 af[4], bf[4];
            #pragma unroll
            for (int tm = 0; tm < 4; tm++)
                af[tm] = *(const bf16x8*)(aRd + tm * 16 * 72 + kk * 32);
            #pragma unroll
            for (int tn = 0; tn < 4; tn++)
                bf[tn] = *(const bf16x8*)(bRd + tn * 16 * 72 + kk * 32);
            #pragma unroll
            for (int tm = 0; tm < 4; tm++)
                #pragma unroll
                for (int tn = 0; tn < 4; tn++)
                    acc[tm][tn] = __builtin_amdgcn_mfma_f32_16x16x32_bf16(
                        af[tm], bf[tn], acc[tm][tn], 0, 0, 0);
        }
    }

    float* base = partU + chunk * 2359296;
    #pragma unroll
    for (int tm = 0; tm < 4; tm++) {
        int m0 = bm * 128 + wm * 64 + tm * 16 + quad * 4;
        #pragma unroll
        for (int tn = 0; tn < 4; tn++) {
            int nn = bn * 128 + wn * 64 + tn * 16 + lane15;
            int ob = nn / 36, os = nn % 36;
            float* up = base + ob * 9216 + os;
            f32x4 a = acc[tm][tn];
            #pragma unroll
            for (int r = 0; r < 4; r++)
                up[(m0 + r) * 36] = a[r];
        }
    }
}

// ---------------- reduce 6 partials + bias + squash -> u_bf [b][k] bf16 ----------
__global__ __launch_bounds__(256) void k_reduce_squash(
    const float* __restrict__ partU, const float* __restrict__ pb,
    ushort* __restrict__ u_bf)
{
    int t = blockIdx.x * 256 + threadIdx.x;              // 294912 threads
    float4 a = {0.f, 0.f, 0.f, 0.f}, b4 = {0.f, 0.f, 0.f, 0.f};
    #pragma unroll
    for (int p = 0; p < 6; p++) {
        const float4* pp = (const float4*)(partU + p * 2359296 + t * 8);
        float4 x = pp[0], y = pp[1];
        a.x += x.x; a.y += x.y; a.z += x.z; a.w += x.w;
        b4.x += y.x; b4.y += y.y; b4.z += y.z; b4.w += y.w;
    }
    int lb = (t % 1152) * 8;
    int oc0 = lb / 36, s0 = lb - oc0 * 36;
    float vals[8] = {a.x, a.y, a.z, a.w, b4.x, b4.y, b4.z, b4.w};
    float sn = 0.f;
    #pragma unroll
    for (int e = 0; e < 8; e++) {
        int oc = oc0 + ((s0 + e) >= 36 ? 1 : 0);
        vals[e] += pb[oc];
        sn += vals[e] * vals[e];
    }
    float sc = sqrtf(sn) / (1.f + sn);
    u16x8 o8;
    #pragma unroll
    for (int e = 0; e < 8; e++) o8[e] = f2bf(vals[e] * sc);
    *(u16x8*)(u_bf + (size_t)t * 8) = o8;
}

// ---------------- s_j with inline softmax ----------------
__global__ __launch_bounds__(320) void k_sj_fused(
    const ushort* __restrict__ u_bf,          // [256][9216] bf16
    const __hip_bfloat16* __restrict__ Wt,    // [9216][160] bf16
    const float* __restrict__ expb,           // [1152][10]
    float* __restrict__ partS,                // [16][256*160]
    int iter)
{
    __shared__ ushort ush[8 * 1152];
    __shared__ float cf[1440];
    __shared__ float sred[320];
    __shared__ float sinv[10];
    const int tid = threadIdx.x;
    const int bt = blockIdx.x & 31, kc = blockIdx.x >> 5;
    const int co = tid % 160, half = tid / 160;

    if (iter > 0) {
        int c = tid % 10, g = tid / 10;                  // 10 x 32 partition
        float s = 0.f;
        for (int r = g; r < 1152; r += 32) s += expb[r * 10 + c];
        sred[tid] = s;
        for (int i = tid; i < 1440; i += 320) cf[i] = expb[kc * 1440 + i];
        __syncthreads();
        if (tid < 10) {
            float t2 = 0.f;
            #pragma unroll
            for (int gg = 0; gg < 32; gg++) t2 += sred[tid + gg * 10];
            sinv[tid] = 1.f / t2;
        }
    }
    for (int i = tid; i < 1152; i += 320)     // 8 b x 144 uint4
        ((uint4*)ush)[i] = ((const uint4*)u_bf)[(size_t)(bt * 8 + (i / 144)) * 1152
                                                + kc * 144 + (i % 144)];
    __syncthreads();

    const int cc = co >> 4;
    const float scl = (iter > 0) ? sinv[cc] : 0.f;
    const float cuni = 1.f / 1152.f;
    const ushort* wp = (const ushort*)Wt + ((size_t)kc * 1152 + half * 576) * 160 + co;

    float acc[8] = {0.f, 0.f, 0.f, 0.f, 0.f, 0.f, 0.f, 0.f};
    for (int rr = 0; rr < 72; rr++) {
        float cl = (iter == 0) ? cuni : cf[(half * 72 + rr) * 10 + cc] * scl;
        float wv[8];
        #pragma unroll
        for (int ii = 0; ii < 8; ii++)
            wv[ii] = b2f(wp[(rr * 8 + ii) * 160]) * cl;
        int kbase = half * 576 + rr * 8;
        #pragma unroll
        for (int bb = 0; bb < 8; bb++) {
            u16x8 uq = *(const u16x8*)&ush[bb * 1152 + kbase];
            #pragma unroll
            for (int ii = 0; ii < 8; ii++)
                acc[bb] += wv[ii] * b2f(uq[ii]);
        }
    }
    float* ps = partS + (kc * 2 + half) * 40960;
    #pragma unroll
    for (int bb = 0; bb < 8; bb++)
        ps[(bt * 8 + bb) * 160 + co] = acc[bb];
}

// ---------------- v = squash(sum partS); final iter also runs classifiers -------
__global__ __launch_bounds__(320) void k_vj_cls(
    const float* __restrict__ partS, float* __restrict__ v,
    const float* __restrict__ w1, const float* __restrict__ b1,
    const float* __restrict__ w2, const float* __restrict__ b2,
    float* __restrict__ out, int write_out)
{
    const int b = blockIdx.x;
    const int tid = threadIdx.x;
    __shared__ float feat[160];
    if (tid < 160) {
        float s = 0.f;
        #pragma unroll
        for (int p = 0; p < 16; p++) s += partS[p * 40960 + b * 160 + tid];
        float vv = s * fabsf(s) / (1.f + s * s);
        v[b * 160 + tid] = vv;
        feat[tid] = vv;
        if (write_out) out[b * 160 + tid] = vv;
    }
    if (!write_out) return;
    __syncthreads();
    int k = tid >> 5, j = tid & 31;                      // 10 classifiers x 32 lanes
    float acc = 0.f;
    for (int h = j; h < 100; h += 32) {
        float a = b1[k * 100 + h];
        for (int f = 0; f < 160; f++) a += feat[f] * w1[(k * 160 + f) * 100 + h];
        acc += fmaxf(a, 0.f) * w2[k * 100 + h];
    }
    #pragma unroll
    for (int d = 16; d > 0; d >>= 1) acc += __shfl_xor(acc, d);
    if (j == 0)
        out[40960 + b * 10 + k] = 1.f / (1.f + expf(-(acc + b2[k])));
}

// ---------------- M rows for route r + a_ij + bij update + expb -----------------
__global__ __launch_bounds__(320) void k_mmat_aij(
    const ushort* __restrict__ u_bf, const float* __restrict__ v,
    const float* __restrict__ W, float* __restrict__ bij,
    float* __restrict__ expb)
{
    const int r = blockIdx.x;
    const int tid = threadIdx.x;
    const int co = tid % 160, bh = tid / 160;
    float acc[8] = {0.f, 0.f, 0.f, 0.f, 0.f, 0.f, 0.f, 0.f};
    for (int b = bh; b < 256; b += 2) {
        float vv = v[b * 160 + co];
        u16x8 uq = *(const u16x8*)(u_bf + (size_t)b * 9216 + r * 8);
        #pragma unroll
        for (int j = 0; j < 8; j++) acc[j] += vv * b2f(uq[j]);
    }
    __shared__ float red[2560];               // [j][bh][co]
    __shared__ float Ml[8][160];
    #pragma unroll
    for (int j = 0; j < 8; j++) red[j * 320 + bh * 160 + co] = acc[j];
    __syncthreads();
    if (tid < 160) {
        #pragma unroll
        for (int j = 0; j < 8; j++)
            Ml[j][tid] = (red[j * 320 + tid] + red[j * 320 + 160 + tid]) * (1.f / 256.f);
    }
    __syncthreads();
    int c = tid >> 5, j32 = tid & 31;                    // 10 c x 32 lanes
    const float* wr = W + ((size_t)r * 10 + c) * 128;    // W[r][c][o][i] flat
    float a2 = 0.f;
    #pragma unroll
    for (int m = 0; m < 4; m++) {
        int idx = j32 + m * 32;                          // = o*8 + i
        int o = idx >> 3, i = idx & 7;
        a2 += wr[idx] * Ml[i][c * 16 + o];
    }
    #pragma unroll
    for (int d = 16; d > 0; d >>= 1) a2 += __shfl_xor(a2, d);
    if (j32 == 0) {
        float nb = bij[c * 1152 + r] + a2;
        bij[c * 1152 + r] = nb;
        expb[r * 10 + c] = expf(nb);
    }
}

extern "C" void kernel_launch(void* const* d_in, const int* in_sizes, int n_in,
                              void* d_out, int out_size, void* d_ws, size_t ws_size,
                              hipStream_t stream) {
    const float* data    = (const float*)d_in[0];
    const float* conv1_w = (const float*)d_in[1];
    const float* conv1_b = (const float*)d_in[2];
    const float* conv2_w = (const float*)d_in[3];
    const float* conv2_b = (const float*)d_in[4];
    const float* prim_w  = (const float*)d_in[5];
    const float* prim_b  = (const float*)d_in[6];
    const float* W       = (const float*)d_in[7];
    const float* cls_w1  = (const float*)d_in[8];
    const float* cls_b1  = (const float*)d_in[9];
    const float* cls_w2  = (const float*)d_in[10];
    const float* cls_b2  = (const float*)d_in[11];
    float* out = (float*)d_out;

    char* ws = (char*)d_ws;
    // ws+0 (94.6 MB): Q (conv2 out) -> partU (56.6 MB split-K partials).
    // ws+94,633,984 (47.3 MB): P1t -> P2t. Both sequential-lifetime reuses.
    __hip_bfloat16* Q     = (__hip_bfloat16*)(ws + 0);
    float*          partU = (float*)(ws + 0);
    __hip_bfloat16* P1t   = (__hip_bfloat16*)(ws + 94633984);
    __hip_bfloat16* P2t   = (__hip_bfloat16*)(ws + 94633984);
    __hip_bfloat16* Awt   = (__hip_bfloat16*)(ws + 141950976);  //  5,308,416
    __hip_bfloat16* Wt    = (__hip_bfloat16*)(ws + 147259392);  //  2,949,120
    ushort*         u_bf  = (ushort*)(ws + 150208512);          //  4,718,592
    float*          partS = (float*)(ws + 154927104);           //  2,621,440
    float*          v     = (float*)(ws + 163446784);           //    163,840
    float*          bij   = (float*)(ws + 163610624);           //     46,080
    float*          expb  = (float*)(ws + 163656704);           //     46,080
    __hip_bfloat16* Aw2   = (__hip_bfloat16*)(ws + 163702784);  //    147,456
    __hip_bfloat16* Aw1   = (__hip_bfloat16*)(ws + 163850240);  //      4,096
    // total: 163,854,336 bytes

    hipMemsetAsync(bij, 0, 11520 * sizeof(float), stream);

    k_prep_all<<<16424, 256, 0, stream>>>(conv1_w, conv2_w, prim_w, W,
                                          Aw1, Aw2, Awt, Wt);
    k_conv1_mfma<<<9728, 256, 0, stream>>>(data, Aw1, conv1_b, P1t);
    k_conv2_mfma<<<1444, 512, 0, stream>>>(P1t, Aw2, conv2_b, Q);
    k_pool2t<<<51200, 256, 0, stream>>>(Q, P2t);
    k_primcaps_mfma<<<864, 256, 0, stream>>>(P2t, Awt, partU);
    k_reduce_squash<<<1152, 256, 0, stream>>>(partU, prim_b, u_bf);

    for (int it = 0; it < 3; it++) {
        k_sj_fused<<<256, 320, 0, stream>>>(u_bf, Wt, expb, partS, it);
        k_vj_cls<<<256, 320, 0, stream>>>(partS, v, cls_w1, cls_b1, cls_w2,
                                          cls_b2, out, it == 2 ? 1 : 0);
        if (it < 2)
            k_mmat_aij<<<1152, 320, 0, stream>>>(u_bf, v, W, bij, expb);
    }
}

// Round 10
// 613.160 us; speedup vs baseline: 10.9525x; 1.0751x over previous
//
#include <hip/hip_runtime.h>
#include <hip/hip_bf16.h>

// CapsNet forward. Round 10: primcaps gets the conv2 recipe — N-tile 256,
// 512 threads, 2x4 waves, shared A staging, halved barrier-drains.
// (72 tiles x splitK6 = 432 blocks.) Rest byte-identical to round 9.
// B=256, R=1152, C=10, O=16, I=8

typedef __bf16 bf16x8 __attribute__((ext_vector_type(8)));
typedef float  f32x4  __attribute__((ext_vector_type(4)));
typedef ushort u16x8  __attribute__((ext_vector_type(8)));

static __device__ __forceinline__ ushort f2bf(float f) {
    __hip_bfloat16 h = __float2bfloat16(f);
    return *(ushort*)&h;
}
static __device__ __forceinline__ float b2f(ushort u) {
    return __uint_as_float(((unsigned)u) << 16);
}

// ---------------- fused weight prep: Awt | Wt | Aw2 | Aw1 ------------------------
__global__ __launch_bounds__(256) void k_prep_all(
    const float* __restrict__ w1, const float* __restrict__ w2,
    const float* __restrict__ pw, const float* __restrict__ W,
    __hip_bfloat16* __restrict__ Aw1, __hip_bfloat16* __restrict__ Aw2,
    __hip_bfloat16* __restrict__ Awt, __hip_bfloat16* __restrict__ Wt)
{
    int t = blockIdx.x * 256 + threadIdx.x;              // 4,204,544 threads
    if (t < 2654208) {
        int oc = t / 10368, rem = t % 10368;
        int k81 = rem >> 7, ic = rem & 127;
        Awt[t] = __float2bfloat16(pw[(oc * 128 + ic) * 81 + k81]);
    } else if (t < 4128768) {
        int q = t - 2654208;
        int k = q / 160, co = q % 160;
        int r = k >> 3, i = k & 7, c = co >> 4, o = co & 15;
        Wt[q] = __float2bfloat16(W[(((size_t)r * 10 + c) * 16 + o) * 8 + i]);
    } else if (t < 4202496) {
        int q = t - 4128768;
        int oc = q / 576, rem = q % 576;
        int k9 = rem >> 6, ic = rem & 63;
        Aw2[q] = __float2bfloat16(w2[(oc * 64 + ic) * 9 + k9]);
    } else {
        int q = t - 4202496;
        int oc = q >> 5, k = q & 31;
        Aw1[q] = __float2bfloat16(k < 27 ? w1[oc * 27 + k] : 0.f);
    }
}

// ---------------- conv1(3->64,3x3,s1,p0) + relu + maxpool(2,2,p1) via MFMA -------
__global__ __launch_bounds__(256) void k_conv1_mfma(
    const float* __restrict__ data, const __hip_bfloat16* __restrict__ Aw1,
    const float* __restrict__ b1, __hip_bfloat16* __restrict__ P1t)
{
    __shared__ float tile[960];          // [ic]*312 + [rloc]*78 + [lc]; lc = x_in+1
    const int tid = threadIdx.x;
    const int py = blockIdx.x % 38, b = blockIdx.x / 38;

    #pragma unroll
    for (int c = 0; c < 4; c++) {
        int idx = tid + c * 256;
        if (idx < 960) {
            float val = 0.f;
            if (idx < 936) {
                int ic = idx / 312, rem = idx % 312;
                int rl = rem / 78, lc = rem % 78;
                int ri = 2 * py - 1 + rl, xi = lc - 1;
                if ((unsigned)ri < 76u && (unsigned)xi < 76u)
                    val = data[(b * 3 + ic) * 5776 + ri * 76 + xi];
            }
            tile[idx] = val;
        }
    }

    const int wave = tid >> 6, lane = tid & 63;
    const int l15 = lane & 15, quad = lane >> 4;

    bf16x8 af = *(const bf16x8*)((const ushort*)Aw1 + (wave * 16 + l15) * 32 + quad * 8);

    int koff[8]; bool kok[8];
    #pragma unroll
    for (int j = 0; j < 8; j++) {
        int kk = quad * 8 + j;
        kok[j] = kk < 27;
        int ic = kk / 9, rem = kk - ic * 9, ky = rem / 3, kx = rem - ky * 3;
        koff[j] = kok[j] ? (ic * 312 + ky * 78 + kx) : 0;
    }

    float bias[4];
    #pragma unroll
    for (int r = 0; r < 4; r++) bias[r] = b1[wave * 16 + quad * 4 + r];

    const bool valid0 = (py > 0);
    const bool valid1 = (py < 37);

    __syncthreads();

    #pragma unroll
    for (int t5 = 0; t5 < 5; t5++) {
        int n_x = t5 * 16 + l15;                         // conv x = n_x - 1
        bool col_ok = (unsigned)(n_x - 1) < 74u;

        bf16x8 bf0, bf1;
        #pragma unroll
        for (int j = 0; j < 8; j++) {
            float v0 = tile[koff[j] + n_x];
            float v1 = tile[koff[j] + 78 + n_x];
            bool ok = col_ok && kok[j];
            bf0[j] = (__bf16)(ok ? v0 : 0.f);
            bf1[j] = (__bf16)(ok ? v1 : 0.f);
        }
        f32x4 z = {0.f, 0.f, 0.f, 0.f};
        f32x4 c0 = __builtin_amdgcn_mfma_f32_16x16x32_bf16(af, bf0, z, 0, 0, 0);
        f32x4 c1 = __builtin_amdgcn_mfma_f32_16x16x32_bf16(af, bf1, z, 0, 0, 0);

        f32x4 p;
        #pragma unroll
        for (int r = 0; r < 4; r++) {
            float r0 = (valid0 && col_ok) ? fmaxf(c0[r] + bias[r], 0.f) : 0.f;
            float r1 = (valid1 && col_ok) ? fmaxf(c1[r] + bias[r], 0.f) : 0.f;
            p[r] = fmaxf(r0, r1);
        }
        #pragma unroll
        for (int r = 0; r < 4; r++)
            p[r] = fmaxf(p[r], __shfl_xor(p[r], 1));

        if (!(l15 & 1)) {
            int px = t5 * 8 + (l15 >> 1);
            if (px < 38) {
                ushort4 pk;
                pk.x = f2bf(p[0]); pk.y = f2bf(p[1]);
                pk.z = f2bf(p[2]); pk.w = f2bf(p[3]);
                *(ushort4*)((ushort*)P1t + ((size_t)(b * 38 + py) * 38 + px) * 64
                            + wave * 16 + quad * 4) = pk;
            }
        }
    }
}

// ---------------- conv2 as MFMA GEMM + bias + relu, N=256 tile ------------------
__global__ __launch_bounds__(512) void k_conv2_mfma(
    const __hip_bfloat16* __restrict__ P1t,   // [256][38][38][64]
    const __hip_bfloat16* __restrict__ Aw2,   // [128][576]
    const float* __restrict__ cb,             // [128]
    __hip_bfloat16* __restrict__ Q)
{
    __shared__ ushort lA[128 * 72];           // 18,432 B
    __shared__ ushort lB[256 * 72];           // 36,864 B
    const int tid  = threadIdx.x;
    const int bn   = blockIdx.x;              // 1444 N-blocks
    const int wave = tid >> 6, lane = tid & 63;
    const int wm   = wave & 1, wn = wave >> 1;      // 2 x 4 waves
    const int lane15 = lane & 15, quad = lane >> 4;

    const int arow = tid >> 2, apart = tid & 3;
    const int brow = tid >> 1, bpart = tid & 1;

    int n = bn * 256 + brow;
    int b = n / 1444, yx = n % 1444;
    int y = yx / 38, x = yx % 38;

    const __hip_bfloat16* Abase = Aw2 + arow * 576;
    ushort* lAw = &lA[arow * 72 + apart * 16];
    ushort* lBw = &lB[brow * 72 + bpart * 32];
    const ushort* aRd = &lA[(wm * 64 + lane15) * 72 + quad * 8];
    const ushort* bRd = &lB[(wn * 64 + lane15) * 72 + quad * 8];

    f32x4 zero = {0.f, 0.f, 0.f, 0.f};
    f32x4 acc[4][4];
    #pragma unroll
    for (int i = 0; i < 4; i++)
        #pragma unroll
        for (int j = 0; j < 4; j++) acc[i][j] = zero;

    for (int kb = 0; kb < 9; kb++) {                      // tap (ky,kx), 64 ic each
        int ky = kb / 3, kx = kb - ky * 3;
        int iy = y + ky - 1, ix = x + kx - 1;
        bool ok = ((unsigned)iy < 38u) && ((unsigned)ix < 38u);

        const uint4* ga = (const uint4*)(Abase + kb * 64 + apart * 16);
        uint4 av0 = ga[0], av1 = ga[1];
        uint4 z4 = {0u, 0u, 0u, 0u};
        uint4 bv0 = z4, bv1 = z4, bv2 = z4, bv3 = z4;
        if (ok) {
            const uint4* gb = (const uint4*)(P1t + (((b * 38 + iy) * 38 + ix) << 6) + bpart * 32);
            bv0 = gb[0]; bv1 = gb[1]; bv2 = gb[2]; bv3 = gb[3];
        }

        __syncthreads();
        ((uint4*)lAw)[0] = av0; ((uint4*)lAw)[1] = av1;
        ((uint4*)lBw)[0] = bv0; ((uint4*)lBw)[1] = bv1;
        ((uint4*)lBw)[2] = bv2; ((uint4*)lBw)[3] = bv3;
        __syncthreads();

        #pragma unroll
        for (int kk = 0; kk < 2; kk++) {
            bf16x8 af[4], bf[4];
            #pragma unroll
            for (int tm = 0; tm < 4; tm++)
                af[tm] = *(const bf16x8*)(aRd + tm * 16 * 72 + kk * 32);
            #pragma unroll
            for (int tn = 0; tn < 4; tn++)
                bf[tn] = *(const bf16x8*)(bRd + tn * 16 * 72 + kk * 32);
            #pragma unroll
            for (int tm = 0; tm < 4; tm++)
                #pragma unroll
                for (int tn = 0; tn < 4; tn++)
                    acc[tm][tn] = __builtin_amdgcn_mfma_f32_16x16x32_bf16(
                        af[tm], bf[tn], acc[tm][tn], 0, 0, 0);
        }
    }

    #pragma unroll
    for (int tm = 0; tm < 4; tm++) {
        int m0 = wm * 64 + tm * 16 + quad * 4;
        float b0 = cb[m0], b1 = cb[m0 + 1], b2 = cb[m0 + 2], b3 = cb[m0 + 3];
        #pragma unroll
        for (int tn = 0; tn < 4; tn++) {
            int nn = bn * 256 + wn * 64 + tn * 16 + lane15;
            f32x4 a = acc[tm][tn];
            ushort4 pk;
            pk.x = f2bf(fmaxf(a[0] + b0, 0.f));
            pk.y = f2bf(fmaxf(a[1] + b1, 0.f));
            pk.z = f2bf(fmaxf(a[2] + b2, 0.f));
            pk.w = f2bf(fmaxf(a[3] + b3, 0.f));
            *(ushort4*)((ushort*)Q + (size_t)nn * 128 + m0) = pk;
        }
    }
}

// ---------------- maxpool(2,2,p1) over Q -> P2t [256][20][20][128] ----------------
__global__ __launch_bounds__(256) void k_pool2t(
    const __hip_bfloat16* __restrict__ Q, __hip_bfloat16* __restrict__ P2t)
{
    int t = blockIdx.x * 256 + threadIdx.x;              // 256*400*128 threads
    int ic = t & 127, rest = t >> 7;
    int px = rest % 20, py = (rest / 20) % 20, b = rest / 400;
    float m = 0.f;
    #pragma unroll
    for (int dy = 0; dy < 2; dy++) {
        int y = 2 * py - 1 + dy;
        if ((unsigned)y >= 38u) continue;
        #pragma unroll
        for (int dx = 0; dx < 2; dx++) {
            int x = 2 * px - 1 + dx;
            if ((unsigned)x >= 38u) continue;
            m = fmaxf(m, __bfloat162float(Q[(((b * 38 + y) * 38 + x) << 7) + ic]));
        }
    }
    P2t[t] = __float2bfloat16(m);
}

// ---------------- primcaps split-K MFMA GEMM, N=256 tile -> 6 fp32 partials ------
// M=256 (bm: 2 tiles of 128), N=9216 (bn: 36 tiles of 256), K: 6 chunks x 27 kb.
// 432 blocks of 512 threads, 2x4 waves. A staged once per kb (shared by 4 wn).
// Per-chunk K-order identical to round 9 -> bit-identical partU.
__global__ __launch_bounds__(512) void k_primcaps_mfma(
    const __hip_bfloat16* __restrict__ P2t,   // [256][20][20][128]
    const __hip_bfloat16* __restrict__ Awt,   // [256][10368]
    float* __restrict__ partU)                // [6][2359296]
{
    __shared__ ushort lA[128 * 72];           // 18,432 B
    __shared__ ushort lB[256 * 72];           // 36,864 B
    const int tid  = threadIdx.x;
    const int chunk = blockIdx.x / 72;
    const int tile  = blockIdx.x % 72;
    const int bm   = tile & 1;
    const int bn   = tile >> 1;               // 0..35
    const int wave = tid >> 6, lane = tid & 63;
    const int wm   = wave & 1, wn = wave >> 1;
    const int lane15 = lane & 15, quad = lane >> 4;

    const int arow = tid >> 2, apart = tid & 3;
    const int brow = tid >> 1, bpart = tid & 1;

    int n  = bn * 256 + brow;
    int cb = n / 36, cs = n % 36;
    int cy = cs / 6, cx = cs % 6;
    const __hip_bfloat16* Bbase = P2t + ((cb * 20 + 2 * cy) * 20 + 2 * cx) * 128;
    const __hip_bfloat16* Abase = Awt + (bm * 128 + arow) * 10368;
    ushort* lAw = &lA[arow * 72 + apart * 16];
    ushort* lBw = &lB[brow * 72 + bpart * 32];
    const ushort* aRd = &lA[(wm * 64 + lane15) * 72 + quad * 8];
    const ushort* bRd = &lB[(wn * 64 + lane15) * 72 + quad * 8];

    f32x4 zero = {0.f, 0.f, 0.f, 0.f};
    f32x4 acc[4][4];
    #pragma unroll
    for (int i = 0; i < 4; i++)
        #pragma unroll
        for (int j = 0; j < 4; j++) acc[i][j] = zero;

    const int kb0 = chunk * 27;
    for (int ki = 0; ki < 27; ki++) {
        int kb = kb0 + ki;
        int k81 = kb >> 1;
        int ky = k81 / 9, kx = k81 - ky * 9;
        int goffA = kb * 64 + apart * 16;
        int goffB = (ky * 20 + kx) * 128 + (kb & 1) * 64 + bpart * 32;

        const uint4* ga = (const uint4*)(Abase + goffA);
        const uint4* gb = (const uint4*)(Bbase + goffB);
        uint4 av0 = ga[0], av1 = ga[1];
        uint4 bv0 = gb[0], bv1 = gb[1], bv2 = gb[2], bv3 = gb[3];

        __syncthreads();
        ((uint4*)lAw)[0] = av0; ((uint4*)lAw)[1] = av1;
        ((uint4*)lBw)[0] = bv0; ((uint4*)lBw)[1] = bv1;
        ((uint4*)lBw)[2] = bv2; ((uint4*)lBw)[3] = bv3;
        __syncthreads();

        #pragma unroll
        for (int kk = 0; kk < 2; kk++) {
            bf16x8 af[4], bf[4];
            #pragma unroll
            for (int tm = 0; tm < 4; tm++)
                af[tm] = *(const bf16x8*)(aRd + tm * 16 * 72 + kk * 32);
            #pragma unroll
            for (int tn = 0; tn < 4; tn++)
                bf[tn] = *(const bf16x8*)(bRd + tn * 16 * 72 + kk * 32);
            #pragma unroll
            for (int tm = 0; tm < 4; tm++)
                #pragma unroll
                for (int tn = 0; tn < 4; tn++)
                    acc[tm][tn] = __builtin_amdgcn_mfma_f32_16x16x32_bf16(
                        af[tm], bf[tn], acc[tm][tn], 0, 0, 0);
        }
    }

    float* base = partU + chunk * 2359296;
    #pragma unroll
    for (int tm = 0; tm < 4; tm++) {
        int m0 = bm * 128 + wm * 64 + tm * 16 + quad * 4;
        #pragma unroll
        for (int tn = 0; tn < 4; tn++) {
            int nn = bn * 256 + wn * 64 + tn * 16 + lane15;
            int ob = nn / 36, os = nn % 36;
            float* up = base + ob * 9216 + os;
            f32x4 a = acc[tm][tn];
            #pragma unroll
            for (int r = 0; r < 4; r++)
                up[(m0 + r) * 36] = a[r];
        }
    }
}

// ---------------- reduce 6 partials + bias + squash -> u_bf [b][k] bf16 ----------
__global__ __launch_bounds__(256) void k_reduce_squash(
    const float* __restrict__ partU, const float* __restrict__ pb,
    ushort* __restrict__ u_bf)
{
    int t = blockIdx.x * 256 + threadIdx.x;              // 294912 threads
    float4 a = {0.f, 0.f, 0.f, 0.f}, b4 = {0.f, 0.f, 0.f, 0.f};
    #pragma unroll
    for (int p = 0; p < 6; p++) {
        const float4* pp = (const float4*)(partU + p * 2359296 + t * 8);
        float4 x = pp[0], y = pp[1];
        a.x += x.x; a.y += x.y; a.z += x.z; a.w += x.w;
        b4.x += y.x; b4.y += y.y; b4.z += y.z; b4.w += y.w;
    }
    int lb = (t % 1152) * 8;
    int oc0 = lb / 36, s0 = lb - oc0 * 36;
    float vals[8] = {a.x, a.y, a.z, a.w, b4.x, b4.y, b4.z, b4.w};
    float sn = 0.f;
    #pragma unroll
    for (int e = 0; e < 8; e++) {
        int oc = oc0 + ((s0 + e) >= 36 ? 1 : 0);
        vals[e] += pb[oc];
        sn += vals[e] * vals[e];
    }
    float sc = sqrtf(sn) / (1.f + sn);
    u16x8 o8;
    #pragma unroll
    for (int e = 0; e < 8; e++) o8[e] = f2bf(vals[e] * sc);
    *(u16x8*)(u_bf + (size_t)t * 8) = o8;
}

// ---------------- s_j with inline softmax ----------------
__global__ __launch_bounds__(320) void k_sj_fused(
    const ushort* __restrict__ u_bf,          // [256][9216] bf16
    const __hip_bfloat16* __restrict__ Wt,    // [9216][160] bf16
    const float* __restrict__ expb,           // [1152][10]
    float* __restrict__ partS,                // [16][256*160]
    int iter)
{
    __shared__ ushort ush[8 * 1152];
    __shared__ float cf[1440];
    __shared__ float sred[320];
    __shared__ float sinv[10];
    const int tid = threadIdx.x;
    const int bt = blockIdx.x & 31, kc = blockIdx.x >> 5;
    const int co = tid % 160, half = tid / 160;

    if (iter > 0) {
        int c = tid % 10, g = tid / 10;                  // 10 x 32 partition
        float s = 0.f;
        for (int r = g; r < 1152; r += 32) s += expb[r * 10 + c];
        sred[tid] = s;
        for (int i = tid; i < 1440; i += 320) cf[i] = expb[kc * 1440 + i];
        __syncthreads();
        if (tid < 10) {
            float t2 = 0.f;
            #pragma unroll
            for (int gg = 0; gg < 32; gg++) t2 += sred[tid + gg * 10];
            sinv[tid] = 1.f / t2;
        }
    }
    for (int i = tid; i < 1152; i += 320)     // 8 b x 144 uint4
        ((uint4*)ush)[i] = ((const uint4*)u_bf)[(size_t)(bt * 8 + (i / 144)) * 1152
                                                + kc * 144 + (i % 144)];
    __syncthreads();

    const int cc = co >> 4;
    const float scl = (iter > 0) ? sinv[cc] : 0.f;
    const float cuni = 1.f / 1152.f;
    const ushort* wp = (const ushort*)Wt + ((size_t)kc * 1152 + half * 576) * 160 + co;

    float acc[8] = {0.f, 0.f, 0.f, 0.f, 0.f, 0.f, 0.f, 0.f};
    for (int rr = 0; rr < 72; rr++) {
        float cl = (iter == 0) ? cuni : cf[(half * 72 + rr) * 10 + cc] * scl;
        float wv[8];
        #pragma unroll
        for (int ii = 0; ii < 8; ii++)
            wv[ii] = b2f(wp[(rr * 8 + ii) * 160]) * cl;
        int kbase = half * 576 + rr * 8;
        #pragma unroll
        for (int bb = 0; bb < 8; bb++) {
            u16x8 uq = *(const u16x8*)&ush[bb * 1152 + kbase];
            #pragma unroll
            for (int ii = 0; ii < 8; ii++)
                acc[bb] += wv[ii] * b2f(uq[ii]);
        }
    }
    float* ps = partS + (kc * 2 + half) * 40960;
    #pragma unroll
    for (int bb = 0; bb < 8; bb++)
        ps[(bt * 8 + bb) * 160 + co] = acc[bb];
}

// ---------------- v = squash(sum partS); final iter also runs classifiers -------
__global__ __launch_bounds__(320) void k_vj_cls(
    const float* __restrict__ partS, float* __restrict__ v,
    const float* __restrict__ w1, const float* __restrict__ b1,
    const float* __restrict__ w2, const float* __restrict__ b2,
    float* __restrict__ out, int write_out)
{
    const int b = blockIdx.x;
    const int tid = threadIdx.x;
    __shared__ float feat[160];
    if (tid < 160) {
        float s = 0.f;
        #pragma unroll
        for (int p = 0; p < 16; p++) s += partS[p * 40960 + b * 160 + tid];
        float vv = s * fabsf(s) / (1.f + s * s);
        v[b * 160 + tid] = vv;
        feat[tid] = vv;
        if (write_out) out[b * 160 + tid] = vv;
    }
    if (!write_out) return;
    __syncthreads();
    int k = tid >> 5, j = tid & 31;                      // 10 classifiers x 32 lanes
    float acc = 0.f;
    for (int h = j; h < 100; h += 32) {
        float a = b1[k * 100 + h];
        for (int f = 0; f < 160; f++) a += feat[f] * w1[(k * 160 + f) * 100 + h];
        acc += fmaxf(a, 0.f) * w2[k * 100 + h];
    }
    #pragma unroll
    for (int d = 16; d > 0; d >>= 1) acc += __shfl_xor(acc, d);
    if (j == 0)
        out[40960 + b * 10 + k] = 1.f / (1.f + expf(-(acc + b2[k])));
}

// ---------------- M rows for route r + a_ij + bij update + expb -----------------
__global__ __launch_bounds__(320) void k_mmat_aij(
    const ushort* __restrict__ u_bf, const float* __restrict__ v,
    const float* __restrict__ W, float* __restrict__ bij,
    float* __restrict__ expb)
{
    const int r = blockIdx.x;
    const int tid = threadIdx.x;
    const int co = tid % 160, bh = tid / 160;
    float acc[8] = {0.f, 0.f, 0.f, 0.f, 0.f, 0.f, 0.f, 0.f};
    for (int b = bh; b < 256; b += 2) {
        float vv = v[b * 160 + co];
        u16x8 uq = *(const u16x8*)(u_bf + (size_t)b * 9216 + r * 8);
        #pragma unroll
        for (int j = 0; j < 8; j++) acc[j] += vv * b2f(uq[j]);
    }
    __shared__ float red[2560];               // [j][bh][co]
    __shared__ float Ml[8][160];
    #pragma unroll
    for (int j = 0; j < 8; j++) red[j * 320 + bh * 160 + co] = acc[j];
    __syncthreads();
    if (tid < 160) {
        #pragma unroll
        for (int j = 0; j < 8; j++)
            Ml[j][tid] = (red[j * 320 + tid] + red[j * 320 + 160 + tid]) * (1.f / 256.f);
    }
    __syncthreads();
    int c = tid >> 5, j32 = tid & 31;                    // 10 c x 32 lanes
    const float* wr = W + ((size_t)r * 10 + c) * 128;    // W[r][c][o][i] flat
    float a2 = 0.f;
    #pragma unroll
    for (int m = 0; m < 4; m++) {
        int idx = j32 + m * 32;                          // = o*8 + i
        int o = idx >> 3, i = idx & 7;
        a2 += wr[idx] * Ml[i][c * 16 + o];
    }
    #pragma unroll
    for (int d = 16; d > 0; d >>= 1) a2 += __shfl_xor(a2, d);
    if (j32 == 0) {
        float nb = bij[c * 1152 + r] + a2;
        bij[c * 1152 + r] = nb;
        expb[r * 10 + c] = expf(nb);
    }
}

extern "C" void kernel_launch(void* const* d_in, const int* in_sizes, int n_in,
                              void* d_out, int out_size, void* d_ws, size_t ws_size,
                              hipStream_t stream) {
    const float* data    = (const float*)d_in[0];
    const float* conv1_w = (const float*)d_in[1];
    const float* conv1_b = (const float*)d_in[2];
    const float* conv2_w = (const float*)d_in[3];
    const float* conv2_b = (const float*)d_in[4];
    const float* prim_w  = (const float*)d_in[5];
    const float* prim_b  = (const float*)d_in[6];
    const float* W       = (const float*)d_in[7];
    const float* cls_w1  = (const float*)d_in[8];
    const float* cls_b1  = (const float*)d_in[9];
    const float* cls_w2  = (const float*)d_in[10];
    const float* cls_b2  = (const float*)d_in[11];
    float* out = (float*)d_out;

    char* ws = (char*)d_ws;
    // ws+0 (94.6 MB): Q (conv2 out) -> partU (56.6 MB split-K partials).
    // ws+94,633,984 (47.3 MB): P1t -> P2t. Both sequential-lifetime reuses.
    __hip_bfloat16* Q     = (__hip_bfloat16*)(ws + 0);
    float*          partU = (float*)(ws + 0);
    __hip_bfloat16* P1t   = (__hip_bfloat16*)(ws + 94633984);
    __hip_bfloat16* P2t   = (__hip_bfloat16*)(ws + 94633984);
    __hip_bfloat16* Awt   = (__hip_bfloat16*)(ws + 141950976);  //  5,308,416
    __hip_bfloat16* Wt    = (__hip_bfloat16*)(ws + 147259392);  //  2,949,120
    ushort*         u_bf  = (ushort*)(ws + 150208512);          //  4,718,592
    float*          partS = (float*)(ws + 154927104);           //  2,621,440
    float*          v     = (float*)(ws + 163446784);           //    163,840
    float*          bij   = (float*)(ws + 163610624);           //     46,080
    float*          expb  = (float*)(ws + 163656704);           //     46,080
    __hip_bfloat16* Aw2   = (__hip_bfloat16*)(ws + 163702784);  //    147,456
    __hip_bfloat16* Aw1   = (__hip_bfloat16*)(ws + 163850240);  //      4,096
    // total: 163,854,336 bytes

    hipMemsetAsync(bij, 0, 11520 * sizeof(float), stream);

    k_prep_all<<<16424, 256, 0, stream>>>(conv1_w, conv2_w, prim_w, W,
                                          Aw1, Aw2, Awt, Wt);
    k_conv1_mfma<<<9728, 256, 0, stream>>>(data, Aw1, conv1_b, P1t);
    k_conv2_mfma<<<1444, 512, 0, stream>>>(P1t, Aw2, conv2_b, Q);
    k_pool2t<<<51200, 256, 0, stream>>>(Q, P2t);
    k_primcaps_mfma<<<432, 512, 0, stream>>>(P2t, Awt, partU);
    k_reduce_squash<<<1152, 256, 0, stream>>>(partU, prim_b, u_bf);

    for (int it = 0; it < 3; it++) {
        k_sj_fused<<<256, 320, 0, stream>>>(u_bf, Wt, expb, partS, it);
        k_vj_cls<<<256, 320, 0, stream>>>(partS, v, cls_w1, cls_b1, cls_w2,
                                          cls_b2, out, it == 2 ? 1 : 0);
        if (it < 2)
            k_mmat_aij<<<1152, 320, 0, stream>>>(u_bf, v, W, bij, expb);
    }
}

// Round 11
// 590.524 us; speedup vs baseline: 11.3724x; 1.0383x over previous
//
#include <hip/hip_runtime.h>
#include <hip/hip_bf16.h>

// CapsNet forward. Round 11: fused conv2+maxpool retry (clean-room, 512-thr,
// cell-quadrant N layout, Q tensor eliminated). bf16-round is monotone so
// P2t is bit-identical to the round-10 unfused path => absmax must stay
// exactly 9.155273e-5. Rest byte-identical to round 10.
// B=256, R=1152, C=10, O=16, I=8

typedef __bf16 bf16x8 __attribute__((ext_vector_type(8)));
typedef float  f32x4  __attribute__((ext_vector_type(4)));
typedef ushort u16x8  __attribute__((ext_vector_type(8)));

static __device__ __forceinline__ ushort f2bf(float f) {
    __hip_bfloat16 h = __float2bfloat16(f);
    return *(ushort*)&h;
}
static __device__ __forceinline__ float b2f(ushort u) {
    return __uint_as_float(((unsigned)u) << 16);
}

// ---------------- fused weight prep: Awt | Wt | Aw2 | Aw1 ------------------------
__global__ __launch_bounds__(256) void k_prep_all(
    const float* __restrict__ w1, const float* __restrict__ w2,
    const float* __restrict__ pw, const float* __restrict__ W,
    __hip_bfloat16* __restrict__ Aw1, __hip_bfloat16* __restrict__ Aw2,
    __hip_bfloat16* __restrict__ Awt, __hip_bfloat16* __restrict__ Wt)
{
    int t = blockIdx.x * 256 + threadIdx.x;              // 4,204,544 threads
    if (t < 2654208) {
        int oc = t / 10368, rem = t % 10368;
        int k81 = rem >> 7, ic = rem & 127;
        Awt[t] = __float2bfloat16(pw[(oc * 128 + ic) * 81 + k81]);
    } else if (t < 4128768) {
        int q = t - 2654208;
        int k = q / 160, co = q % 160;
        int r = k >> 3, i = k & 7, c = co >> 4, o = co & 15;
        Wt[q] = __float2bfloat16(W[(((size_t)r * 10 + c) * 16 + o) * 8 + i]);
    } else if (t < 4202496) {
        int q = t - 4128768;
        int oc = q / 576, rem = q % 576;
        int k9 = rem >> 6, ic = rem & 63;
        Aw2[q] = __float2bfloat16(w2[(oc * 64 + ic) * 9 + k9]);
    } else {
        int q = t - 4202496;
        int oc = q >> 5, k = q & 31;
        Aw1[q] = __float2bfloat16(k < 27 ? w1[oc * 27 + k] : 0.f);
    }
}

// ---------------- conv1(3->64,3x3,s1,p0) + relu + maxpool(2,2,p1) via MFMA -------
__global__ __launch_bounds__(256) void k_conv1_mfma(
    const float* __restrict__ data, const __hip_bfloat16* __restrict__ Aw1,
    const float* __restrict__ b1, __hip_bfloat16* __restrict__ P1t)
{
    __shared__ float tile[960];          // [ic]*312 + [rloc]*78 + [lc]; lc = x_in+1
    const int tid = threadIdx.x;
    const int py = blockIdx.x % 38, b = blockIdx.x / 38;

    #pragma unroll
    for (int c = 0; c < 4; c++) {
        int idx = tid + c * 256;
        if (idx < 960) {
            float val = 0.f;
            if (idx < 936) {
                int ic = idx / 312, rem = idx % 312;
                int rl = rem / 78, lc = rem % 78;
                int ri = 2 * py - 1 + rl, xi = lc - 1;
                if ((unsigned)ri < 76u && (unsigned)xi < 76u)
                    val = data[(b * 3 + ic) * 5776 + ri * 76 + xi];
            }
            tile[idx] = val;
        }
    }

    const int wave = tid >> 6, lane = tid & 63;
    const int l15 = lane & 15, quad = lane >> 4;

    bf16x8 af = *(const bf16x8*)((const ushort*)Aw1 + (wave * 16 + l15) * 32 + quad * 8);

    int koff[8]; bool kok[8];
    #pragma unroll
    for (int j = 0; j < 8; j++) {
        int kk = quad * 8 + j;
        kok[j] = kk < 27;
        int ic = kk / 9, rem = kk - ic * 9, ky = rem / 3, kx = rem - ky * 3;
        koff[j] = kok[j] ? (ic * 312 + ky * 78 + kx) : 0;
    }

    float bias[4];
    #pragma unroll
    for (int r = 0; r < 4; r++) bias[r] = b1[wave * 16 + quad * 4 + r];

    const bool valid0 = (py > 0);
    const bool valid1 = (py < 37);

    __syncthreads();

    #pragma unroll
    for (int t5 = 0; t5 < 5; t5++) {
        int n_x = t5 * 16 + l15;                         // conv x = n_x - 1
        bool col_ok = (unsigned)(n_x - 1) < 74u;

        bf16x8 bf0, bf1;
        #pragma unroll
        for (int j = 0; j < 8; j++) {
            float v0 = tile[koff[j] + n_x];
            float v1 = tile[koff[j] + 78 + n_x];
            bool ok = col_ok && kok[j];
            bf0[j] = (__bf16)(ok ? v0 : 0.f);
            bf1[j] = (__bf16)(ok ? v1 : 0.f);
        }
        f32x4 z = {0.f, 0.f, 0.f, 0.f};
        f32x4 c0 = __builtin_amdgcn_mfma_f32_16x16x32_bf16(af, bf0, z, 0, 0, 0);
        f32x4 c1 = __builtin_amdgcn_mfma_f32_16x16x32_bf16(af, bf1, z, 0, 0, 0);

        f32x4 p;
        #pragma unroll
        for (int r = 0; r < 4; r++) {
            float r0 = (valid0 && col_ok) ? fmaxf(c0[r] + bias[r], 0.f) : 0.f;
            float r1 = (valid1 && col_ok) ? fmaxf(c1[r] + bias[r], 0.f) : 0.f;
            p[r] = fmaxf(r0, r1);
        }
        #pragma unroll
        for (int r = 0; r < 4; r++)
            p[r] = fmaxf(p[r], __shfl_xor(p[r], 1));

        if (!(l15 & 1)) {
            int px = t5 * 8 + (l15 >> 1);
            if (px < 38) {
                ushort4 pk;
                pk.x = f2bf(p[0]); pk.y = f2bf(p[1]);
                pk.z = f2bf(p[2]); pk.w = f2bf(p[3]);
                *(ushort4*)((ushort*)P1t + ((size_t)(b * 38 + py) * 38 + px) * 64
                            + wave * 16 + quad * 4) = pk;
            }
        }
    }
}

// ---------------- conv2 MFMA + bias + relu + FUSED maxpool(2,2,p1) --------------
// N as (b-group of 4, cell, quadrant): 6400 n per group = 25 tiles of 256.
// Grid 1600 = 64 groups x 25 tiles, 512 threads, 2x4 waves of 64x64.
// n decode: off = toff*256 + row; bb = off/1600; rem = off%1600; cell = rem>>2;
// q = rem&3; conv pos y = 2py-1+(q>>1), x = 2px-1+(q&1). Invalid pos -> 0
// (relu >= 0, safe under max). Epilogue pools quadrants via shfl_xor(1),(2)
// (eq == lane15&3; 4-groups never straddle cell/bb boundaries since 4|1600)
// and the eq==0 lane stores P2t[b][py][px][oc]. Q tensor eliminated.
__global__ __launch_bounds__(512) void k_conv2_pool_mfma(
    const __hip_bfloat16* __restrict__ P1t,   // [256][38][38][64]
    const __hip_bfloat16* __restrict__ Aw2,   // [128][576]
    const float* __restrict__ cb,             // [128]
    __hip_bfloat16* __restrict__ P2t)         // [256][20][20][128]
{
    __shared__ ushort lA[128 * 72];           // 18,432 B
    __shared__ ushort lB[256 * 72];           // 36,864 B
    const int tid  = threadIdx.x;
    const int grp  = blockIdx.x / 25, toff = blockIdx.x % 25;
    const int wave = tid >> 6, lane = tid & 63;
    const int wm   = wave & 1, wn = wave >> 1;      // 2 x 4 waves
    const int lane15 = lane & 15, quad = lane >> 4;

    const int arow = tid >> 2, apart = tid & 3;
    const int brow = tid >> 1, bpart = tid & 1;

    // staging-row n decode
    int off = toff * 256 + brow;              // 0..6399 within group
    int bb = off / 1600, rem = off % 1600;
    int cell = rem >> 2, q = rem & 3;
    int py = cell / 20, px = cell % 20;
    int y = 2 * py - 1 + (q >> 1), x = 2 * px - 1 + (q & 1);
    int b = grp * 4 + bb;

    const __hip_bfloat16* Abase = Aw2 + arow * 576;
    ushort* lAw = &lA[arow * 72 + apart * 16];
    ushort* lBw = &lB[brow * 72 + bpart * 32];
    const ushort* aRd = &lA[(wm * 64 + lane15) * 72 + quad * 8];
    const ushort* bRd = &lB[(wn * 64 + lane15) * 72 + quad * 8];

    f32x4 zero = {0.f, 0.f, 0.f, 0.f};
    f32x4 acc[4][4];
    #pragma unroll
    for (int i = 0; i < 4; i++)
        #pragma unroll
        for (int j = 0; j < 4; j++) acc[i][j] = zero;

    for (int kb = 0; kb < 9; kb++) {                      // tap (ky,kx), 64 ic each
        int ky = kb / 3, kx = kb - ky * 3;
        int iy = y + ky - 1, ix = x + kx - 1;
        bool ok = ((unsigned)iy < 38u) && ((unsigned)ix < 38u);

        const uint4* ga = (const uint4*)(Abase + kb * 64 + apart * 16);
        uint4 av0 = ga[0], av1 = ga[1];
        uint4 z4 = {0u, 0u, 0u, 0u};
        uint4 bv0 = z4, bv1 = z4, bv2 = z4, bv3 = z4;
        if (ok) {
            const uint4* gb = (const uint4*)(P1t + (((b * 38 + iy) * 38 + ix) << 6) + bpart * 32);
            bv0 = gb[0]; bv1 = gb[1]; bv2 = gb[2]; bv3 = gb[3];
        }

        __syncthreads();
        ((uint4*)lAw)[0] = av0; ((uint4*)lAw)[1] = av1;
        ((uint4*)lBw)[0] = bv0; ((uint4*)lBw)[1] = bv1;
        ((uint4*)lBw)[2] = bv2; ((uint4*)lBw)[3] = bv3;
        __syncthreads();

        #pragma unroll
        for (int kk = 0; kk < 2; kk++) {
            bf16x8 af[4], bf[4];
            #pragma unroll
            for (int tm = 0; tm < 4; tm++)
                af[tm] = *(const bf16x8*)(aRd + tm * 16 * 72 + kk * 32);
            #pragma unroll
            for (int tn = 0; tn < 4; tn++)
                bf[tn] = *(const bf16x8*)(bRd + tn * 16 * 72 + kk * 32);
            #pragma unroll
            for (int tm = 0; tm < 4; tm++)
                #pragma unroll
                for (int tn = 0; tn < 4; tn++)
                    acc[tm][tn] = __builtin_amdgcn_mfma_f32_16x16x32_bf16(
                        af[tm], bf[tn], acc[tm][tn], 0, 0, 0);
        }
    }

    // epilogue: relu(val+bias), zero invalid quadrants, pool via shfl, store q==0
    #pragma unroll
    for (int tn = 0; tn < 4; tn++) {
        int woff = toff * 256 + wn * 64 + tn * 16 + lane15;
        int ebb = woff / 1600, erem = woff % 1600;
        int ecell = erem >> 2, eq = erem & 3;
        int epy = ecell / 20, epx = ecell % 20;
        int ey = 2 * epy - 1 + (eq >> 1), ex = 2 * epx - 1 + (eq & 1);
        bool vq = ((unsigned)ey < 38u) && ((unsigned)ex < 38u);
        int eb = grp * 4 + ebb;
        #pragma unroll
        for (int tm = 0; tm < 4; tm++) {
            int m0 = wm * 64 + tm * 16 + quad * 4;
            f32x4 a = acc[tm][tn];
            f32x4 p;
            #pragma unroll
            for (int r = 0; r < 4; r++)
                p[r] = vq ? fmaxf(a[r] + cb[m0 + r], 0.f) : 0.f;
            #pragma unroll
            for (int r = 0; r < 4; r++) {
                p[r] = fmaxf(p[r], __shfl_xor(p[r], 1));
                p[r] = fmaxf(p[r], __shfl_xor(p[r], 2));
            }
            if (eq == 0) {
                ushort4 pk;
                pk.x = f2bf(p[0]); pk.y = f2bf(p[1]);
                pk.z = f2bf(p[2]); pk.w = f2bf(p[3]);
                *(ushort4*)((ushort*)P2t + (((size_t)eb * 20 + epy) * 20 + epx) * 128 + m0) = pk;
            }
        }
    }
}

// ---------------- primcaps split-K MFMA GEMM, N=256 tile -> 6 fp32 partials ------
__global__ __launch_bounds__(512) void k_primcaps_mfma(
    const __hip_bfloat16* __restrict__ P2t,   // [256][20][20][128]
    const __hip_bfloat16* __restrict__ Awt,   // [256][10368]
    float* __restrict__ partU)                // [6][2359296]
{
    __shared__ ushort lA[128 * 72];           // 18,432 B
    __shared__ ushort lB[256 * 72];           // 36,864 B
    const int tid  = threadIdx.x;
    const int chunk = blockIdx.x / 72;
    const int tile  = blockIdx.x % 72;
    const int bm   = tile & 1;
    const int bn   = tile >> 1;               // 0..35
    const int wave = tid >> 6, lane = tid & 63;
    const int wm   = wave & 1, wn = wave >> 1;
    const int lane15 = lane & 15, quad = lane >> 4;

    const int arow = tid >> 2, apart = tid & 3;
    const int brow = tid >> 1, bpart = tid & 1;

    int n  = bn * 256 + brow;
    int cb = n / 36, cs = n % 36;
    int cy = cs / 6, cx = cs % 6;
    const __hip_bfloat16* Bbase = P2t + ((cb * 20 + 2 * cy) * 20 + 2 * cx) * 128;
    const __hip_bfloat16* Abase = Awt + (bm * 128 + arow) * 10368;
    ushort* lAw = &lA[arow * 72 + apart * 16];
    ushort* lBw = &lB[brow * 72 + bpart * 32];
    const ushort* aRd = &lA[(wm * 64 + lane15) * 72 + quad * 8];
    const ushort* bRd = &lB[(wn * 64 + lane15) * 72 + quad * 8];

    f32x4 zero = {0.f, 0.f, 0.f, 0.f};
    f32x4 acc[4][4];
    #pragma unroll
    for (int i = 0; i < 4; i++)
        #pragma unroll
        for (int j = 0; j < 4; j++) acc[i][j] = zero;

    const int kb0 = chunk * 27;
    for (int ki = 0; ki < 27; ki++) {
        int kb = kb0 + ki;
        int k81 = kb >> 1;
        int ky = k81 / 9, kx = k81 - ky * 9;
        int goffA = kb * 64 + apart * 16;
        int goffB = (ky * 20 + kx) * 128 + (kb & 1) * 64 + bpart * 32;

        const uint4* ga = (const uint4*)(Abase + goffA);
        const uint4* gb = (const uint4*)(Bbase + goffB);
        uint4 av0 = ga[0], av1 = ga[1];
        uint4 bv0 = gb[0], bv1 = gb[1], bv2 = gb[2], bv3 = gb[3];

        __syncthreads();
        ((uint4*)lAw)[0] = av0; ((uint4*)lAw)[1] = av1;
        ((uint4*)lBw)[0] = bv0; ((uint4*)lBw)[1] = bv1;
        ((uint4*)lBw)[2] = bv2; ((uint4*)lBw)[3] = bv3;
        __syncthreads();

        #pragma unroll
        for (int kk = 0; kk < 2; kk++) {
            bf16x8 af[4], bf[4];
            #pragma unroll
            for (int tm = 0; tm < 4; tm++)
                af[tm] = *(const bf16x8*)(aRd + tm * 16 * 72 + kk * 32);
            #pragma unroll
            for (int tn = 0; tn < 4; tn++)
                bf[tn] = *(const bf16x8*)(bRd + tn * 16 * 72 + kk * 32);
            #pragma unroll
            for (int tm = 0; tm < 4; tm++)
                #pragma unroll
                for (int tn = 0; tn < 4; tn++)
                    acc[tm][tn] = __builtin_amdgcn_mfma_f32_16x16x32_bf16(
                        af[tm], bf[tn], acc[tm][tn], 0, 0, 0);
        }
    }

    float* base = partU + chunk * 2359296;
    #pragma unroll
    for (int tm = 0; tm < 4; tm++) {
        int m0 = bm * 128 + wm * 64 + tm * 16 + quad * 4;
        #pragma unroll
        for (int tn = 0; tn < 4; tn++) {
            int nn = bn * 256 + wn * 64 + tn * 16 + lane15;
            int ob = nn / 36, os = nn % 36;
            float* up = base + ob * 9216 + os;
            f32x4 a = acc[tm][tn];
            #pragma unroll
            for (int r = 0; r < 4; r++)
                up[(m0 + r) * 36] = a[r];
        }
    }
}

// ---------------- reduce 6 partials + bias + squash -> u_bf [b][k] bf16 ----------
__global__ __launch_bounds__(256) void k_reduce_squash(
    const float* __restrict__ partU, const float* __restrict__ pb,
    ushort* __restrict__ u_bf)
{
    int t = blockIdx.x * 256 + threadIdx.x;              // 294912 threads
    float4 a = {0.f, 0.f, 0.f, 0.f}, b4 = {0.f, 0.f, 0.f, 0.f};
    #pragma unroll
    for (int p = 0; p < 6; p++) {
        const float4* pp = (const float4*)(partU + p * 2359296 + t * 8);
        float4 x = pp[0], y = pp[1];
        a.x += x.x; a.y += x.y; a.z += x.z; a.w += x.w;
        b4.x += y.x; b4.y += y.y; b4.z += y.z; b4.w += y.w;
    }
    int lb = (t % 1152) * 8;
    int oc0 = lb / 36, s0 = lb - oc0 * 36;
    float vals[8] = {a.x, a.y, a.z, a.w, b4.x, b4.y, b4.z, b4.w};
    float sn = 0.f;
    #pragma unroll
    for (int e = 0; e < 8; e++) {
        int oc = oc0 + ((s0 + e) >= 36 ? 1 : 0);
        vals[e] += pb[oc];
        sn += vals[e] * vals[e];
    }
    float sc = sqrtf(sn) / (1.f + sn);
    u16x8 o8;
    #pragma unroll
    for (int e = 0; e < 8; e++) o8[e] = f2bf(vals[e] * sc);
    *(u16x8*)(u_bf + (size_t)t * 8) = o8;
}

// ---------------- s_j with inline softmax ----------------
__global__ __launch_bounds__(320) void k_sj_fused(
    const ushort* __restrict__ u_bf,          // [256][9216] bf16
    const __hip_bfloat16* __restrict__ Wt,    // [9216][160] bf16
    const float* __restrict__ expb,           // [1152][10]
    float* __restrict__ partS,                // [16][256*160]
    int iter)
{
    __shared__ ushort ush[8 * 1152];
    __shared__ float cf[1440];
    __shared__ float sred[320];
    __shared__ float sinv[10];
    const int tid = threadIdx.x;
    const int bt = blockIdx.x & 31, kc = blockIdx.x >> 5;
    const int co = tid % 160, half = tid / 160;

    if (iter > 0) {
        int c = tid % 10, g = tid / 10;                  // 10 x 32 partition
        float s = 0.f;
        for (int r = g; r < 1152; r += 32) s += expb[r * 10 + c];
        sred[tid] = s;
        for (int i = tid; i < 1440; i += 320) cf[i] = expb[kc * 1440 + i];
        __syncthreads();
        if (tid < 10) {
            float t2 = 0.f;
            #pragma unroll
            for (int gg = 0; gg < 32; gg++) t2 += sred[tid + gg * 10];
            sinv[tid] = 1.f / t2;
        }
    }
    for (int i = tid; i < 1152; i += 320)     // 8 b x 144 uint4
        ((uint4*)ush)[i] = ((const uint4*)u_bf)[(size_t)(bt * 8 + (i / 144)) * 1152
                                                + kc * 144 + (i % 144)];
    __syncthreads();

    const int cc = co >> 4;
    const float scl = (iter > 0) ? sinv[cc] : 0.f;
    const float cuni = 1.f / 1152.f;
    const ushort* wp = (const ushort*)Wt + ((size_t)kc * 1152 + half * 576) * 160 + co;

    float acc[8] = {0.f, 0.f, 0.f, 0.f, 0.f, 0.f, 0.f, 0.f};
    for (int rr = 0; rr < 72; rr++) {
        float cl = (iter == 0) ? cuni : cf[(half * 72 + rr) * 10 + cc] * scl;
        float wv[8];
        #pragma unroll
        for (int ii = 0; ii < 8; ii++)
            wv[ii] = b2f(wp[(rr * 8 + ii) * 160]) * cl;
        int kbase = half * 576 + rr * 8;
        #pragma unroll
        for (int bb = 0; bb < 8; bb++) {
            u16x8 uq = *(const u16x8*)&ush[bb * 1152 + kbase];
            #pragma unroll
            for (int ii = 0; ii < 8; ii++)
                acc[bb] += wv[ii] * b2f(uq[ii]);
        }
    }
    float* ps = partS + (kc * 2 + half) * 40960;
    #pragma unroll
    for (int bb = 0; bb < 8; bb++)
        ps[(bt * 8 + bb) * 160 + co] = acc[bb];
}

// ---------------- v = squash(sum partS); final iter also runs classifiers -------
__global__ __launch_bounds__(320) void k_vj_cls(
    const float* __restrict__ partS, float* __restrict__ v,
    const float* __restrict__ w1, const float* __restrict__ b1,
    const float* __restrict__ w2, const float* __restrict__ b2,
    float* __restrict__ out, int write_out)
{
    const int b = blockIdx.x;
    const int tid = threadIdx.x;
    __shared__ float feat[160];
    if (tid < 160) {
        float s = 0.f;
        #pragma unroll
        for (int p = 0; p < 16; p++) s += partS[p * 40960 + b * 160 + tid];
        float vv = s * fabsf(s) / (1.f + s * s);
        v[b * 160 + tid] = vv;
        feat[tid] = vv;
        if (write_out) out[b * 160 + tid] = vv;
    }
    if (!write_out) return;
    __syncthreads();
    int k = tid >> 5, j = tid & 31;                      // 10 classifiers x 32 lanes
    float acc = 0.f;
    for (int h = j; h < 100; h += 32) {
        float a = b1[k * 100 + h];
        for (int f = 0; f < 160; f++) a += feat[f] * w1[(k * 160 + f) * 100 + h];
        acc += fmaxf(a, 0.f) * w2[k * 100 + h];
    }
    #pragma unroll
    for (int d = 16; d > 0; d >>= 1) acc += __shfl_xor(acc, d);
    if (j == 0)
        out[40960 + b * 10 + k] = 1.f / (1.f + expf(-(acc + b2[k])));
}

// ---------------- M rows for route r + a_ij + bij update + expb -----------------
__global__ __launch_bounds__(320) void k_mmat_aij(
    const ushort* __restrict__ u_bf, const float* __restrict__ v,
    const float* __restrict__ W, float* __restrict__ bij,
    float* __restrict__ expb)
{
    const int r = blockIdx.x;
    const int tid = threadIdx.x;
    const int co = tid % 160, bh = tid / 160;
    float acc[8] = {0.f, 0.f, 0.f, 0.f, 0.f, 0.f, 0.f, 0.f};
    for (int b = bh; b < 256; b += 2) {
        float vv = v[b * 160 + co];
        u16x8 uq = *(const u16x8*)(u_bf + (size_t)b * 9216 + r * 8);
        #pragma unroll
        for (int j = 0; j < 8; j++) acc[j] += vv * b2f(uq[j]);
    }
    __shared__ float red[2560];               // [j][bh][co]
    __shared__ float Ml[8][160];
    #pragma unroll
    for (int j = 0; j < 8; j++) red[j * 320 + bh * 160 + co] = acc[j];
    __syncthreads();
    if (tid < 160) {
        #pragma unroll
        for (int j = 0; j < 8; j++)
            Ml[j][tid] = (red[j * 320 + tid] + red[j * 320 + 160 + tid]) * (1.f / 256.f);
    }
    __syncthreads();
    int c = tid >> 5, j32 = tid & 31;                    // 10 c x 32 lanes
    const float* wr = W + ((size_t)r * 10 + c) * 128;    // W[r][c][o][i] flat
    float a2 = 0.f;
    #pragma unroll
    for (int m = 0; m < 4; m++) {
        int idx = j32 + m * 32;                          // = o*8 + i
        int o = idx >> 3, i = idx & 7;
        a2 += wr[idx] * Ml[i][c * 16 + o];
    }
    #pragma unroll
    for (int d = 16; d > 0; d >>= 1) a2 += __shfl_xor(a2, d);
    if (j32 == 0) {
        float nb = bij[c * 1152 + r] + a2;
        bij[c * 1152 + r] = nb;
        expb[r * 10 + c] = expf(nb);
    }
}

extern "C" void kernel_launch(void* const* d_in, const int* in_sizes, int n_in,
                              void* d_out, int out_size, void* d_ws, size_t ws_size,
                              hipStream_t stream) {
    const float* data    = (const float*)d_in[0];
    const float* conv1_w = (const float*)d_in[1];
    const float* conv1_b = (const float*)d_in[2];
    const float* conv2_w = (const float*)d_in[3];
    const float* conv2_b = (const float*)d_in[4];
    const float* prim_w  = (const float*)d_in[5];
    const float* prim_b  = (const float*)d_in[6];
    const float* W       = (const float*)d_in[7];
    const float* cls_w1  = (const float*)d_in[8];
    const float* cls_b1  = (const float*)d_in[9];
    const float* cls_w2  = (const float*)d_in[10];
    const float* cls_b2  = (const float*)d_in[11];
    float* out = (float*)d_out;

    char* ws = (char*)d_ws;
    // NOTE: fused conv2+pool reads P1t while writing P2t -> they MUST be
    // disjoint. P2t now lives after partU; partU (written later by primcaps)
    // does not overlap P2t either. No region aliasing anywhere this round.
    float*          partU = (float*)(ws + 0);                   // 56,623,104
    __hip_bfloat16* P2t   = (__hip_bfloat16*)(ws + 56623104);   // 13,107,200
    __hip_bfloat16* P1t   = (__hip_bfloat16*)(ws + 94633984);   // 47,316,992
    __hip_bfloat16* Awt   = (__hip_bfloat16*)(ws + 141950976);  //  5,308,416
    __hip_bfloat16* Wt    = (__hip_bfloat16*)(ws + 147259392);  //  2,949,120
    ushort*         u_bf  = (ushort*)(ws + 150208512);          //  4,718,592
    float*          partS = (float*)(ws + 154927104);           //  2,621,440
    float*          v     = (float*)(ws + 163446784);           //    163,840
    float*          bij   = (float*)(ws + 163610624);           //     46,080
    float*          expb  = (float*)(ws + 163656704);           //     46,080
    __hip_bfloat16* Aw2   = (__hip_bfloat16*)(ws + 163702784);  //    147,456
    __hip_bfloat16* Aw1   = (__hip_bfloat16*)(ws + 163850240);  //      4,096
    // total: 163,854,336 bytes

    hipMemsetAsync(bij, 0, 11520 * sizeof(float), stream);

    k_prep_all<<<16424, 256, 0, stream>>>(conv1_w, conv2_w, prim_w, W,
                                          Aw1, Aw2, Awt, Wt);
    k_conv1_mfma<<<9728, 256, 0, stream>>>(data, Aw1, conv1_b, P1t);
    k_conv2_pool_mfma<<<1600, 512, 0, stream>>>(P1t, Aw2, conv2_b, P2t);
    k_primcaps_mfma<<<432, 512, 0, stream>>>(P2t, Awt, partU);
    k_reduce_squash<<<1152, 256, 0, stream>>>(partU, prim_b, u_bf);

    for (int it = 0; it < 3; it++) {
        k_sj_fused<<<256, 320, 0, stream>>>(u_bf, Wt, expb, partS, it);
        k_vj_cls<<<256, 320, 0, stream>>>(partS, v, cls_w1, cls_b1, cls_w2,
                                          cls_b2, out, it == 2 ? 1 : 0);
        if (it < 2)
            k_mmat_aij<<<1152, 320, 0, stream>>>(u_bf, v, W, bij, expb);
    }
}